// Round 2
// baseline (2997.294 us; speedup 1.0000x reference)
//
#include <hip/hip_runtime.h>
#include <math.h>

#define BB 16
#define NN 512
#define DIN 128
#define DM 256
#define NH 8
#define DH 32
#define FF 1024
#define DOUT 128
#define NHOP 258
#define NEDGE 27
#define ROWS (BB*NN)   // 8192

// ---------------- layernorm: one wave per row, float4 + shuffle ----------------
__global__ __launch_bounds__(256) void k_ln(const float* __restrict__ in, const float* __restrict__ g,
                                            const float* __restrict__ bta, float* __restrict__ out) {
    int row = blockIdx.x * 4 + (threadIdx.x >> 6);
    int l = threadIdx.x & 63;
    float4 xv = ((const float4*)(in + (size_t)row*DM))[l];
    float s = xv.x + xv.y + xv.z + xv.w;
    #pragma unroll
    for (int o = 32; o > 0; o >>= 1) s += __shfl_xor(s, o, 64);
    float mean = s * (1.0f/DM);
    float dx = xv.x-mean, dy = xv.y-mean, dz = xv.z-mean, dw = xv.w-mean;
    float vs = dx*dx + dy*dy + dz*dz + dw*dw;
    #pragma unroll
    for (int o = 32; o > 0; o >>= 1) vs += __shfl_xor(vs, o, 64);
    float r = rsqrtf(vs * (1.0f/DM) + 1e-5f);
    float4 gg = ((const float4*)g)[l];
    float4 bb = ((const float4*)bta)[l];
    float4 ov; ov.x = dx*r*gg.x+bb.x; ov.y = dy*r*gg.y+bb.y; ov.z = dz*r*gg.z+bb.z; ov.w = dw*r*gg.w+bb.w;
    ((float4*)(out + (size_t)row*DM))[l] = ov;
}

// ---------------- tiled GEMM: 16 rows/block, 256 cols/block ----------------
// QKV=1 writes out in [B,H,N,DH] layout. RES=1 accumulates into out. ACT=1 exact gelu.
template<int K, int N, int ACT, int RES, int QKV>
__global__ __launch_bounds__(256) void k_gemm(const float* __restrict__ A, const float* __restrict__ W,
                                              const float* __restrict__ bias, float* __restrict__ out) {
    constexpr int KC = (K < 256) ? K : 256;
    __shared__ __align__(16) float As[16][KC];
    int r0 = blockIdx.x * 16;
    int colbase = blockIdx.y * 256;
    int tid = threadIdx.x;
    int col = colbase + tid;
    bool active = tid < ((N < 256) ? N : 256);
    float bv = 0.f;
    if (active) bv = bias[col];
    float acc[16];
    #pragma unroll
    for (int r = 0; r < 16; ++r) acc[r] = 0.f;

    for (int kc = 0; kc < K; kc += KC) {
        for (int idx = tid*4; idx < 16*KC; idx += 1024) {
            int r = idx / KC, kk = idx % KC;
            *(float4*)&As[r][kk] = *(const float4*)&A[(size_t)(r0 + r)*K + kc + kk];
        }
        __syncthreads();
        if (active) {
            for (int kk = 0; kk < KC; kk += 4) {
                const float* wp = W + (size_t)(kc + kk)*N + col;
                float w0 = wp[0], w1 = wp[N], w2 = wp[2*N], w3 = wp[3*N];
                #pragma unroll
                for (int r = 0; r < 16; ++r) {
                    float4 a = *(const float4*)&As[r][kk];
                    acc[r] += a.x*w0 + a.y*w1 + a.z*w2 + a.w*w3;
                }
            }
        }
        __syncthreads();
    }
    if (active) {
        #pragma unroll
        for (int r = 0; r < 16; ++r) {
            float val = acc[r] + bv;
            if (ACT) val = 0.5f * val * (1.0f + erff(val * 0.70710678118654752f));
            int row = r0 + r;
            if (QKV) {
                int b = row >> 9, n = row & (NN-1);
                int hh = col >> 5, d = col & (DH-1);
                out[(size_t)((b*NH + hh)*NN + n)*DH + d] = val;
            } else if (RES) {
                out[(size_t)row*N + col] += val;
            } else {
                out[(size_t)row*N + col] = val;
            }
        }
    }
}

// ---------------- khT[bh,m,j] = k[bh,j,:] . Kh[h,m,:] ----------------
__global__ __launch_bounds__(256) void k_kht(const float* __restrict__ k, const float* __restrict__ k_hop,
                                             float* __restrict__ kht) {
    int bm = blockIdx.x;             // bh*NHOP + m
    int m = bm % NHOP;
    int bh = bm / NHOP;
    int hh = bh & (NH-1);
    const float4* khp = (const float4*)(k_hop + (size_t)m*DM + hh*DH);
    float4 c0 = khp[0], c1 = khp[1], c2 = khp[2], c3 = khp[3];
    float4 c4 = khp[4], c5 = khp[5], c6 = khp[6], c7 = khp[7];
    const float* kb = k + (size_t)bh*NN*DH;
    for (int j = threadIdx.x; j < NN; j += 256) {
        const float4* kj = (const float4*)(kb + j*DH);
        float4 a0 = kj[0], a1 = kj[1], a2 = kj[2], a3 = kj[3];
        float4 a4 = kj[4], a5 = kj[5], a6 = kj[6], a7 = kj[7];
        float acc = a0.x*c0.x + a0.y*c0.y + a0.z*c0.z + a0.w*c0.w
                  + a1.x*c1.x + a1.y*c1.y + a1.z*c1.z + a1.w*c1.w
                  + a2.x*c2.x + a2.y*c2.y + a2.z*c2.z + a2.w*c2.w
                  + a3.x*c3.x + a3.y*c3.y + a3.z*c3.z + a3.w*c3.w
                  + a4.x*c4.x + a4.y*c4.y + a4.z*c4.z + a4.w*c4.w
                  + a5.x*c5.x + a5.y*c5.y + a5.z*c5.z + a5.w*c5.w
                  + a6.x*c6.x + a6.y*c6.y + a6.z*c6.z + a6.w*c6.w
                  + a7.x*c7.x + a7.y*c7.y + a7.z*c7.z + a7.w*c7.w;
        kht[(size_t)bm*NN + j] = acc;
    }
}

// ---------------- fused attention: one block per (b,i), all 8 heads ----------------
__global__ __launch_bounds__(256) void k_attn(
    const float* __restrict__ q, const float* __restrict__ k, const float* __restrict__ v,
    const float* __restrict__ kht, const int* __restrict__ dist, const int* __restrict__ edge,
    const unsigned char* __restrict__ mask,
    const float* __restrict__ q_hop, const float* __restrict__ q_edge,
    const float* __restrict__ k_edge, const float* __restrict__ v_hop,
    const float* __restrict__ v_edge, float* __restrict__ ctx)
{
    int bi = blockIdx.x;            // b*NN + i
    int i  = bi & (NN-1);
    int b  = bi >> 9;
    int t  = threadIdx.x;

    __shared__ __align__(16) float qi[NH][DH];
    __shared__ __align__(16) float ki[NH][DH];
    __shared__ int   mjs[NN];
    __shared__ int   ejs[NN];
    __shared__ float qh[NH][NHOP];
    __shared__ float qec[NH][28];
    __shared__ float p[NH][NN];

    // ---- phase A: indices + per-row q/k fragments ----
    {
        const int* dr = dist + ((size_t)b*NN + i)*NN;
        const int* er = edge + ((size_t)b*NN + i)*NN;
        for (int j = t; j < NN; j += 256) {
            int dv = dr[j]; int m = dv > 256 ? 256 : dv; if (dv < 0) m = 257;
            int ev = er[j]; int e = ev > 25  ? 25  : ev; if (ev < 0) e = 26;
            mjs[j] = m; ejs[j] = e;
        }
        int hh = t >> 5, d = t & (DH-1);
        qi[hh][d] = q[(size_t)((b*NH + hh)*NN + i)*DH + d];
        ki[hh][d] = k[(size_t)((b*NH + hh)*NN + i)*DH + d];
    }
    __syncthreads();

    // ---- phase B: per-row bias tables ----
    for (int idx = t; idx < NH*NHOP; idx += 256) {
        int hh = idx / NHOP, m = idx - hh*NHOP;
        const float4* Qh = (const float4*)(q_hop + (size_t)m*DM + hh*DH);
        const float4* qv = (const float4*)qi[hh];
        float a = 0.f;
        #pragma unroll
        for (int d4 = 0; d4 < 8; ++d4) {
            float4 w = Qh[d4]; float4 qq = qv[d4];
            a += qq.x*w.x + qq.y*w.y + qq.z*w.z + qq.w*w.w;
        }
        qh[hh][m] = a;
    }
    if (t < NH*NEDGE) {
        int hh = t / NEDGE, e = t - hh*NEDGE;
        const float4* Qe = (const float4*)(q_edge + (size_t)e*DM + hh*DH);
        const float4* Ke = (const float4*)(k_edge + (size_t)e*DM + hh*DH);
        const float4* qv = (const float4*)qi[hh];
        const float4* kv = (const float4*)ki[hh];
        float a = 0.f;
        #pragma unroll
        for (int d4 = 0; d4 < 8; ++d4) {
            float4 w = Qe[d4]; float4 qq = qv[d4];
            float4 u = Ke[d4]; float4 kk = kv[d4];
            a += qq.x*w.x + qq.y*w.y + qq.z*w.z + qq.w*w.w
               + kk.x*u.x + kk.y*u.y + kk.z*u.z + kk.w*u.w;
        }
        qec[hh][e] = a;
    }
    __syncthreads();

    // ---- phase C: scores + softmax in registers ----
    {
        int hh = t >> 5, l = t & 31;
        const float4* qp = (const float4*)qi[hh];
        float4 q0 = qp[0], q1 = qp[1], q2 = qp[2], q3 = qp[3];
        float4 q4 = qp[4], q5 = qp[5], q6 = qp[6], q7 = qp[7];
        const float* kbase = k + (size_t)((b*NH + hh)*NN)*DH;
        const float* khtb  = kht + (size_t)(b*NH + hh)*NHOP*NN;
        const unsigned char* mrow = mask + (size_t)b*NN;
        const float scale = 0.17677669529663687f;
        float sc[16];
        #pragma unroll
        for (int s = 0; s < 16; ++s) {
            int j = l + 32*s;
            const float4* kj = (const float4*)(kbase + j*DH);
            float4 a0 = kj[0], a1 = kj[1], a2 = kj[2], a3 = kj[3];
            float4 a4 = kj[4], a5 = kj[5], a6 = kj[6], a7 = kj[7];
            float a = a0.x*q0.x + a0.y*q0.y + a0.z*q0.z + a0.w*q0.w
                    + a1.x*q1.x + a1.y*q1.y + a1.z*q1.z + a1.w*q1.w
                    + a2.x*q2.x + a2.y*q2.y + a2.z*q2.z + a2.w*q2.w
                    + a3.x*q3.x + a3.y*q3.y + a3.z*q3.z + a3.w*q3.w
                    + a4.x*q4.x + a4.y*q4.y + a4.z*q4.z + a4.w*q4.w
                    + a5.x*q5.x + a5.y*q5.y + a5.z*q5.z + a5.w*q5.w
                    + a6.x*q6.x + a6.y*q6.y + a6.z*q6.z + a6.w*q6.w
                    + a7.x*q7.x + a7.y*q7.y + a7.z*q7.z + a7.w*q7.w;
            int m = mjs[j], e = ejs[j];
            a += qh[hh][m] + khtb[(size_t)m*NN + j] + qec[hh][e];
            a *= scale;
            if (mrow[j]) a = -INFINITY;
            sc[s] = a;
        }
        float mx = sc[0];
        #pragma unroll
        for (int s = 1; s < 16; ++s) mx = fmaxf(mx, sc[s]);
        #pragma unroll
        for (int o = 16; o > 0; o >>= 1) mx = fmaxf(mx, __shfl_xor(mx, o, 32));
        float sum = 0.f;
        #pragma unroll
        for (int s = 0; s < 16; ++s) { sc[s] = __expf(sc[s] - mx); sum += sc[s]; }
        #pragma unroll
        for (int o = 16; o > 0; o >>= 1) sum += __shfl_xor(sum, o, 32);
        float inv = 1.0f / sum;
        #pragma unroll
        for (int s = 0; s < 16; ++s) p[hh][l + 32*s] = sc[s] * inv;
    }
    __syncthreads();

    // ---- phase D: AV with fused Vh/Ve gathers ----
    {
        int hh = t >> 5;
        int rest = t & 31;
        int jc = rest & 3;        // j interleave (kills p[] bank conflicts)
        int d4 = rest >> 2;       // 0..7, float4 column
        const float* vb  = v + (size_t)((b*NH + hh)*NN)*DH + d4*4;
        const float* vhb = v_hop  + hh*DH + d4*4;
        const float* veb = v_edge + hh*DH + d4*4;
        float4 acc; acc.x = acc.y = acc.z = acc.w = 0.f;
        for (int off = 0; off < 128; ++off) {
            int j = jc + 4*off;
            float w = p[hh][j];
            int m = mjs[j], e = ejs[j];
            float4 vv = *(const float4*)(vb + (size_t)j*DH);
            float4 vh = *(const float4*)(vhb + (size_t)m*DM);
            float4 ve = *(const float4*)(veb + (size_t)e*DM);
            acc.x += w * (vv.x + vh.x + ve.x);
            acc.y += w * (vv.y + vh.y + ve.y);
            acc.z += w * (vv.z + vh.z + ve.z);
            acc.w += w * (vv.w + vh.w + ve.w);
        }
        // reduce over jc (lane bits 0-1)
        acc.x += __shfl_xor(acc.x, 1, 4); acc.x += __shfl_xor(acc.x, 2, 4);
        acc.y += __shfl_xor(acc.y, 1, 4); acc.y += __shfl_xor(acc.y, 2, 4);
        acc.z += __shfl_xor(acc.z, 1, 4); acc.z += __shfl_xor(acc.z, 2, 4);
        acc.w += __shfl_xor(acc.w, 1, 4); acc.w += __shfl_xor(acc.w, 2, 4);
        if (jc == 0) {
            *(float4*)(ctx + (size_t)(b*NN + i)*DM + hh*DH + d4*4) = acc;
        }
    }
}

extern "C" void kernel_launch(void* const* d_in, const int* in_sizes, int n_in,
                              void* d_out, int out_size, void* d_ws, size_t ws_size,
                              hipStream_t stream) {
    const float* x     = (const float*)d_in[0];
    const unsigned char* mask = (const unsigned char*)d_in[1];
    const int*   dist  = (const int*)d_in[2];
    const int*   edge  = (const int*)d_in[3];
    const float* node_W = (const float*)d_in[4];
    const float* node_b = (const float*)d_in[5];
    const float* ln1_g = (const float*)d_in[6];
    const float* ln1_b = (const float*)d_in[7];
    const float* Wq = (const float*)d_in[8];
    const float* bq = (const float*)d_in[9];
    const float* Wk = (const float*)d_in[10];
    const float* bk = (const float*)d_in[11];
    const float* Wv = (const float*)d_in[12];
    const float* bv = (const float*)d_in[13];
    const float* Wo = (const float*)d_in[14];
    const float* bo = (const float*)d_in[15];
    const float* ln2_g = (const float*)d_in[16];
    const float* ln2_b = (const float*)d_in[17];
    const float* W1 = (const float*)d_in[18];
    const float* b1 = (const float*)d_in[19];
    const float* W2 = (const float*)d_in[20];
    const float* b2 = (const float*)d_in[21];
    const float* q_hop  = (const float*)d_in[22];
    const float* q_edge = (const float*)d_in[23];
    const float* k_hop  = (const float*)d_in[24];
    const float* k_edge = (const float*)d_in[25];
    const float* v_hop  = (const float*)d_in[26];
    const float* v_edge = (const float*)d_in[27];
    const float* fln_g = (const float*)d_in[28];
    const float* fln_b = (const float*)d_in[29];
    const float* out_W = (const float*)d_in[30];
    const float* out_b = (const float*)d_in[31];
    float* out = (float*)d_out;

    float* ws = (float*)d_ws;
    float* h   = ws + 0;                         //  2,097,152
    float* y   = ws + 2097152;                   //  2,097,152
    float* q   = ws + 4194304;                   //  2,097,152  [B,H,N,DH]
    float* k   = ws + 6291456;                   //  2,097,152
    float* v   = ws + 8388608;                   //  2,097,152
    float* ctx = ws + 10485760;                  //  2,097,152
    float* kht = ws + 12582912;                  // 16,908,288  [B,H,NHOP,N]
    float* ffn = kht;                            //  8,388,608  (aliases kht, dead by then)

    k_gemm<DIN, DM, 0, 0, 0><<<dim3(ROWS/16, 1), 256, 0, stream>>>(x, node_W, node_b, h);
    k_ln<<<ROWS/4, 256, 0, stream>>>(h, ln1_g, ln1_b, y);
    k_gemm<DM, DM, 0, 0, 1><<<dim3(ROWS/16, 1), 256, 0, stream>>>(y, Wq, bq, q);
    k_gemm<DM, DM, 0, 0, 1><<<dim3(ROWS/16, 1), 256, 0, stream>>>(y, Wk, bk, k);
    k_gemm<DM, DM, 0, 0, 1><<<dim3(ROWS/16, 1), 256, 0, stream>>>(y, Wv, bv, v);
    k_kht<<<BB*NH*NHOP, 256, 0, stream>>>(k, k_hop, kht);
    k_attn<<<BB*NN, 256, 0, stream>>>(q, k, v, kht, dist, edge, mask,
                                      q_hop, q_edge, k_edge, v_hop, v_edge, ctx);
    k_gemm<DM, DM, 0, 1, 0><<<dim3(ROWS/16, 1), 256, 0, stream>>>(ctx, Wo, bo, h);
    k_ln<<<ROWS/4, 256, 0, stream>>>(h, ln2_g, ln2_b, y);
    k_gemm<DM, FF, 1, 0, 0><<<dim3(ROWS/16, 4), 256, 0, stream>>>(y, W1, b1, ffn);
    k_gemm<FF, DM, 0, 1, 0><<<dim3(ROWS/16, 1), 256, 0, stream>>>(ffn, W2, b2, h);
    k_ln<<<ROWS/4, 256, 0, stream>>>(h, fln_g, fln_b, y);
    k_gemm<DM, DOUT, 0, 0, 0><<<dim3(ROWS/16, 1), 256, 0, stream>>>(y, out_W, out_b, out);
}

// Round 3
// 2333.777 us; speedup vs baseline: 1.2843x; 1.2843x over previous
//
#include <hip/hip_runtime.h>
#include <math.h>

#define BB 16
#define NN 512
#define DIN 128
#define DM 256
#define NH 8
#define DH 32
#define FF 1024
#define DOUT 128
#define NHOP 258
#define NEDGE 27
#define ROWS (BB*NN)   // 8192

// ---------------- layernorm: one wave per row, float4 + shuffle ----------------
__global__ __launch_bounds__(256) void k_ln(const float* __restrict__ in, const float* __restrict__ g,
                                            const float* __restrict__ bta, float* __restrict__ out) {
    int row = blockIdx.x * 4 + (threadIdx.x >> 6);
    int l = threadIdx.x & 63;
    float4 xv = ((const float4*)(in + (size_t)row*DM))[l];
    float s = xv.x + xv.y + xv.z + xv.w;
    #pragma unroll
    for (int o = 32; o > 0; o >>= 1) s += __shfl_xor(s, o, 64);
    float mean = s * (1.0f/DM);
    float dx = xv.x-mean, dy = xv.y-mean, dz = xv.z-mean, dw = xv.w-mean;
    float vs = dx*dx + dy*dy + dz*dz + dw*dw;
    #pragma unroll
    for (int o = 32; o > 0; o >>= 1) vs += __shfl_xor(vs, o, 64);
    float r = rsqrtf(vs * (1.0f/DM) + 1e-5f);
    float4 gg = ((const float4*)g)[l];
    float4 bb = ((const float4*)bta)[l];
    float4 ov; ov.x = dx*r*gg.x+bb.x; ov.y = dy*r*gg.y+bb.y; ov.z = dz*r*gg.z+bb.z; ov.w = dw*r*gg.w+bb.w;
    ((float4*)(out + (size_t)row*DM))[l] = ov;
}

// ---------------- tiled GEMM: 16 rows/block, 256 cols/block ----------------
template<int K, int N, int ACT, int RES, int QKV>
__global__ __launch_bounds__(256) void k_gemm(const float* __restrict__ A, const float* __restrict__ W,
                                              const float* __restrict__ bias, float* __restrict__ out) {
    constexpr int KC = (K < 256) ? K : 256;
    __shared__ __align__(16) float As[16][KC];
    int r0 = blockIdx.x * 16;
    int colbase = blockIdx.y * 256;
    int tid = threadIdx.x;
    int col = colbase + tid;
    bool active = tid < ((N < 256) ? N : 256);
    float bv = 0.f;
    if (active) bv = bias[col];
    float acc[16];
    #pragma unroll
    for (int r = 0; r < 16; ++r) acc[r] = 0.f;

    for (int kc = 0; kc < K; kc += KC) {
        for (int idx = tid*4; idx < 16*KC; idx += 1024) {
            int r = idx / KC, kk = idx % KC;
            *(float4*)&As[r][kk] = *(const float4*)&A[(size_t)(r0 + r)*K + kc + kk];
        }
        __syncthreads();
        if (active) {
            for (int kk = 0; kk < KC; kk += 4) {
                const float* wp = W + (size_t)(kc + kk)*N + col;
                float w0 = wp[0], w1 = wp[N], w2 = wp[2*N], w3 = wp[3*N];
                #pragma unroll
                for (int r = 0; r < 16; ++r) {
                    float4 a = *(const float4*)&As[r][kk];
                    acc[r] += a.x*w0 + a.y*w1 + a.z*w2 + a.w*w3;
                }
            }
        }
        __syncthreads();
    }
    if (active) {
        #pragma unroll
        for (int r = 0; r < 16; ++r) {
            float val = acc[r] + bv;
            if (ACT) val = 0.5f * val * (1.0f + erff(val * 0.70710678118654752f));
            int row = r0 + r;
            if (QKV) {
                int b = row >> 9, n = row & (NN-1);
                int hh = col >> 5, d = col & (DH-1);
                out[(size_t)((b*NH + hh)*NN + n)*DH + d] = val;
            } else if (RES) {
                out[(size_t)row*N + col] += val;
            } else {
                out[(size_t)row*N + col] = val;
            }
        }
    }
}

// ---------------- khT[bh,m,j] = k[bh,j,:] . Kh[h,m,:] ----------------
__global__ __launch_bounds__(256) void k_kht(const float* __restrict__ k, const float* __restrict__ k_hop,
                                             float* __restrict__ kht) {
    int bm = blockIdx.x;             // bh*NHOP + m
    int m = bm % NHOP;
    int bh = bm / NHOP;
    int hh = bh & (NH-1);
    const float4* khp = (const float4*)(k_hop + (size_t)m*DM + hh*DH);
    float4 c0 = khp[0], c1 = khp[1], c2 = khp[2], c3 = khp[3];
    float4 c4 = khp[4], c5 = khp[5], c6 = khp[6], c7 = khp[7];
    const float* kb = k + (size_t)bh*NN*DH;
    for (int j = threadIdx.x; j < NN; j += 256) {
        const float4* kj = (const float4*)(kb + j*DH);
        float4 a0 = kj[0], a1 = kj[1], a2 = kj[2], a3 = kj[3];
        float4 a4 = kj[4], a5 = kj[5], a6 = kj[6], a7 = kj[7];
        float acc = a0.x*c0.x + a0.y*c0.y + a0.z*c0.z + a0.w*c0.w
                  + a1.x*c1.x + a1.y*c1.y + a1.z*c1.z + a1.w*c1.w
                  + a2.x*c2.x + a2.y*c2.y + a2.z*c2.z + a2.w*c2.w
                  + a3.x*c3.x + a3.y*c3.y + a3.z*c3.z + a3.w*c3.w
                  + a4.x*c4.x + a4.y*c4.y + a4.z*c4.z + a4.w*c4.w
                  + a5.x*c5.x + a5.y*c5.y + a5.z*c5.z + a5.w*c5.w
                  + a6.x*c6.x + a6.y*c6.y + a6.z*c6.z + a6.w*c6.w
                  + a7.x*c7.x + a7.y*c7.y + a7.z*c7.z + a7.w*c7.w;
        kht[(size_t)bm*NN + j] = acc;
    }
}

// ---------------- fused attention: one WAVE per (b,h,i); block = (b,i,4 heads) ----------------
__global__ __launch_bounds__(256) void k_attn(
    const float* __restrict__ q, const float* __restrict__ k, const float* __restrict__ v,
    const float* __restrict__ kht, const int* __restrict__ dist, const int* __restrict__ edge,
    const unsigned char* __restrict__ mask,
    const float* __restrict__ q_hop, const float* __restrict__ q_edge,
    const float* __restrict__ k_edge, const float* __restrict__ v_hop,
    const float* __restrict__ v_edge, float* __restrict__ ctx)
{
    // blockIdx.x = (b * 512 + i) * 2 + hg ; wave w handles head h = hg*4 + w
    int blk = blockIdx.x;
    int hg  = blk & 1;
    int bi  = blk >> 1;
    int i   = bi & (NN-1);
    int b   = bi >> 9;
    int w   = threadIdx.x >> 6;
    int l   = threadIdx.x & 63;
    int hh  = hg*4 + w;
    int bh  = b*NH + hh;

    __shared__ int   mje[NN];            // m | (e<<16), shared by the 4 waves (same b,i)
    __shared__ float qhq[4][NHOP + 6 + NEDGE];  // per-wave: qh[0..257], qec at [264..290]
    __shared__ float pbuf[4][NN];

    // ---- phase A (block-shared): decode dist/edge row ----
    {
        int t = threadIdx.x;
        if (t < 128) {
            int4 dv = ((const int4*)(dist + ((size_t)b*NN + i)*NN))[t];
            int4 ev = ((const int4*)(edge + ((size_t)b*NN + i)*NN))[t];
            int m0 = dv.x > 256 ? 256 : dv.x; if (dv.x < 0) m0 = 257;
            int m1 = dv.y > 256 ? 256 : dv.y; if (dv.y < 0) m1 = 257;
            int m2 = dv.z > 256 ? 256 : dv.z; if (dv.z < 0) m2 = 257;
            int m3 = dv.w > 256 ? 256 : dv.w; if (dv.w < 0) m3 = 257;
            int e0 = ev.x > 25 ? 25 : ev.x; if (ev.x < 0) e0 = 26;
            int e1 = ev.y > 25 ? 25 : ev.y; if (ev.y < 0) e1 = 26;
            int e2 = ev.z > 25 ? 25 : ev.z; if (ev.z < 0) e2 = 26;
            int e3 = ev.w > 25 ? 25 : ev.w; if (ev.w < 0) e3 = 26;
            mje[t*4+0] = m0 | (e0<<16);
            mje[t*4+1] = m1 | (e1<<16);
            mje[t*4+2] = m2 | (e2<<16);
            mje[t*4+3] = m3 | (e3<<16);
        }
    }
    __syncthreads();

    // ---- load q_i into registers (broadcast across lanes) ----
    float4 q0, q1, q2, q3, q4, q5, q6, q7;
    {
        const float4* qp = (const float4*)(q + ((size_t)bh*NN + i)*DH);
        q0 = qp[0]; q1 = qp[1]; q2 = qp[2]; q3 = qp[3];
        q4 = qp[4]; q5 = qp[5]; q6 = qp[6]; q7 = qp[7];
    }

    // ---- phase B (per wave): qh table + qec table ----
    #pragma unroll
    for (int s = 0; s < 5; ++s) {
        int m = l + 64*s;
        if (m < NHOP) {
            const float4* Qh = (const float4*)(q_hop + (size_t)m*DM + hh*DH);
            float4 a0 = Qh[0], a1 = Qh[1], a2 = Qh[2], a3 = Qh[3];
            float4 a4 = Qh[4], a5 = Qh[5], a6 = Qh[6], a7 = Qh[7];
            qhq[w][m] = a0.x*q0.x + a0.y*q0.y + a0.z*q0.z + a0.w*q0.w
                      + a1.x*q1.x + a1.y*q1.y + a1.z*q1.z + a1.w*q1.w
                      + a2.x*q2.x + a2.y*q2.y + a2.z*q2.z + a2.w*q2.w
                      + a3.x*q3.x + a3.y*q3.y + a3.z*q3.z + a3.w*q3.w
                      + a4.x*q4.x + a4.y*q4.y + a4.z*q4.z + a4.w*q4.w
                      + a5.x*q5.x + a5.y*q5.y + a5.z*q5.z + a5.w*q5.w
                      + a6.x*q6.x + a6.y*q6.y + a6.z*q6.z + a6.w*q6.w
                      + a7.x*q7.x + a7.y*q7.y + a7.z*q7.z + a7.w*q7.w;
        }
    }
    if (l < NEDGE) {
        const float4* Qe = (const float4*)(q_edge + (size_t)l*DM + hh*DH);
        const float4* Ke = (const float4*)(k_edge + (size_t)l*DM + hh*DH);
        const float4* kp = (const float4*)(k + ((size_t)bh*NN + i)*DH);
        float a = 0.f;
        #pragma unroll
        for (int d4 = 0; d4 < 8; ++d4) {
            float4 ww = Qe[d4]; float4 u = Ke[d4]; float4 kk = kp[d4];
            const float4* qq4 = &q0; float4 qq = qq4[d4];
            a += qq.x*ww.x + qq.y*ww.y + qq.z*ww.z + qq.w*ww.w
               + kk.x*u.x + kk.y*u.y + kk.z*u.z + kk.w*u.w;
        }
        qhq[w][264 + l] = a;
    }
    // wave-local producer/consumer on qhq/pbuf: same wave, program order suffices.

    // ---- phase C (per wave): scores + softmax, 8 j per lane ----
    {
        const float* kbase = k + (size_t)bh*NN*DH;
        const float* khtb  = kht + (size_t)bh*NHOP*NN;
        const unsigned char* mrow = mask + (size_t)b*NN;
        const float scale = 0.17677669529663687f;

        int mv[8], evv[8];
        #pragma unroll
        for (int s = 0; s < 8; ++s) {
            int pk = mje[l + 64*s];
            mv[s] = pk & 0xFFFF; evv[s] = pk >> 16;
        }
        float khtv[8];
        #pragma unroll
        for (int s = 0; s < 8; ++s) {             // 8 independent scattered gathers in flight
            khtv[s] = khtb[(size_t)mv[s]*NN + (l + 64*s)];
        }
        float sc[8];
        #pragma unroll
        for (int s = 0; s < 8; ++s) {
            int j = l + 64*s;
            const float4* kj = (const float4*)(kbase + (size_t)j*DH);
            float4 a0 = kj[0], a1 = kj[1], a2 = kj[2], a3 = kj[3];
            float4 a4 = kj[4], a5 = kj[5], a6 = kj[6], a7 = kj[7];
            float a = a0.x*q0.x + a0.y*q0.y + a0.z*q0.z + a0.w*q0.w
                    + a1.x*q1.x + a1.y*q1.y + a1.z*q1.z + a1.w*q1.w
                    + a2.x*q2.x + a2.y*q2.y + a2.z*q2.z + a2.w*q2.w
                    + a3.x*q3.x + a3.y*q3.y + a3.z*q3.z + a3.w*q3.w
                    + a4.x*q4.x + a4.y*q4.y + a4.z*q4.z + a4.w*q4.w
                    + a5.x*q5.x + a5.y*q5.y + a5.z*q5.z + a5.w*q5.w
                    + a6.x*q6.x + a6.y*q6.y + a6.z*q6.z + a6.w*q6.w
                    + a7.x*q7.x + a7.y*q7.y + a7.z*q7.z + a7.w*q7.w;
            a += qhq[w][mv[s]] + khtv[s] + qhq[w][264 + evv[s]];
            a *= scale;
            if (mrow[j]) a = -INFINITY;
            sc[s] = a;
        }
        float mx = sc[0];
        #pragma unroll
        for (int s = 1; s < 8; ++s) mx = fmaxf(mx, sc[s]);
        #pragma unroll
        for (int o = 32; o > 0; o >>= 1) mx = fmaxf(mx, __shfl_xor(mx, o, 64));
        float sum = 0.f;
        #pragma unroll
        for (int s = 0; s < 8; ++s) { sc[s] = __expf(sc[s] - mx); sum += sc[s]; }
        #pragma unroll
        for (int o = 32; o > 0; o >>= 1) sum += __shfl_xor(sum, o, 64);
        float inv = 1.0f / sum;
        #pragma unroll
        for (int s = 0; s < 8; ++s) pbuf[w][l + 64*s] = sc[s] * inv;
    }

    // ---- phase D (per wave): AV + fused Vh/Ve; lane = (jc, d4) ----
    {
        int jc = l >> 3;          // 0..7
        int d4 = l & 7;           // float4 chunk 0..7
        const float* vb  = v + (size_t)bh*NN*DH + d4*4;
        const float* vhb = v_hop  + hh*DH + d4*4;
        const float* veb = v_edge + hh*DH + d4*4;
        float4 acc; acc.x = acc.y = acc.z = acc.w = 0.f;
        #pragma unroll 4
        for (int off = 0; off < 64; ++off) {
            int j = jc + 8*off;
            float wp = pbuf[w][j];
            int pk = mje[j];
            int m = pk & 0xFFFF, e = pk >> 16;
            float4 vv = *(const float4*)(vb + (size_t)j*DH);
            float4 vh = *(const float4*)(vhb + (size_t)m*DM);
            float4 ve = *(const float4*)(veb + (size_t)e*DM);
            acc.x += wp * (vv.x + vh.x + ve.x);
            acc.y += wp * (vv.y + vh.y + ve.y);
            acc.z += wp * (vv.z + vh.z + ve.z);
            acc.w += wp * (vv.w + vh.w + ve.w);
        }
        // reduce over jc (lane bits 3..5)
        #pragma unroll
        for (int o = 8; o <= 32; o <<= 1) {
            acc.x += __shfl_xor(acc.x, o, 64);
            acc.y += __shfl_xor(acc.y, o, 64);
            acc.z += __shfl_xor(acc.z, o, 64);
            acc.w += __shfl_xor(acc.w, o, 64);
        }
        if (jc == 0) {
            *(float4*)(ctx + ((size_t)b*NN + i)*DM + hh*DH + d4*4) = acc;
        }
    }
}

extern "C" void kernel_launch(void* const* d_in, const int* in_sizes, int n_in,
                              void* d_out, int out_size, void* d_ws, size_t ws_size,
                              hipStream_t stream) {
    const float* x     = (const float*)d_in[0];
    const unsigned char* mask = (const unsigned char*)d_in[1];
    const int*   dist  = (const int*)d_in[2];
    const int*   edge  = (const int*)d_in[3];
    const float* node_W = (const float*)d_in[4];
    const float* node_b = (const float*)d_in[5];
    const float* ln1_g = (const float*)d_in[6];
    const float* ln1_b = (const float*)d_in[7];
    const float* Wq = (const float*)d_in[8];
    const float* bq = (const float*)d_in[9];
    const float* Wk = (const float*)d_in[10];
    const float* bk = (const float*)d_in[11];
    const float* Wv = (const float*)d_in[12];
    const float* bv = (const float*)d_in[13];
    const float* Wo = (const float*)d_in[14];
    const float* bo = (const float*)d_in[15];
    const float* ln2_g = (const float*)d_in[16];
    const float* ln2_b = (const float*)d_in[17];
    const float* W1 = (const float*)d_in[18];
    const float* b1 = (const float*)d_in[19];
    const float* W2 = (const float*)d_in[20];
    const float* b2 = (const float*)d_in[21];
    const float* q_hop  = (const float*)d_in[22];
    const float* q_edge = (const float*)d_in[23];
    const float* k_hop  = (const float*)d_in[24];
    const float* k_edge = (const float*)d_in[25];
    const float* v_hop  = (const float*)d_in[26];
    const float* v_edge = (const float*)d_in[27];
    const float* fln_g = (const float*)d_in[28];
    const float* fln_b = (const float*)d_in[29];
    const float* out_W = (const float*)d_in[30];
    const float* out_b = (const float*)d_in[31];
    float* out = (float*)d_out;

    float* ws = (float*)d_ws;
    float* h   = ws + 0;                         //  2,097,152
    float* y   = ws + 2097152;                   //  2,097,152
    float* q   = ws + 4194304;                   //  2,097,152  [B,H,N,DH]
    float* k   = ws + 6291456;                   //  2,097,152
    float* v   = ws + 8388608;                   //  2,097,152
    float* ctx = ws + 10485760;                  //  2,097,152
    float* kht = ws + 12582912;                  // 16,908,288  [B,H,NHOP,N]
    float* ffn = kht;                            //  8,388,608  (aliases kht, dead by then)

    k_gemm<DIN, DM, 0, 0, 0><<<dim3(ROWS/16, 1), 256, 0, stream>>>(x, node_W, node_b, h);
    k_ln<<<ROWS/4, 256, 0, stream>>>(h, ln1_g, ln1_b, y);
    k_gemm<DM, DM, 0, 0, 1><<<dim3(ROWS/16, 1), 256, 0, stream>>>(y, Wq, bq, q);
    k_gemm<DM, DM, 0, 0, 1><<<dim3(ROWS/16, 1), 256, 0, stream>>>(y, Wk, bk, k);
    k_gemm<DM, DM, 0, 0, 1><<<dim3(ROWS/16, 1), 256, 0, stream>>>(y, Wv, bv, v);
    k_kht<<<BB*NH*NHOP, 256, 0, stream>>>(k, k_hop, kht);
    k_attn<<<BB*NN*2, 256, 0, stream>>>(q, k, v, kht, dist, edge, mask,
                                        q_hop, q_edge, k_edge, v_hop, v_edge, ctx);
    k_gemm<DM, DM, 0, 1, 0><<<dim3(ROWS/16, 1), 256, 0, stream>>>(ctx, Wo, bo, h);
    k_ln<<<ROWS/4, 256, 0, stream>>>(h, ln2_g, ln2_b, y);
    k_gemm<DM, FF, 1, 0, 0><<<dim3(ROWS/16, 4), 256, 0, stream>>>(y, W1, b1, ffn);
    k_gemm<FF, DM, 0, 1, 0><<<dim3(ROWS/16, 1), 256, 0, stream>>>(ffn, W2, b2, h);
    k_ln<<<ROWS/4, 256, 0, stream>>>(h, fln_g, fln_b, y);
    k_gemm<DM, DOUT, 0, 0, 0><<<dim3(ROWS/16, 1), 256, 0, stream>>>(y, out_W, out_b, out);
}

// Round 4
// 2038.556 us; speedup vs baseline: 1.4703x; 1.1448x over previous
//
#include <hip/hip_runtime.h>
#include <math.h>

#define BB 16
#define NN 512
#define DIN 128
#define DM 256
#define NH 8
#define DH 32
#define FF 1024
#define DOUT 128
#define NHOP 258
#define NEDGE 27
#define ROWS (BB*NN)   // 8192
#define QHQ_W 292      // per-wave table: qh[0..257], qec at [264..290]

// ---------------- layernorm: one wave per row, float4 + shuffle ----------------
__global__ __launch_bounds__(256) void k_ln(const float* __restrict__ in, const float* __restrict__ g,
                                            const float* __restrict__ bta, float* __restrict__ out) {
    int row = blockIdx.x * 4 + (threadIdx.x >> 6);
    int l = threadIdx.x & 63;
    float4 xv = ((const float4*)(in + (size_t)row*DM))[l];
    float s = xv.x + xv.y + xv.z + xv.w;
    #pragma unroll
    for (int o = 32; o > 0; o >>= 1) s += __shfl_xor(s, o, 64);
    float mean = s * (1.0f/DM);
    float dx = xv.x-mean, dy = xv.y-mean, dz = xv.z-mean, dw = xv.w-mean;
    float vs = dx*dx + dy*dy + dz*dz + dw*dw;
    #pragma unroll
    for (int o = 32; o > 0; o >>= 1) vs += __shfl_xor(vs, o, 64);
    float r = rsqrtf(vs * (1.0f/DM) + 1e-5f);
    float4 gg = ((const float4*)g)[l];
    float4 bb = ((const float4*)bta)[l];
    float4 ov; ov.x = dx*r*gg.x+bb.x; ov.y = dy*r*gg.y+bb.y; ov.z = dz*r*gg.z+bb.z; ov.w = dw*r*gg.w+bb.w;
    ((float4*)(out + (size_t)row*DM))[l] = ov;
}

// ---------------- tiled GEMM: 16 rows/block, 256 cols/block ----------------
template<int K, int N, int ACT, int RES, int QKV>
__global__ __launch_bounds__(256) void k_gemm(const float* __restrict__ A, const float* __restrict__ W,
                                              const float* __restrict__ bias, float* __restrict__ out) {
    constexpr int KC = (K < 256) ? K : 256;
    __shared__ __align__(16) float As[16][KC];
    int r0 = blockIdx.x * 16;
    int colbase = blockIdx.y * 256;
    int tid = threadIdx.x;
    int col = colbase + tid;
    bool active = tid < ((N < 256) ? N : 256);
    float bv = 0.f;
    if (active) bv = bias[col];
    float acc[16];
    #pragma unroll
    for (int r = 0; r < 16; ++r) acc[r] = 0.f;

    for (int kc = 0; kc < K; kc += KC) {
        for (int idx = tid*4; idx < 16*KC; idx += 1024) {
            int r = idx / KC, kk = idx % KC;
            *(float4*)&As[r][kk] = *(const float4*)&A[(size_t)(r0 + r)*K + kc + kk];
        }
        __syncthreads();
        if (active) {
            for (int kk = 0; kk < KC; kk += 4) {
                const float* wp = W + (size_t)(kc + kk)*N + col;
                float w0 = wp[0], w1 = wp[N], w2 = wp[2*N], w3 = wp[3*N];
                #pragma unroll
                for (int r = 0; r < 16; ++r) {
                    float4 a = *(const float4*)&As[r][kk];
                    acc[r] += a.x*w0 + a.y*w1 + a.z*w2 + a.w*w3;
                }
            }
        }
        __syncthreads();
    }
    if (active) {
        #pragma unroll
        for (int r = 0; r < 16; ++r) {
            float val = acc[r] + bv;
            if (ACT) val = 0.5f * val * (1.0f + erff(val * 0.70710678118654752f));
            int row = r0 + r;
            if (QKV) {
                int b = row >> 9, n = row & (NN-1);
                int hh = col >> 5, d = col & (DH-1);
                out[(size_t)((b*NH + hh)*NN + n)*DH + d] = val;
            } else if (RES) {
                out[(size_t)row*N + col] += val;
            } else {
                out[(size_t)row*N + col] = val;
            }
        }
    }
}

// ---------------- transpose bias table [M][256] -> [8][M][32] ----------------
__global__ __launch_bounds__(256) void k_tr(const float* __restrict__ in, float* __restrict__ out, int M) {
    int m = blockIdx.x, t = threadIdx.x;
    out[((size_t)(t >> 5)*M + m)*DH + (t & 31)] = in[(size_t)m*DM + t];
}

// ---------------- khT[bh,m,j] = k[bh,j,:] . Kh[h,m,:] ----------------
__global__ __launch_bounds__(256) void k_kht(const float* __restrict__ k, const float* __restrict__ k_hop,
                                             float* __restrict__ kht) {
    int bm = blockIdx.x;             // bh*NHOP + m
    int m = bm % NHOP;
    int bh = bm / NHOP;
    int hh = bh & (NH-1);
    const float4* khp = (const float4*)(k_hop + (size_t)m*DM + hh*DH);
    float4 c0 = khp[0], c1 = khp[1], c2 = khp[2], c3 = khp[3];
    float4 c4 = khp[4], c5 = khp[5], c6 = khp[6], c7 = khp[7];
    const float* kb = k + (size_t)bh*NN*DH;
    for (int j = threadIdx.x; j < NN; j += 256) {
        const float4* kj = (const float4*)(kb + j*DH);
        float4 a0 = kj[0], a1 = kj[1], a2 = kj[2], a3 = kj[3];
        float4 a4 = kj[4], a5 = kj[5], a6 = kj[6], a7 = kj[7];
        float acc = a0.x*c0.x + a0.y*c0.y + a0.z*c0.z + a0.w*c0.w
                  + a1.x*c1.x + a1.y*c1.y + a1.z*c1.z + a1.w*c1.w
                  + a2.x*c2.x + a2.y*c2.y + a2.z*c2.z + a2.w*c2.w
                  + a3.x*c3.x + a3.y*c3.y + a3.z*c3.z + a3.w*c3.w
                  + a4.x*c4.x + a4.y*c4.y + a4.z*c4.z + a4.w*c4.w
                  + a5.x*c5.x + a5.y*c5.y + a5.z*c5.z + a5.w*c5.w
                  + a6.x*c6.x + a6.y*c6.y + a6.z*c6.z + a6.w*c6.w
                  + a7.x*c7.x + a7.y*c7.y + a7.z*c7.z + a7.w*c7.w;
        kht[(size_t)bm*NN + j] = acc;
    }
}

// ---------------- fused attention: one block per (b,i); 8 waves = 8 heads ----------------
__global__ __launch_bounds__(512) void k_attn(
    const float* __restrict__ q, const float* __restrict__ k, const float* __restrict__ v,
    const float* __restrict__ kht, const int* __restrict__ dist, const int* __restrict__ edge,
    const unsigned char* __restrict__ mask,
    const float* __restrict__ Qh_t, const float* __restrict__ Qe_t, const float* __restrict__ Ke_t,
    const float* __restrict__ Vh_t, const float* __restrict__ Ve_t,
    float* __restrict__ ctx)
{
    int bi = blockIdx.x;            // b*NN + i
    int i  = bi & (NN-1);
    int b  = bi >> 9;
    int w  = threadIdx.x >> 6;      // head
    int l  = threadIdx.x & 63;
    int bh = b*NH + w;

    __shared__ int   mje[NN];          // m | (e<<16), shared by all waves (same b,i)
    __shared__ float qhq[NH][QHQ_W];   // per-wave bias tables
    __shared__ float bins[NH][QHQ_W];  // per-wave scatter bins (vha / vea)
    __shared__ float pbuf[NH][NN];     // per-wave probabilities

    // ---- phase A (block-shared): decode dist/edge row ----
    {
        int t = threadIdx.x;
        if (t < 128) {
            int4 dv = ((const int4*)(dist + ((size_t)b*NN + i)*NN))[t];
            int4 ev = ((const int4*)(edge + ((size_t)b*NN + i)*NN))[t];
            int m0 = dv.x > 256 ? 256 : dv.x; if (dv.x < 0) m0 = 257;
            int m1 = dv.y > 256 ? 256 : dv.y; if (dv.y < 0) m1 = 257;
            int m2 = dv.z > 256 ? 256 : dv.z; if (dv.z < 0) m2 = 257;
            int m3 = dv.w > 256 ? 256 : dv.w; if (dv.w < 0) m3 = 257;
            int e0 = ev.x > 25 ? 25 : ev.x; if (ev.x < 0) e0 = 26;
            int e1 = ev.y > 25 ? 25 : ev.y; if (ev.y < 0) e1 = 26;
            int e2 = ev.z > 25 ? 25 : ev.z; if (ev.z < 0) e2 = 26;
            int e3 = ev.w > 25 ? 25 : ev.w; if (ev.w < 0) e3 = 26;
            mje[t*4+0] = m0 | (e0<<16);
            mje[t*4+1] = m1 | (e1<<16);
            mje[t*4+2] = m2 | (e2<<16);
            mje[t*4+3] = m3 | (e3<<16);
        }
    }
    __syncthreads();

    // ---- phase B (per wave): zero bins; qh + qec tables via coalesced transposed reads ----
    {
        #pragma unroll
        for (int s = 0; s < 5; ++s) {
            int idx = l + 64*s;
            if (idx < QHQ_W) bins[w][idx] = 0.f;
        }
        int mg = l >> 3, d4 = l & 7;
        float4 q4 = *(const float4*)(q + ((size_t)bh*NN + i)*DH + d4*4);
        float4 k4 = *(const float4*)(k + ((size_t)bh*NN + i)*DH + d4*4);
        const float* qhb = Qh_t + (size_t)w*NHOP*DH + d4*4;
        for (int t = 0; t < 33; ++t) {
            int m = 8*t + mg;
            if (m < NHOP) {
                float4 wv = *(const float4*)(qhb + (size_t)m*DH);
                float a = q4.x*wv.x + q4.y*wv.y + q4.z*wv.z + q4.w*wv.w;
                a += __shfl_xor(a, 1, 8); a += __shfl_xor(a, 2, 8); a += __shfl_xor(a, 4, 8);
                if (d4 == 0) qhq[w][m] = a;
            }
        }
        const float* qeb = Qe_t + (size_t)w*NEDGE*DH + d4*4;
        const float* keb = Ke_t + (size_t)w*NEDGE*DH + d4*4;
        #pragma unroll
        for (int t = 0; t < 4; ++t) {
            int e = 8*t + mg;
            if (e < NEDGE) {
                float4 wv = *(const float4*)(qeb + (size_t)e*DH);
                float4 uv = *(const float4*)(keb + (size_t)e*DH);
                float a = q4.x*wv.x + q4.y*wv.y + q4.z*wv.z + q4.w*wv.w
                        + k4.x*uv.x + k4.y*uv.y + k4.z*uv.z + k4.w*uv.w;
                a += __shfl_xor(a, 1, 8); a += __shfl_xor(a, 2, 8); a += __shfl_xor(a, 4, 8);
                if (d4 == 0) qhq[w][264 + e] = a;
            }
        }
    }

    // ---- phase C (per wave): scores + softmax + scatter-bins ----
    {
        const float4* qp = (const float4*)(q + ((size_t)bh*NN + i)*DH);
        float4 q0 = qp[0], q1 = qp[1], q2 = qp[2], q3 = qp[3];
        float4 q4 = qp[4], q5 = qp[5], q6 = qp[6], q7 = qp[7];
        const float* kbase = k + (size_t)bh*NN*DH;
        const float* khtb  = kht + (size_t)bh*NHOP*NN;
        const unsigned char* mrow = mask + (size_t)b*NN;
        const float scale = 0.17677669529663687f;

        int mv[8], evv[8];
        #pragma unroll
        for (int s = 0; s < 8; ++s) {
            int pk = mje[l + 64*s];
            mv[s] = pk & 0xFFFF; evv[s] = pk >> 16;
        }
        float khtv[8];
        #pragma unroll
        for (int s = 0; s < 8; ++s) {             // 8 independent scattered gathers in flight
            khtv[s] = khtb[(size_t)mv[s]*NN + (l + 64*s)];
        }
        float sc[8];
        #pragma unroll
        for (int s = 0; s < 8; ++s) {
            int j = l + 64*s;
            const float4* kj = (const float4*)(kbase + (size_t)j*DH);
            float4 a0 = kj[0], a1 = kj[1], a2 = kj[2], a3 = kj[3];
            float4 a4 = kj[4], a5 = kj[5], a6 = kj[6], a7 = kj[7];
            float a = a0.x*q0.x + a0.y*q0.y + a0.z*q0.z + a0.w*q0.w
                    + a1.x*q1.x + a1.y*q1.y + a1.z*q1.z + a1.w*q1.w
                    + a2.x*q2.x + a2.y*q2.y + a2.z*q2.z + a2.w*q2.w
                    + a3.x*q3.x + a3.y*q3.y + a3.z*q3.z + a3.w*q3.w
                    + a4.x*q4.x + a4.y*q4.y + a4.z*q4.z + a4.w*q4.w
                    + a5.x*q5.x + a5.y*q5.y + a5.z*q5.z + a5.w*q5.w
                    + a6.x*q6.x + a6.y*q6.y + a6.z*q6.z + a6.w*q6.w
                    + a7.x*q7.x + a7.y*q7.y + a7.z*q7.z + a7.w*q7.w;
            a += qhq[w][mv[s]] + khtv[s] + qhq[w][264 + evv[s]];
            a *= scale;
            if (mrow[j]) a = -INFINITY;
            sc[s] = a;
        }
        float mx = sc[0];
        #pragma unroll
        for (int s = 1; s < 8; ++s) mx = fmaxf(mx, sc[s]);
        #pragma unroll
        for (int o = 32; o > 0; o >>= 1) mx = fmaxf(mx, __shfl_xor(mx, o, 64));
        float sum = 0.f;
        #pragma unroll
        for (int s = 0; s < 8; ++s) { sc[s] = __expf(sc[s] - mx); sum += sc[s]; }
        #pragma unroll
        for (int o = 32; o > 0; o >>= 1) sum += __shfl_xor(sum, o, 64);
        float inv = 1.0f / sum;
        #pragma unroll
        for (int s = 0; s < 8; ++s) {
            float ps = sc[s] * inv;
            pbuf[w][l + 64*s] = ps;
            atomicAdd(&bins[w][mv[s]], ps);
            atomicAdd(&bins[w][264 + evv[s]], ps);
        }
    }

    // ---- phase D (per wave): dense AV + bin reductions; lane = (jc, d4) ----
    {
        int jc = l >> 3;          // 0..7
        int d4 = l & 7;           // float4 chunk 0..7
        const float* vb = v + (size_t)bh*NN*DH + d4*4;
        float4 acc; acc.x = acc.y = acc.z = acc.w = 0.f;
        #pragma unroll 4
        for (int off = 0; off < 64; ++off) {
            int j = 8*off + jc;
            float wp = pbuf[w][j];
            float4 vv = *(const float4*)(vb + (size_t)j*DH);
            acc.x += wp * vv.x; acc.y += wp * vv.y;
            acc.z += wp * vv.z; acc.w += wp * vv.w;
        }
        const float* vhb = Vh_t + (size_t)w*NHOP*DH + d4*4;
        for (int t = 0; t < 33; ++t) {
            int m = 8*t + jc;
            if (m < NHOP) {
                float bw = bins[w][m];
                float4 vv = *(const float4*)(vhb + (size_t)m*DH);
                acc.x += bw * vv.x; acc.y += bw * vv.y;
                acc.z += bw * vv.z; acc.w += bw * vv.w;
            }
        }
        const float* veb = Ve_t + (size_t)w*NEDGE*DH + d4*4;
        #pragma unroll
        for (int t = 0; t < 4; ++t) {
            int e = 8*t + jc;
            if (e < NEDGE) {
                float bw = bins[w][264 + e];
                float4 vv = *(const float4*)(veb + (size_t)e*DH);
                acc.x += bw * vv.x; acc.y += bw * vv.y;
                acc.z += bw * vv.z; acc.w += bw * vv.w;
            }
        }
        #pragma unroll
        for (int o = 8; o <= 32; o <<= 1) {
            acc.x += __shfl_xor(acc.x, o, 64);
            acc.y += __shfl_xor(acc.y, o, 64);
            acc.z += __shfl_xor(acc.z, o, 64);
            acc.w += __shfl_xor(acc.w, o, 64);
        }
        if (jc == 0) {
            *(float4*)(ctx + ((size_t)b*NN + i)*DM + w*DH + d4*4) = acc;
        }
    }
}

extern "C" void kernel_launch(void* const* d_in, const int* in_sizes, int n_in,
                              void* d_out, int out_size, void* d_ws, size_t ws_size,
                              hipStream_t stream) {
    const float* x     = (const float*)d_in[0];
    const unsigned char* mask = (const unsigned char*)d_in[1];
    const int*   dist  = (const int*)d_in[2];
    const int*   edge  = (const int*)d_in[3];
    const float* node_W = (const float*)d_in[4];
    const float* node_b = (const float*)d_in[5];
    const float* ln1_g = (const float*)d_in[6];
    const float* ln1_b = (const float*)d_in[7];
    const float* Wq = (const float*)d_in[8];
    const float* bq = (const float*)d_in[9];
    const float* Wk = (const float*)d_in[10];
    const float* bk = (const float*)d_in[11];
    const float* Wv = (const float*)d_in[12];
    const float* bv = (const float*)d_in[13];
    const float* Wo = (const float*)d_in[14];
    const float* bo = (const float*)d_in[15];
    const float* ln2_g = (const float*)d_in[16];
    const float* ln2_b = (const float*)d_in[17];
    const float* W1 = (const float*)d_in[18];
    const float* b1 = (const float*)d_in[19];
    const float* W2 = (const float*)d_in[20];
    const float* b2 = (const float*)d_in[21];
    const float* q_hop  = (const float*)d_in[22];
    const float* q_edge = (const float*)d_in[23];
    const float* k_hop  = (const float*)d_in[24];
    const float* k_edge = (const float*)d_in[25];
    const float* v_hop  = (const float*)d_in[26];
    const float* v_edge = (const float*)d_in[27];
    const float* fln_g = (const float*)d_in[28];
    const float* fln_b = (const float*)d_in[29];
    const float* out_W = (const float*)d_in[30];
    const float* out_b = (const float*)d_in[31];
    float* out = (float*)d_out;

    float* ws = (float*)d_ws;
    float* h   = ws + 0;                         //  2,097,152
    float* y   = ws + 2097152;                   //  2,097,152
    float* q   = ws + 4194304;                   //  2,097,152  [B,H,N,DH]
    float* k   = ws + 6291456;                   //  2,097,152
    float* v   = ws + 8388608;                   //  2,097,152
    float* ctx = ws + 10485760;                  //  2,097,152
    float* kht = ws + 12582912;                  // 16,908,288  [B,H,NHOP,N]
    float* ffn = kht;                            //  8,388,608  (aliases kht, dead by then)
    // transposed bias tables alias y (y is dead between qkv-projection and ln2)
    float* Qh_t = y + 0;                         // 8*258*32 = 66,048
    float* Vh_t = y + 66048;                     // 66,048
    float* Qe_t = y + 132096;                    // 8*27*32 = 6,912
    float* Ke_t = y + 139008;                    // 6,912
    float* Ve_t = y + 145920;                    // 6,912

    k_gemm<DIN, DM, 0, 0, 0><<<dim3(ROWS/16, 1), 256, 0, stream>>>(x, node_W, node_b, h);
    k_ln<<<ROWS/4, 256, 0, stream>>>(h, ln1_g, ln1_b, y);
    k_gemm<DM, DM, 0, 0, 1><<<dim3(ROWS/16, 1), 256, 0, stream>>>(y, Wq, bq, q);
    k_gemm<DM, DM, 0, 0, 1><<<dim3(ROWS/16, 1), 256, 0, stream>>>(y, Wk, bk, k);
    k_gemm<DM, DM, 0, 0, 1><<<dim3(ROWS/16, 1), 256, 0, stream>>>(y, Wv, bv, v);
    // y is now dead -> stash transposed tables there
    k_tr<<<NHOP, 256, 0, stream>>>(q_hop, Qh_t, NHOP);
    k_tr<<<NHOP, 256, 0, stream>>>(v_hop, Vh_t, NHOP);
    k_tr<<<NEDGE, 256, 0, stream>>>(q_edge, Qe_t, NEDGE);
    k_tr<<<NEDGE, 256, 0, stream>>>(k_edge, Ke_t, NEDGE);
    k_tr<<<NEDGE, 256, 0, stream>>>(v_edge, Ve_t, NEDGE);
    k_kht<<<BB*NH*NHOP, 256, 0, stream>>>(k, k_hop, kht);
    k_attn<<<BB*NN, 512, 0, stream>>>(q, k, v, kht, dist, edge, mask,
                                      Qh_t, Qe_t, Ke_t, Vh_t, Ve_t, ctx);
    k_gemm<DM, DM, 0, 1, 0><<<dim3(ROWS/16, 1), 256, 0, stream>>>(ctx, Wo, bo, h);
    k_ln<<<ROWS/4, 256, 0, stream>>>(h, ln2_g, ln2_b, y);
    k_gemm<DM, FF, 1, 0, 0><<<dim3(ROWS/16, 4), 256, 0, stream>>>(y, W1, b1, ffn);
    k_gemm<FF, DM, 0, 1, 0><<<dim3(ROWS/16, 1), 256, 0, stream>>>(ffn, W2, b2, h);
    k_ln<<<ROWS/4, 256, 0, stream>>>(h, fln_g, fln_b, y);
    k_gemm<DM, DOUT, 0, 0, 0><<<dim3(ROWS/16, 1), 256, 0, stream>>>(y, out_W, out_b, out);
}

// Round 5
// 2031.940 us; speedup vs baseline: 1.4751x; 1.0033x over previous
//
#include <hip/hip_runtime.h>
#include <hip/hip_bf16.h>
#include <math.h>

#define BB 16
#define NN 512
#define DIN 128
#define DM 256
#define NH 8
#define DH 32
#define FF 1024
#define DOUT 128
#define NHOP 258
#define NEDGE 27
#define ROWS (BB*NN)   // 8192
#define QHQ_W 292      // per-wave table: qh[0..257], qec at [264..290]

// ---------------- layernorm: one wave per row, float4 + shuffle ----------------
__global__ __launch_bounds__(256) void k_ln(const float* __restrict__ in, const float* __restrict__ g,
                                            const float* __restrict__ bta, float* __restrict__ out) {
    int row = blockIdx.x * 4 + (threadIdx.x >> 6);
    int l = threadIdx.x & 63;
    float4 xv = ((const float4*)(in + (size_t)row*DM))[l];
    float s = xv.x + xv.y + xv.z + xv.w;
    #pragma unroll
    for (int o = 32; o > 0; o >>= 1) s += __shfl_xor(s, o, 64);
    float mean = s * (1.0f/DM);
    float dx = xv.x-mean, dy = xv.y-mean, dz = xv.z-mean, dw = xv.w-mean;
    float vs = dx*dx + dy*dy + dz*dz + dw*dw;
    #pragma unroll
    for (int o = 32; o > 0; o >>= 1) vs += __shfl_xor(vs, o, 64);
    float r = rsqrtf(vs * (1.0f/DM) + 1e-5f);
    float4 gg = ((const float4*)g)[l];
    float4 bb = ((const float4*)bta)[l];
    float4 ov; ov.x = dx*r*gg.x+bb.x; ov.y = dy*r*gg.y+bb.y; ov.z = dz*r*gg.z+bb.z; ov.w = dw*r*gg.w+bb.w;
    ((float4*)(out + (size_t)row*DM))[l] = ov;
}

// ---------------- tiled GEMM: 16 rows/block, 256 cols/block ----------------
template<int K, int N, int ACT, int RES, int QKV>
__global__ __launch_bounds__(256) void k_gemm(const float* __restrict__ A, const float* __restrict__ W,
                                              const float* __restrict__ bias, float* __restrict__ out) {
    constexpr int KC = (K < 256) ? K : 256;
    __shared__ __align__(16) float As[16][KC];
    int r0 = blockIdx.x * 16;
    int colbase = blockIdx.y * 256;
    int tid = threadIdx.x;
    int col = colbase + tid;
    bool active = tid < ((N < 256) ? N : 256);
    float bv = 0.f;
    if (active) bv = bias[col];
    float acc[16];
    #pragma unroll
    for (int r = 0; r < 16; ++r) acc[r] = 0.f;

    for (int kc = 0; kc < K; kc += KC) {
        for (int idx = tid*4; idx < 16*KC; idx += 1024) {
            int r = idx / KC, kk = idx % KC;
            *(float4*)&As[r][kk] = *(const float4*)&A[(size_t)(r0 + r)*K + kc + kk];
        }
        __syncthreads();
        if (active) {
            for (int kk = 0; kk < KC; kk += 4) {
                const float* wp = W + (size_t)(kc + kk)*N + col;
                float w0 = wp[0], w1 = wp[N], w2 = wp[2*N], w3 = wp[3*N];
                #pragma unroll
                for (int r = 0; r < 16; ++r) {
                    float4 a = *(const float4*)&As[r][kk];
                    acc[r] += a.x*w0 + a.y*w1 + a.z*w2 + a.w*w3;
                }
            }
        }
        __syncthreads();
    }
    if (active) {
        #pragma unroll
        for (int r = 0; r < 16; ++r) {
            float val = acc[r] + bv;
            if (ACT) val = 0.5f * val * (1.0f + erff(val * 0.70710678118654752f));
            int row = r0 + r;
            if (QKV) {
                int b = row >> 9, n = row & (NN-1);
                int hh = col >> 5, d = col & (DH-1);
                out[(size_t)((b*NH + hh)*NN + n)*DH + d] = val;
            } else if (RES) {
                out[(size_t)row*N + col] += val;
            } else {
                out[(size_t)row*N + col] = val;
            }
        }
    }
}

// ---------------- transpose bias table [M][256] -> [8][M][32] ----------------
__global__ __launch_bounds__(256) void k_tr(const float* __restrict__ in, float* __restrict__ out, int M) {
    int m = blockIdx.x, t = threadIdx.x;
    out[((size_t)(t >> 5)*M + m)*DH + (t & 31)] = in[(size_t)m*DM + t];
}

// ---------------- khT[bh,m,j] = k[bh,j,:] . Kh[h,m,:]  (stored bf16) ----------------
__global__ __launch_bounds__(256) void k_kht(const float* __restrict__ k, const float* __restrict__ k_hop,
                                             __hip_bfloat16* __restrict__ kht) {
    int bm = blockIdx.x;             // bh*NHOP + m
    int m = bm % NHOP;
    int bh = bm / NHOP;
    int hh = bh & (NH-1);
    const float4* khp = (const float4*)(k_hop + (size_t)m*DM + hh*DH);
    float4 c0 = khp[0], c1 = khp[1], c2 = khp[2], c3 = khp[3];
    float4 c4 = khp[4], c5 = khp[5], c6 = khp[6], c7 = khp[7];
    const float* kb = k + (size_t)bh*NN*DH;
    for (int j = threadIdx.x; j < NN; j += 256) {
        const float4* kj = (const float4*)(kb + j*DH);
        float4 a0 = kj[0], a1 = kj[1], a2 = kj[2], a3 = kj[3];
        float4 a4 = kj[4], a5 = kj[5], a6 = kj[6], a7 = kj[7];
        float acc = a0.x*c0.x + a0.y*c0.y + a0.z*c0.z + a0.w*c0.w
                  + a1.x*c1.x + a1.y*c1.y + a1.z*c1.z + a1.w*c1.w
                  + a2.x*c2.x + a2.y*c2.y + a2.z*c2.z + a2.w*c2.w
                  + a3.x*c3.x + a3.y*c3.y + a3.z*c3.z + a3.w*c3.w
                  + a4.x*c4.x + a4.y*c4.y + a4.z*c4.z + a4.w*c4.w
                  + a5.x*c5.x + a5.y*c5.y + a5.z*c5.z + a5.w*c5.w
                  + a6.x*c6.x + a6.y*c6.y + a6.z*c6.z + a6.w*c6.w
                  + a7.x*c7.x + a7.y*c7.y + a7.z*c7.z + a7.w*c7.w;
        kht[(size_t)bm*NN + j] = __float2bfloat16(acc);
    }
}

// ---------------- fused attention: one block per (b,i); 8 waves = 8 heads ----------------
// Grid swizzled so all blocks of one b land on one XCD (kht L2 residency).
__global__ __launch_bounds__(512) void k_attn(
    const float* __restrict__ q, const float* __restrict__ k, const float* __restrict__ v,
    const __hip_bfloat16* __restrict__ kht, const int* __restrict__ dist, const int* __restrict__ edge,
    const unsigned char* __restrict__ mask,
    const float* __restrict__ Qh_t, const float* __restrict__ Qe_t, const float* __restrict__ Ke_t,
    const float* __restrict__ Vh_t, const float* __restrict__ Ve_t,
    float* __restrict__ ctx)
{
    // XCD-affine decode: xcd = g&7 gets b = xcd (first half) / xcd+8 (second half)
    int g  = blockIdx.x;
    int r  = g >> 3;
    int b  = (g & 7) + ((r >> 9) << 3);
    int i  = r & (NN-1);
    int w  = threadIdx.x >> 6;      // head
    int l  = threadIdx.x & 63;
    int bh = b*NH + w;

    __shared__ int   mje[NN];          // m | (e<<16), shared by all waves (same b,i)
    __shared__ float qhq[NH][QHQ_W];   // per-wave bias tables
    __shared__ float bins[NH][QHQ_W];  // per-wave scatter bins (vha / vea)
    __shared__ float pbuf[NH][NN];     // per-wave probabilities

    // ---- phase A (block-shared): decode dist/edge row ----
    {
        int t = threadIdx.x;
        if (t < 128) {
            int4 dv = ((const int4*)(dist + ((size_t)b*NN + i)*NN))[t];
            int4 ev = ((const int4*)(edge + ((size_t)b*NN + i)*NN))[t];
            int m0 = dv.x > 256 ? 256 : dv.x; if (dv.x < 0) m0 = 257;
            int m1 = dv.y > 256 ? 256 : dv.y; if (dv.y < 0) m1 = 257;
            int m2 = dv.z > 256 ? 256 : dv.z; if (dv.z < 0) m2 = 257;
            int m3 = dv.w > 256 ? 256 : dv.w; if (dv.w < 0) m3 = 257;
            int e0 = ev.x > 25 ? 25 : ev.x; if (ev.x < 0) e0 = 26;
            int e1 = ev.y > 25 ? 25 : ev.y; if (ev.y < 0) e1 = 26;
            int e2 = ev.z > 25 ? 25 : ev.z; if (ev.z < 0) e2 = 26;
            int e3 = ev.w > 25 ? 25 : ev.w; if (ev.w < 0) e3 = 26;
            mje[t*4+0] = m0 | (e0<<16);
            mje[t*4+1] = m1 | (e1<<16);
            mje[t*4+2] = m2 | (e2<<16);
            mje[t*4+3] = m3 | (e3<<16);
        }
    }
    __syncthreads();

    // ---- phase B (per wave): zero bins; qh + qec tables via coalesced transposed reads ----
    {
        #pragma unroll
        for (int s = 0; s < 5; ++s) {
            int idx = l + 64*s;
            if (idx < QHQ_W) bins[w][idx] = 0.f;
        }
        int mg = l >> 3, d4 = l & 7;
        float4 q4 = *(const float4*)(q + ((size_t)bh*NN + i)*DH + d4*4);
        float4 k4 = *(const float4*)(k + ((size_t)bh*NN + i)*DH + d4*4);
        const float* qhb = Qh_t + (size_t)w*NHOP*DH + d4*4;
        for (int t = 0; t < 33; ++t) {
            int m = 8*t + mg;
            if (m < NHOP) {
                float4 wv = *(const float4*)(qhb + (size_t)m*DH);
                float a = q4.x*wv.x + q4.y*wv.y + q4.z*wv.z + q4.w*wv.w;
                a += __shfl_xor(a, 1, 8); a += __shfl_xor(a, 2, 8); a += __shfl_xor(a, 4, 8);
                if (d4 == 0) qhq[w][m] = a;
            }
        }
        const float* qeb = Qe_t + (size_t)w*NEDGE*DH + d4*4;
        const float* keb = Ke_t + (size_t)w*NEDGE*DH + d4*4;
        #pragma unroll
        for (int t = 0; t < 4; ++t) {
            int e = 8*t + mg;
            if (e < NEDGE) {
                float4 wv = *(const float4*)(qeb + (size_t)e*DH);
                float4 uv = *(const float4*)(keb + (size_t)e*DH);
                float a = q4.x*wv.x + q4.y*wv.y + q4.z*wv.z + q4.w*wv.w
                        + k4.x*uv.x + k4.y*uv.y + k4.z*uv.z + k4.w*uv.w;
                a += __shfl_xor(a, 1, 8); a += __shfl_xor(a, 2, 8); a += __shfl_xor(a, 4, 8);
                if (d4 == 0) qhq[w][264 + e] = a;
            }
        }
    }

    // ---- phase C (per wave): scores + softmax + scatter-bins ----
    {
        const float4* qp = (const float4*)(q + ((size_t)bh*NN + i)*DH);
        float4 q0 = qp[0], q1 = qp[1], q2 = qp[2], q3 = qp[3];
        float4 q4 = qp[4], q5 = qp[5], q6 = qp[6], q7 = qp[7];
        const float* kbase = k + (size_t)bh*NN*DH;
        const __hip_bfloat16* khtb = kht + (size_t)bh*NHOP*NN;
        const unsigned char* mrow = mask + (size_t)b*NN;
        const float scale = 0.17677669529663687f;

        int mv[8], evv[8];
        #pragma unroll
        for (int s = 0; s < 8; ++s) {
            int pk = mje[l + 64*s];
            mv[s] = pk & 0xFFFF; evv[s] = pk >> 16;
        }
        __hip_bfloat16 raw[8];
        #pragma unroll
        for (int s = 0; s < 8; ++s) {             // 8 independent scattered gathers in flight
            raw[s] = khtb[(size_t)mv[s]*NN + (l + 64*s)];
        }
        float sc[8];
        #pragma unroll
        for (int s = 0; s < 8; ++s) {
            int j = l + 64*s;
            const float4* kj = (const float4*)(kbase + (size_t)j*DH);
            float4 a0 = kj[0], a1 = kj[1], a2 = kj[2], a3 = kj[3];
            float4 a4 = kj[4], a5 = kj[5], a6 = kj[6], a7 = kj[7];
            float a = a0.x*q0.x + a0.y*q0.y + a0.z*q0.z + a0.w*q0.w
                    + a1.x*q1.x + a1.y*q1.y + a1.z*q1.z + a1.w*q1.w
                    + a2.x*q2.x + a2.y*q2.y + a2.z*q2.z + a2.w*q2.w
                    + a3.x*q3.x + a3.y*q3.y + a3.z*q3.z + a3.w*q3.w
                    + a4.x*q4.x + a4.y*q4.y + a4.z*q4.z + a4.w*q4.w
                    + a5.x*q5.x + a5.y*q5.y + a5.z*q5.z + a5.w*q5.w
                    + a6.x*q6.x + a6.y*q6.y + a6.z*q6.z + a6.w*q6.w
                    + a7.x*q7.x + a7.y*q7.y + a7.z*q7.z + a7.w*q7.w;
            a += qhq[w][mv[s]] + __bfloat162float(raw[s]) + qhq[w][264 + evv[s]];
            a *= scale;
            if (mrow[j]) a = -INFINITY;
            sc[s] = a;
        }
        float mx = sc[0];
        #pragma unroll
        for (int s = 1; s < 8; ++s) mx = fmaxf(mx, sc[s]);
        #pragma unroll
        for (int o = 32; o > 0; o >>= 1) mx = fmaxf(mx, __shfl_xor(mx, o, 64));
        float sum = 0.f;
        #pragma unroll
        for (int s = 0; s < 8; ++s) { sc[s] = __expf(sc[s] - mx); sum += sc[s]; }
        #pragma unroll
        for (int o = 32; o > 0; o >>= 1) sum += __shfl_xor(sum, o, 64);
        float inv = 1.0f / sum;
        #pragma unroll
        for (int s = 0; s < 8; ++s) {
            float ps = sc[s] * inv;
            pbuf[w][l + 64*s] = ps;
            atomicAdd(&bins[w][mv[s]], ps);
            atomicAdd(&bins[w][264 + evv[s]], ps);
        }
    }

    // ---- phase D (per wave): dense AV + bin reductions; lane = (jc, d4) ----
    {
        int jc = l >> 3;          // 0..7
        int d4 = l & 7;           // float4 chunk 0..7
        const float* vb = v + (size_t)bh*NN*DH + d4*4;
        float4 acc; acc.x = acc.y = acc.z = acc.w = 0.f;
        #pragma unroll 4
        for (int off = 0; off < 64; ++off) {
            int j = 8*off + jc;
            float wp = pbuf[w][j];
            float4 vv = *(const float4*)(vb + (size_t)j*DH);
            acc.x += wp * vv.x; acc.y += wp * vv.y;
            acc.z += wp * vv.z; acc.w += wp * vv.w;
        }
        const float* vhb = Vh_t + (size_t)w*NHOP*DH + d4*4;
        for (int t = 0; t < 33; ++t) {
            int m = 8*t + jc;
            if (m < NHOP) {
                float bw = bins[w][m];
                float4 vv = *(const float4*)(vhb + (size_t)m*DH);
                acc.x += bw * vv.x; acc.y += bw * vv.y;
                acc.z += bw * vv.z; acc.w += bw * vv.w;
            }
        }
        const float* veb = Ve_t + (size_t)w*NEDGE*DH + d4*4;
        #pragma unroll
        for (int t = 0; t < 4; ++t) {
            int e = 8*t + jc;
            if (e < NEDGE) {
                float bw = bins[w][264 + e];
                float4 vv = *(const float4*)(veb + (size_t)e*DH);
                acc.x += bw * vv.x; acc.y += bw * vv.y;
                acc.z += bw * vv.z; acc.w += bw * vv.w;
            }
        }
        #pragma unroll
        for (int o = 8; o <= 32; o <<= 1) {
            acc.x += __shfl_xor(acc.x, o, 64);
            acc.y += __shfl_xor(acc.y, o, 64);
            acc.z += __shfl_xor(acc.z, o, 64);
            acc.w += __shfl_xor(acc.w, o, 64);
        }
        if (jc == 0) {
            *(float4*)(ctx + ((size_t)b*NN + i)*DM + w*DH + d4*4) = acc;
        }
    }
}

extern "C" void kernel_launch(void* const* d_in, const int* in_sizes, int n_in,
                              void* d_out, int out_size, void* d_ws, size_t ws_size,
                              hipStream_t stream) {
    const float* x     = (const float*)d_in[0];
    const unsigned char* mask = (const unsigned char*)d_in[1];
    const int*   dist  = (const int*)d_in[2];
    const int*   edge  = (const int*)d_in[3];
    const float* node_W = (const float*)d_in[4];
    const float* node_b = (const float*)d_in[5];
    const float* ln1_g = (const float*)d_in[6];
    const float* ln1_b = (const float*)d_in[7];
    const float* Wq = (const float*)d_in[8];
    const float* bq = (const float*)d_in[9];
    const float* Wk = (const float*)d_in[10];
    const float* bk = (const float*)d_in[11];
    const float* Wv = (const float*)d_in[12];
    const float* bv = (const float*)d_in[13];
    const float* Wo = (const float*)d_in[14];
    const float* bo = (const float*)d_in[15];
    const float* ln2_g = (const float*)d_in[16];
    const float* ln2_b = (const float*)d_in[17];
    const float* W1 = (const float*)d_in[18];
    const float* b1 = (const float*)d_in[19];
    const float* W2 = (const float*)d_in[20];
    const float* b2 = (const float*)d_in[21];
    const float* q_hop  = (const float*)d_in[22];
    const float* q_edge = (const float*)d_in[23];
    const float* k_hop  = (const float*)d_in[24];
    const float* k_edge = (const float*)d_in[25];
    const float* v_hop  = (const float*)d_in[26];
    const float* v_edge = (const float*)d_in[27];
    const float* fln_g = (const float*)d_in[28];
    const float* fln_b = (const float*)d_in[29];
    const float* out_W = (const float*)d_in[30];
    const float* out_b = (const float*)d_in[31];
    float* out = (float*)d_out;

    float* ws = (float*)d_ws;
    float* h   = ws + 0;                         //  2,097,152
    float* y   = ws + 2097152;                   //  2,097,152
    float* q   = ws + 4194304;                   //  2,097,152  [B,H,N,DH]
    float* k   = ws + 6291456;                   //  2,097,152
    float* v   = ws + 8388608;                   //  2,097,152
    float* ctx = ws + 10485760;                  //  2,097,152
    __hip_bfloat16* kht = (__hip_bfloat16*)(ws + 12582912);  // 16,908,288 bf16 = 33.8 MB
    float* ffn = ws + 12582912;                  //  8,388,608 floats (aliases kht, dead by then)
    // transposed bias tables alias y (y is dead between qkv-projection and ln2)
    float* Qh_t = y + 0;                         // 8*258*32 = 66,048
    float* Vh_t = y + 66048;                     // 66,048
    float* Qe_t = y + 132096;                    // 8*27*32 = 6,912
    float* Ke_t = y + 139008;                    // 6,912
    float* Ve_t = y + 145920;                    // 6,912

    k_gemm<DIN, DM, 0, 0, 0><<<dim3(ROWS/16, 1), 256, 0, stream>>>(x, node_W, node_b, h);
    k_ln<<<ROWS/4, 256, 0, stream>>>(h, ln1_g, ln1_b, y);
    k_gemm<DM, DM, 0, 0, 1><<<dim3(ROWS/16, 1), 256, 0, stream>>>(y, Wq, bq, q);
    k_gemm<DM, DM, 0, 0, 1><<<dim3(ROWS/16, 1), 256, 0, stream>>>(y, Wk, bk, k);
    k_gemm<DM, DM, 0, 0, 1><<<dim3(ROWS/16, 1), 256, 0, stream>>>(y, Wv, bv, v);
    // y is now dead -> stash transposed tables there
    k_tr<<<NHOP, 256, 0, stream>>>(q_hop, Qh_t, NHOP);
    k_tr<<<NHOP, 256, 0, stream>>>(v_hop, Vh_t, NHOP);
    k_tr<<<NEDGE, 256, 0, stream>>>(q_edge, Qe_t, NEDGE);
    k_tr<<<NEDGE, 256, 0, stream>>>(k_edge, Ke_t, NEDGE);
    k_tr<<<NEDGE, 256, 0, stream>>>(v_edge, Ve_t, NEDGE);
    k_kht<<<BB*NH*NHOP, 256, 0, stream>>>(k, k_hop, kht);
    k_attn<<<BB*NN, 512, 0, stream>>>(q, k, v, kht, dist, edge, mask,
                                      Qh_t, Qe_t, Ke_t, Vh_t, Ve_t, ctx);
    k_gemm<DM, DM, 0, 1, 0><<<dim3(ROWS/16, 1), 256, 0, stream>>>(ctx, Wo, bo, h);
    k_ln<<<ROWS/4, 256, 0, stream>>>(h, ln2_g, ln2_b, y);
    k_gemm<DM, FF, 1, 0, 0><<<dim3(ROWS/16, 4), 256, 0, stream>>>(y, W1, b1, ffn);
    k_gemm<FF, DM, 0, 1, 0><<<dim3(ROWS/16, 1), 256, 0, stream>>>(ffn, W2, b2, h);
    k_ln<<<ROWS/4, 256, 0, stream>>>(h, fln_g, fln_b, y);
    k_gemm<DM, DOUT, 0, 0, 0><<<dim3(ROWS/16, 1), 256, 0, stream>>>(y, out_W, out_b, out);
}

// Round 6
// 1353.891 us; speedup vs baseline: 2.2138x; 1.5008x over previous
//
#include <hip/hip_runtime.h>
#include <hip/hip_bf16.h>
#include <math.h>

#define BB 16
#define NN 512
#define DIN 128
#define DM 256
#define NH 8
#define DH 32
#define FF 1024
#define DOUT 128
#define NHOP 258
#define NEDGE 27
#define ROWS (BB*NN)   // 8192
#define QHQ_W 292      // per-wave table: qh[0..257], qec at [264..290]

// ---------------- layernorm: one wave per row, float4 + shuffle ----------------
__global__ __launch_bounds__(256) void k_ln(const float* __restrict__ in, const float* __restrict__ g,
                                            const float* __restrict__ bta, float* __restrict__ out) {
    int row = blockIdx.x * 4 + (threadIdx.x >> 6);
    int l = threadIdx.x & 63;
    float4 xv = ((const float4*)(in + (size_t)row*DM))[l];
    float s = xv.x + xv.y + xv.z + xv.w;
    #pragma unroll
    for (int o = 32; o > 0; o >>= 1) s += __shfl_xor(s, o, 64);
    float mean = s * (1.0f/DM);
    float dx = xv.x-mean, dy = xv.y-mean, dz = xv.z-mean, dw = xv.w-mean;
    float vs = dx*dx + dy*dy + dz*dz + dw*dw;
    #pragma unroll
    for (int o = 32; o > 0; o >>= 1) vs += __shfl_xor(vs, o, 64);
    float r = rsqrtf(vs * (1.0f/DM) + 1e-5f);
    float4 gg = ((const float4*)g)[l];
    float4 bb = ((const float4*)bta)[l];
    float4 ov; ov.x = dx*r*gg.x+bb.x; ov.y = dy*r*gg.y+bb.y; ov.z = dz*r*gg.z+bb.z; ov.w = dw*r*gg.w+bb.w;
    ((float4*)(out + (size_t)row*DM))[l] = ov;
}

// ---------------- tiled GEMM: 16 rows/block, 256 cols/block ----------------
template<int K, int N, int ACT, int RES, int QKV>
__global__ __launch_bounds__(256) void k_gemm(const float* __restrict__ A, const float* __restrict__ W,
                                              const float* __restrict__ bias, float* __restrict__ out) {
    constexpr int KC = (K < 256) ? K : 256;
    __shared__ __align__(16) float As[16][KC];
    int r0 = blockIdx.x * 16;
    int colbase = blockIdx.y * 256;
    int tid = threadIdx.x;
    int col = colbase + tid;
    bool active = tid < ((N < 256) ? N : 256);
    float bv = 0.f;
    if (active) bv = bias[col];
    float acc[16];
    #pragma unroll
    for (int r = 0; r < 16; ++r) acc[r] = 0.f;

    for (int kc = 0; kc < K; kc += KC) {
        for (int idx = tid*4; idx < 16*KC; idx += 1024) {
            int r = idx / KC, kk = idx % KC;
            *(float4*)&As[r][kk] = *(const float4*)&A[(size_t)(r0 + r)*K + kc + kk];
        }
        __syncthreads();
        if (active) {
            for (int kk = 0; kk < KC; kk += 4) {
                const float* wp = W + (size_t)(kc + kk)*N + col;
                float w0 = wp[0], w1 = wp[N], w2 = wp[2*N], w3 = wp[3*N];
                #pragma unroll
                for (int r = 0; r < 16; ++r) {
                    float4 a = *(const float4*)&As[r][kk];
                    acc[r] += a.x*w0 + a.y*w1 + a.z*w2 + a.w*w3;
                }
            }
        }
        __syncthreads();
    }
    if (active) {
        #pragma unroll
        for (int r = 0; r < 16; ++r) {
            float val = acc[r] + bv;
            if (ACT) val = 0.5f * val * (1.0f + erff(val * 0.70710678118654752f));
            int row = r0 + r;
            if (QKV) {
                int b = row >> 9, n = row & (NN-1);
                int hh = col >> 5, d = col & (DH-1);
                out[(size_t)((b*NH + hh)*NN + n)*DH + d] = val;
            } else if (RES) {
                out[(size_t)row*N + col] += val;
            } else {
                out[(size_t)row*N + col] = val;
            }
        }
    }
}

// ---------------- transpose bias table [M][256] -> [8][M][32] ----------------
__global__ __launch_bounds__(256) void k_tr(const float* __restrict__ in, float* __restrict__ out, int M) {
    int m = blockIdx.x, t = threadIdx.x;
    out[((size_t)(t >> 5)*M + m)*DH + (t & 31)] = in[(size_t)m*DM + t];
}

// ---------------- k [bh][j][d] -> kT [bh][d][j] (64-j tile per block) ----------------
__global__ __launch_bounds__(256) void k_tx(const float* __restrict__ k, float* __restrict__ kT) {
    __shared__ float lds[64*33];
    int bh = blockIdx.x;
    int j0 = blockIdx.y * 64;
    int tid = threadIdx.x;
    {
        int jj = tid >> 2, d8 = tid & 3;           // 4 threads/row, 8 floats each
        const float* src = k + ((size_t)bh*NN + j0 + jj)*DH + d8*8;
        float4 a = *(const float4*)(src);
        float4 b = *(const float4*)(src + 4);
        float* dst = lds + jj*33 + d8*8;
        dst[0]=a.x; dst[1]=a.y; dst[2]=a.z; dst[3]=a.w;
        dst[4]=b.x; dst[5]=b.y; dst[6]=b.z; dst[7]=b.w;
    }
    __syncthreads();
    {
        int d = tid >> 3, jg = tid & 7;            // 8 threads/d-row, 8 j each
        float* dst = kT + ((size_t)bh*DH + d)*NN + j0;
        #pragma unroll
        for (int jj2 = 0; jj2 < 8; ++jj2) {
            int j = jg*8 + jj2;
            dst[j] = lds[j*33 + d];
        }
    }
}

// ---------------- khT[bh,m,j] = sum_d kT[bh,d,j] * Kh[h,m,d]  (stored bf16) ----------------
__global__ __launch_bounds__(256) void k_kht(const float* __restrict__ kT, const float* __restrict__ k_hop,
                                             __hip_bfloat16* __restrict__ kht) {
    int bm = blockIdx.x;             // bh*NHOP + m
    int m = bm % NHOP;
    int bh = bm / NHOP;
    int hh = bh & (NH-1);
    float kh[32];
    {
        const float4* khp = (const float4*)(k_hop + (size_t)m*DM + hh*DH);
        #pragma unroll
        for (int c = 0; c < 8; ++c) *(float4*)&kh[c*4] = khp[c];
    }
    const float* kTb = kT + (size_t)bh*DH*NN;
    #pragma unroll
    for (int it = 0; it < 2; ++it) {
        int j = threadIdx.x + it*256;
        float acc = 0.f;
        #pragma unroll
        for (int d = 0; d < DH; ++d) acc += kh[d] * kTb[(size_t)d*NN + j];
        kht[(size_t)bm*NN + j] = __float2bfloat16(acc);
    }
}

// ---------------- fused attention: one block per (b,i); 8 waves = 8 heads ----------------
// Grid swizzled so all blocks of one b land on one XCD (kht L2 residency).
__global__ __launch_bounds__(512) void k_attn(
    const float* __restrict__ q, const float* __restrict__ k, const float* __restrict__ kT,
    const float* __restrict__ v,
    const __hip_bfloat16* __restrict__ kht, const int* __restrict__ dist, const int* __restrict__ edge,
    const unsigned char* __restrict__ mask,
    const float* __restrict__ Qh_t, const float* __restrict__ Qe_t, const float* __restrict__ Ke_t,
    const float* __restrict__ Vh_t, const float* __restrict__ Ve_t,
    float* __restrict__ ctx)
{
    // XCD-affine decode: xcd = g&7 gets b = xcd (first half) / xcd+8 (second half)
    int g  = blockIdx.x;
    int r  = g >> 3;
    int b  = (g & 7) + ((r >> 9) << 3);
    int i  = r & (NN-1);
    int w  = threadIdx.x >> 6;      // head
    int l  = threadIdx.x & 63;
    int bh = b*NH + w;

    __shared__ int   mje[NN];          // m | (e<<16), shared by all waves (same b,i)
    __shared__ float qhq[NH][QHQ_W];   // per-wave bias tables
    __shared__ float bins[NH][QHQ_W];  // per-wave scatter bins (vha / vea)
    __shared__ float pbuf[NH][NN];     // per-wave probabilities

    // ---- phase A (block-shared): decode dist/edge row ----
    {
        int t = threadIdx.x;
        if (t < 128) {
            int4 dv = ((const int4*)(dist + ((size_t)b*NN + i)*NN))[t];
            int4 ev = ((const int4*)(edge + ((size_t)b*NN + i)*NN))[t];
            int m0 = dv.x > 256 ? 256 : dv.x; if (dv.x < 0) m0 = 257;
            int m1 = dv.y > 256 ? 256 : dv.y; if (dv.y < 0) m1 = 257;
            int m2 = dv.z > 256 ? 256 : dv.z; if (dv.z < 0) m2 = 257;
            int m3 = dv.w > 256 ? 256 : dv.w; if (dv.w < 0) m3 = 257;
            int e0 = ev.x > 25 ? 25 : ev.x; if (ev.x < 0) e0 = 26;
            int e1 = ev.y > 25 ? 25 : ev.y; if (ev.y < 0) e1 = 26;
            int e2 = ev.z > 25 ? 25 : ev.z; if (ev.z < 0) e2 = 26;
            int e3 = ev.w > 25 ? 25 : ev.w; if (ev.w < 0) e3 = 26;
            mje[t*4+0] = m0 | (e0<<16);
            mje[t*4+1] = m1 | (e1<<16);
            mje[t*4+2] = m2 | (e2<<16);
            mje[t*4+3] = m3 | (e3<<16);
        }
    }
    __syncthreads();

    // ---- phase B (per wave): zero bins; qh + qec tables via coalesced transposed reads ----
    {
        #pragma unroll
        for (int s = 0; s < 5; ++s) {
            int idx = l + 64*s;
            if (idx < QHQ_W) bins[w][idx] = 0.f;
        }
        int mg = l >> 3, d4 = l & 7;
        float4 q4 = *(const float4*)(q + ((size_t)bh*NN + i)*DH + d4*4);
        float4 k4 = *(const float4*)(k + ((size_t)bh*NN + i)*DH + d4*4);
        const float* qhb = Qh_t + (size_t)w*NHOP*DH + d4*4;
        for (int t = 0; t < 33; ++t) {
            int m = 8*t + mg;
            if (m < NHOP) {
                float4 wv = *(const float4*)(qhb + (size_t)m*DH);
                float a = q4.x*wv.x + q4.y*wv.y + q4.z*wv.z + q4.w*wv.w;
                a += __shfl_xor(a, 1, 8); a += __shfl_xor(a, 2, 8); a += __shfl_xor(a, 4, 8);
                if (d4 == 0) qhq[w][m] = a;
            }
        }
        const float* qeb = Qe_t + (size_t)w*NEDGE*DH + d4*4;
        const float* keb = Ke_t + (size_t)w*NEDGE*DH + d4*4;
        #pragma unroll
        for (int t = 0; t < 4; ++t) {
            int e = 8*t + mg;
            if (e < NEDGE) {
                float4 wv = *(const float4*)(qeb + (size_t)e*DH);
                float4 uv = *(const float4*)(keb + (size_t)e*DH);
                float a = q4.x*wv.x + q4.y*wv.y + q4.z*wv.z + q4.w*wv.w
                        + k4.x*uv.x + k4.y*uv.y + k4.z*uv.z + k4.w*uv.w;
                a += __shfl_xor(a, 1, 8); a += __shfl_xor(a, 2, 8); a += __shfl_xor(a, 4, 8);
                if (d4 == 0) qhq[w][264 + e] = a;
            }
        }
    }

    // ---- phase C (per wave): scores via kT (lane-contiguous), softmax, scatter-bins ----
    {
        float qreg[32];
        {
            const float4* qp = (const float4*)(q + ((size_t)bh*NN + i)*DH);
            #pragma unroll
            for (int c = 0; c < 8; ++c) *(float4*)&qreg[c*4] = qp[c];
        }
        const float* kTb = kT + (size_t)bh*DH*NN;
        const __hip_bfloat16* khtb = kht + (size_t)bh*NHOP*NN;
        const unsigned char* mrow = mask + (size_t)b*NN;
        const float scale = 0.17677669529663687f;

        int mv[8], evv[8];
        #pragma unroll
        for (int s = 0; s < 8; ++s) {
            int pk = mje[l + 64*s];
            mv[s] = pk & 0xFFFF; evv[s] = pk >> 16;
        }
        __hip_bfloat16 raw[8];
        #pragma unroll
        for (int s = 0; s < 8; ++s) {             // 8 independent scattered gathers in flight
            raw[s] = khtb[(size_t)mv[s]*NN + (l + 64*s)];
        }
        float sc[8];
        #pragma unroll
        for (int s = 0; s < 8; ++s) sc[s] = 0.f;
        #pragma unroll
        for (int d = 0; d < 32; ++d) {
            const float* kr = kTb + (size_t)d*NN + l;
            float qd = qreg[d];
            #pragma unroll
            for (int s = 0; s < 8; ++s) sc[s] += qd * kr[64*s];
        }
        #pragma unroll
        for (int s = 0; s < 8; ++s) {
            int j = l + 64*s;
            float a = sc[s] + qhq[w][mv[s]] + __bfloat162float(raw[s]) + qhq[w][264 + evv[s]];
            a *= scale;
            if (mrow[j]) a = -INFINITY;
            sc[s] = a;
        }
        float mx = sc[0];
        #pragma unroll
        for (int s = 1; s < 8; ++s) mx = fmaxf(mx, sc[s]);
        #pragma unroll
        for (int o = 32; o > 0; o >>= 1) mx = fmaxf(mx, __shfl_xor(mx, o, 64));
        float sum = 0.f;
        #pragma unroll
        for (int s = 0; s < 8; ++s) { sc[s] = __expf(sc[s] - mx); sum += sc[s]; }
        #pragma unroll
        for (int o = 32; o > 0; o >>= 1) sum += __shfl_xor(sum, o, 64);
        float inv = 1.0f / sum;
        #pragma unroll
        for (int s = 0; s < 8; ++s) {
            float ps = sc[s] * inv;
            pbuf[w][l + 64*s] = ps;
            atomicAdd(&bins[w][mv[s]], ps);
            atomicAdd(&bins[w][264 + evv[s]], ps);
        }
    }

    // ---- phase D (per wave): dense AV + bin reductions; lane = (jc, d4) ----
    {
        int jc = l >> 3;          // 0..7
        int d4 = l & 7;           // float4 chunk 0..7
        const float* vb = v + (size_t)bh*NN*DH + d4*4;
        float4 acc; acc.x = acc.y = acc.z = acc.w = 0.f;
        #pragma unroll 4
        for (int off = 0; off < 64; ++off) {
            int j = 8*off + jc;
            float wp = pbuf[w][j];
            float4 vv = *(const float4*)(vb + (size_t)j*DH);
            acc.x += wp * vv.x; acc.y += wp * vv.y;
            acc.z += wp * vv.z; acc.w += wp * vv.w;
        }
        const float* vhb = Vh_t + (size_t)w*NHOP*DH + d4*4;
        for (int t = 0; t < 33; ++t) {
            int m = 8*t + jc;
            if (m < NHOP) {
                float bw = bins[w][m];
                float4 vv = *(const float4*)(vhb + (size_t)m*DH);
                acc.x += bw * vv.x; acc.y += bw * vv.y;
                acc.z += bw * vv.z; acc.w += bw * vv.w;
            }
        }
        const float* veb = Ve_t + (size_t)w*NEDGE*DH + d4*4;
        #pragma unroll
        for (int t = 0; t < 4; ++t) {
            int e = 8*t + jc;
            if (e < NEDGE) {
                float bw = bins[w][264 + e];
                float4 vv = *(const float4*)(veb + (size_t)e*DH);
                acc.x += bw * vv.x; acc.y += bw * vv.y;
                acc.z += bw * vv.z; acc.w += bw * vv.w;
            }
        }
        #pragma unroll
        for (int o = 8; o <= 32; o <<= 1) {
            acc.x += __shfl_xor(acc.x, o, 64);
            acc.y += __shfl_xor(acc.y, o, 64);
            acc.z += __shfl_xor(acc.z, o, 64);
            acc.w += __shfl_xor(acc.w, o, 64);
        }
        if (jc == 0) {
            *(float4*)(ctx + ((size_t)b*NN + i)*DM + w*DH + d4*4) = acc;
        }
    }
}

extern "C" void kernel_launch(void* const* d_in, const int* in_sizes, int n_in,
                              void* d_out, int out_size, void* d_ws, size_t ws_size,
                              hipStream_t stream) {
    const float* x     = (const float*)d_in[0];
    const unsigned char* mask = (const unsigned char*)d_in[1];
    const int*   dist  = (const int*)d_in[2];
    const int*   edge  = (const int*)d_in[3];
    const float* node_W = (const float*)d_in[4];
    const float* node_b = (const float*)d_in[5];
    const float* ln1_g = (const float*)d_in[6];
    const float* ln1_b = (const float*)d_in[7];
    const float* Wq = (const float*)d_in[8];
    const float* bq = (const float*)d_in[9];
    const float* Wk = (const float*)d_in[10];
    const float* bk = (const float*)d_in[11];
    const float* Wv = (const float*)d_in[12];
    const float* bv = (const float*)d_in[13];
    const float* Wo = (const float*)d_in[14];
    const float* bo = (const float*)d_in[15];
    const float* ln2_g = (const float*)d_in[16];
    const float* ln2_b = (const float*)d_in[17];
    const float* W1 = (const float*)d_in[18];
    const float* b1 = (const float*)d_in[19];
    const float* W2 = (const float*)d_in[20];
    const float* b2 = (const float*)d_in[21];
    const float* q_hop  = (const float*)d_in[22];
    const float* q_edge = (const float*)d_in[23];
    const float* k_hop  = (const float*)d_in[24];
    const float* k_edge = (const float*)d_in[25];
    const float* v_hop  = (const float*)d_in[26];
    const float* v_edge = (const float*)d_in[27];
    const float* fln_g = (const float*)d_in[28];
    const float* fln_b = (const float*)d_in[29];
    const float* out_W = (const float*)d_in[30];
    const float* out_b = (const float*)d_in[31];
    float* out = (float*)d_out;

    float* ws = (float*)d_ws;
    float* h   = ws + 0;                         //  2,097,152
    float* y   = ws + 2097152;                   //  2,097,152
    float* q   = ws + 4194304;                   //  2,097,152  [B,H,N,DH]
    float* k   = ws + 6291456;                   //  2,097,152
    float* v   = ws + 8388608;                   //  2,097,152
    float* ctx = ws + 10485760;                  //  2,097,152
    __hip_bfloat16* kht = (__hip_bfloat16*)(ws + 12582912);  // 16,908,288 bf16 -> ends at float ofs 21,037,056
    float* ffn = ws + 12582912;                  //  8,388,608 floats (aliases kht, dead by then)
    float* kT  = ws + 21037056;                  //  2,097,152  [B,H,DH,NN]
    // transposed bias tables alias y (y is dead between qkv-projection and ln2)
    float* Qh_t = y + 0;                         // 8*258*32 = 66,048
    float* Vh_t = y + 66048;                     // 66,048
    float* Qe_t = y + 132096;                    // 8*27*32 = 6,912
    float* Ke_t = y + 139008;                    // 6,912
    float* Ve_t = y + 145920;                    // 6,912

    k_gemm<DIN, DM, 0, 0, 0><<<dim3(ROWS/16, 1), 256, 0, stream>>>(x, node_W, node_b, h);
    k_ln<<<ROWS/4, 256, 0, stream>>>(h, ln1_g, ln1_b, y);
    k_gemm<DM, DM, 0, 0, 1><<<dim3(ROWS/16, 1), 256, 0, stream>>>(y, Wq, bq, q);
    k_gemm<DM, DM, 0, 0, 1><<<dim3(ROWS/16, 1), 256, 0, stream>>>(y, Wk, bk, k);
    k_gemm<DM, DM, 0, 0, 1><<<dim3(ROWS/16, 1), 256, 0, stream>>>(y, Wv, bv, v);
    // y is now dead -> stash transposed tables there
    k_tr<<<NHOP, 256, 0, stream>>>(q_hop, Qh_t, NHOP);
    k_tr<<<NHOP, 256, 0, stream>>>(v_hop, Vh_t, NHOP);
    k_tr<<<NEDGE, 256, 0, stream>>>(q_edge, Qe_t, NEDGE);
    k_tr<<<NEDGE, 256, 0, stream>>>(k_edge, Ke_t, NEDGE);
    k_tr<<<NEDGE, 256, 0, stream>>>(v_edge, Ve_t, NEDGE);
    k_tx<<<dim3(BB*NH, 8), 256, 0, stream>>>(k, kT);
    k_kht<<<BB*NH*NHOP, 256, 0, stream>>>(kT, k_hop, kht);
    k_attn<<<BB*NN, 512, 0, stream>>>(q, k, kT, v, kht, dist, edge, mask,
                                      Qh_t, Qe_t, Ke_t, Vh_t, Ve_t, ctx);
    k_gemm<DM, DM, 0, 1, 0><<<dim3(ROWS/16, 1), 256, 0, stream>>>(ctx, Wo, bo, h);
    k_ln<<<ROWS/4, 256, 0, stream>>>(h, ln2_g, ln2_b, y);
    k_gemm<DM, FF, 1, 0, 0><<<dim3(ROWS/16, 4), 256, 0, stream>>>(y, W1, b1, ffn);
    k_gemm<FF, DM, 0, 1, 0><<<dim3(ROWS/16, 1), 256, 0, stream>>>(ffn, W2, b2, h);
    k_ln<<<ROWS/4, 256, 0, stream>>>(h, fln_g, fln_b, y);
    k_gemm<DM, DOUT, 0, 0, 0><<<dim3(ROWS/16, 1), 256, 0, stream>>>(y, out_W, out_b, out);
}

// Round 7
// 1151.152 us; speedup vs baseline: 2.6037x; 1.1761x over previous
//
#include <hip/hip_runtime.h>
#include <hip/hip_bf16.h>
#include <math.h>

#define BB 16
#define NN 512
#define DIN 128
#define DM 256
#define NH 8
#define DH 32
#define FF 1024
#define DOUT 128
#define NHOP 258
#define NEDGE 27
#define ROWS (BB*NN)   // 8192
#define QHE_S 296      // qhe row stride (ushorts): qh 0..257, qec at 264..290

static __device__ __forceinline__ float bf2f(unsigned short u) {
    union { float f; unsigned int i; } c; c.i = ((unsigned int)u) << 16; return c.f;
}

// ---------------- layernorm: one wave per row, float4 + shuffle ----------------
__global__ __launch_bounds__(256) void k_ln(const float* __restrict__ in, const float* __restrict__ g,
                                            const float* __restrict__ bta, float* __restrict__ out) {
    int row = blockIdx.x * 4 + (threadIdx.x >> 6);
    int l = threadIdx.x & 63;
    float4 xv = ((const float4*)(in + (size_t)row*DM))[l];
    float s = xv.x + xv.y + xv.z + xv.w;
    #pragma unroll
    for (int o = 32; o > 0; o >>= 1) s += __shfl_xor(s, o, 64);
    float mean = s * (1.0f/DM);
    float dx = xv.x-mean, dy = xv.y-mean, dz = xv.z-mean, dw = xv.w-mean;
    float vs = dx*dx + dy*dy + dz*dz + dw*dw;
    #pragma unroll
    for (int o = 32; o > 0; o >>= 1) vs += __shfl_xor(vs, o, 64);
    float r = rsqrtf(vs * (1.0f/DM) + 1e-5f);
    float4 gg = ((const float4*)g)[l];
    float4 bb = ((const float4*)bta)[l];
    float4 ov; ov.x = dx*r*gg.x+bb.x; ov.y = dy*r*gg.y+bb.y; ov.z = dz*r*gg.z+bb.z; ov.w = dw*r*gg.w+bb.w;
    ((float4*)(out + (size_t)row*DM))[l] = ov;
}

// ---------------- tiled GEMM: 16 rows/block, 256 cols/block ----------------
template<int K, int N, int ACT, int RES, int QKV>
__global__ __launch_bounds__(256) void k_gemm(const float* __restrict__ A, const float* __restrict__ W,
                                              const float* __restrict__ bias, float* __restrict__ out) {
    constexpr int KC = (K < 256) ? K : 256;
    __shared__ __align__(16) float As[16][KC];
    int r0 = blockIdx.x * 16;
    int colbase = blockIdx.y * 256;
    int tid = threadIdx.x;
    int col = colbase + tid;
    bool active = tid < ((N < 256) ? N : 256);
    float bv = 0.f;
    if (active) bv = bias[col];
    float acc[16];
    #pragma unroll
    for (int r = 0; r < 16; ++r) acc[r] = 0.f;

    for (int kc = 0; kc < K; kc += KC) {
        for (int idx = tid*4; idx < 16*KC; idx += 1024) {
            int r = idx / KC, kk = idx % KC;
            *(float4*)&As[r][kk] = *(const float4*)&A[(size_t)(r0 + r)*K + kc + kk];
        }
        __syncthreads();
        if (active) {
            for (int kk = 0; kk < KC; kk += 4) {
                const float* wp = W + (size_t)(kc + kk)*N + col;
                float w0 = wp[0], w1 = wp[N], w2 = wp[2*N], w3 = wp[3*N];
                #pragma unroll
                for (int r = 0; r < 16; ++r) {
                    float4 a = *(const float4*)&As[r][kk];
                    acc[r] += a.x*w0 + a.y*w1 + a.z*w2 + a.w*w3;
                }
            }
        }
        __syncthreads();
    }
    if (active) {
        #pragma unroll
        for (int r = 0; r < 16; ++r) {
            float val = acc[r] + bv;
            if (ACT) val = 0.5f * val * (1.0f + erff(val * 0.70710678118654752f));
            int row = r0 + r;
            if (QKV) {
                int b = row >> 9, n = row & (NN-1);
                int hh = col >> 5, d = col & (DH-1);
                out[(size_t)((b*NH + hh)*NN + n)*DH + d] = val;
            } else if (RES) {
                out[(size_t)row*N + col] += val;
            } else {
                out[(size_t)row*N + col] = val;
            }
        }
    }
}

// ---------------- transpose bias table [M][256] -> [8][M][32] (for Vh/Ve) ----------------
__global__ __launch_bounds__(256) void k_tr(const float* __restrict__ in, float* __restrict__ out, int M) {
    int m = blockIdx.x, t = threadIdx.x;
    out[((size_t)(t >> 5)*M + m)*DH + (t & 31)] = in[(size_t)m*DM + t];
}

// ---------------- transpose bias table [M][256] -> [8][32][M] (d-major, for k_qhe) ----------------
__global__ __launch_bounds__(256) void k_trd(const float* __restrict__ in, float* __restrict__ out, int M) {
    int m = blockIdx.x, t = threadIdx.x;
    out[(size_t)t*M + m] = in[(size_t)m*DM + t];
}

// ---------------- k [bh][j][d] -> kT [bh][d][j] (64-j tile per block) ----------------
__global__ __launch_bounds__(256) void k_tx(const float* __restrict__ k, float* __restrict__ kT) {
    __shared__ float lds[64*33];
    int bh = blockIdx.x;
    int j0 = blockIdx.y * 64;
    int tid = threadIdx.x;
    {
        int jj = tid >> 2, d8 = tid & 3;
        const float* src = k + ((size_t)bh*NN + j0 + jj)*DH + d8*8;
        float4 a = *(const float4*)(src);
        float4 b = *(const float4*)(src + 4);
        float* dst = lds + jj*33 + d8*8;
        dst[0]=a.x; dst[1]=a.y; dst[2]=a.z; dst[3]=a.w;
        dst[4]=b.x; dst[5]=b.y; dst[6]=b.z; dst[7]=b.w;
    }
    __syncthreads();
    {
        int d = tid >> 3, jg = tid & 7;
        float* dst = kT + ((size_t)bh*DH + d)*NN + j0;
        #pragma unroll
        for (int jj2 = 0; jj2 < 8; ++jj2) {
            int j = jg*8 + jj2;
            dst[j] = lds[j*33 + d];
        }
    }
}

// ---------------- khT[bh,m,j] = sum_d kT[bh,d,j] * Kh[h,m,d]  (stored bf16) ----------------
__global__ __launch_bounds__(256) void k_kht(const float* __restrict__ kT, const float* __restrict__ k_hop,
                                             __hip_bfloat16* __restrict__ kht) {
    int bm = blockIdx.x;             // bh*NHOP + m
    int m = bm % NHOP;
    int bh = bm / NHOP;
    int hh = bh & (NH-1);
    float kh[32];
    {
        const float4* khp = (const float4*)(k_hop + (size_t)m*DM + hh*DH);
        #pragma unroll
        for (int c = 0; c < 8; ++c) *(float4*)&kh[c*4] = khp[c];
    }
    const float* kTb = kT + (size_t)bh*DH*NN;
    #pragma unroll
    for (int it = 0; it < 2; ++it) {
        int j = threadIdx.x + it*256;
        float acc = 0.f;
        #pragma unroll
        for (int d = 0; d < DH; ++d) acc += kh[d] * kTb[(size_t)d*NN + j];
        kht[(size_t)bm*NN + j] = __float2bfloat16(acc);
    }
}

// ---------------- qhe[bh][i][m] = q_i . Qh[m] (m<258) ; q_i.Qe[e] + k_i.Ke[e] (m=264+e) ----------------
__global__ __launch_bounds__(256) void k_qhe(const float* __restrict__ q, const float* __restrict__ k,
                                             const float* __restrict__ Qh_d, const float* __restrict__ Qe_d,
                                             const float* __restrict__ Ke_d, unsigned short* __restrict__ qhe) {
    int bh = blockIdx.x;
    int hh = bh & (NH-1);
    int i0 = blockIdx.y * 16;
    int tid = threadIdx.x;
    __shared__ __align__(16) float As[16][32];
    __shared__ __align__(16) float Ks[16][32];
    {
        int r = (tid & 127) >> 3, c4 = tid & 7;
        const float* src = ((tid < 128) ? q : k) + ((size_t)bh*NN + i0 + r)*DH + c4*4;
        float4 vv = *(const float4*)src;
        float* dst = (tid < 128) ? &As[r][c4*4] : &Ks[r][c4*4];
        *(float4*)dst = vv;
    }
    __syncthreads();
    // main hop cols m = tid (0..255)
    {
        float acc[16];
        #pragma unroll
        for (int r = 0; r < 16; ++r) acc[r] = 0.f;
        const float* wb = Qh_d + (size_t)hh*32*NHOP + tid;
        for (int d = 0; d < 32; ++d) {
            float wv = wb[(size_t)d*NHOP];
            #pragma unroll
            for (int r = 0; r < 16; ++r) acc[r] += As[r][d] * wv;
        }
        #pragma unroll
        for (int r = 0; r < 16; ++r) {
            __hip_bfloat16 bv = __float2bfloat16(acc[r]);
            qhe[((size_t)bh*NN + i0 + r)*QHE_S + tid] = *(unsigned short*)&bv;
        }
    }
    // tail cols: m = 256,257 (threads 0,1) and edge cols e=0..26 (threads 8..34)
    if (tid < 2) {
        int m = 256 + tid;
        float acc[16];
        #pragma unroll
        for (int r = 0; r < 16; ++r) acc[r] = 0.f;
        const float* wb = Qh_d + (size_t)hh*32*NHOP + m;
        for (int d = 0; d < 32; ++d) {
            float wv = wb[(size_t)d*NHOP];
            #pragma unroll
            for (int r = 0; r < 16; ++r) acc[r] += As[r][d] * wv;
        }
        #pragma unroll
        for (int r = 0; r < 16; ++r) {
            __hip_bfloat16 bv = __float2bfloat16(acc[r]);
            qhe[((size_t)bh*NN + i0 + r)*QHE_S + m] = *(unsigned short*)&bv;
        }
    } else if (tid >= 8 && tid < 8 + NEDGE) {
        int e = tid - 8;
        float acc[16];
        #pragma unroll
        for (int r = 0; r < 16; ++r) acc[r] = 0.f;
        const float* wq = Qe_d + (size_t)hh*32*NEDGE + e;
        const float* wk = Ke_d + (size_t)hh*32*NEDGE + e;
        for (int d = 0; d < 32; ++d) {
            float a = wq[(size_t)d*NEDGE], bbw = wk[(size_t)d*NEDGE];
            #pragma unroll
            for (int r = 0; r < 16; ++r) acc[r] += As[r][d]*a + Ks[r][d]*bbw;
        }
        #pragma unroll
        for (int r = 0; r < 16; ++r) {
            __hip_bfloat16 bv = __float2bfloat16(acc[r]);
            qhe[((size_t)bh*NN + i0 + r)*QHE_S + 264 + e] = *(unsigned short*)&bv;
        }
    }
}

// ---------------- fused attention: block = (b, 4-i tile); 8 waves = 8 heads x 4 rows ----------------
__global__ __launch_bounds__(512) void k_attn(
    const float* __restrict__ q, const float* __restrict__ kT, const float* __restrict__ v,
    const __hip_bfloat16* __restrict__ kht, const int* __restrict__ dist, const int* __restrict__ edge,
    const unsigned char* __restrict__ mask, const unsigned short* __restrict__ qhe,
    const float* __restrict__ Vh_t, const float* __restrict__ Ve_t,
    float* __restrict__ ctx)
{
    // XCD-affine: xcd = g&7 -> b = xcd or xcd+8
    int g  = blockIdx.x;
    int rr = g >> 3;
    int b  = (g & 7) + ((rr >> 7) << 3);
    int i0 = (rr & 127) * 4;
    int w  = threadIdx.x >> 6;
    int l  = threadIdx.x & 63;
    int bh = b*NH + w;

    __shared__ unsigned short mje[4][NN];      // m | (e<<9)
    __shared__ float qv[NH][4][DH];
    __shared__ __hip_bfloat16 pb[NH][4][NN];
    __shared__ float bins[NH][292];            // hop 0..257, edge 264..290

    // ---- phase A ----
    {
        int t = threadIdx.x;
        int row = t >> 7, c4 = t & 127;
        int4 dv = ((const int4*)(dist + ((size_t)(b*NN) + i0 + row)*NN))[c4];
        int4 ev = ((const int4*)(edge + ((size_t)(b*NN) + i0 + row)*NN))[c4];
        int m0 = dv.x > 256 ? 256 : dv.x; if (dv.x < 0) m0 = 257;
        int m1 = dv.y > 256 ? 256 : dv.y; if (dv.y < 0) m1 = 257;
        int m2 = dv.z > 256 ? 256 : dv.z; if (dv.z < 0) m2 = 257;
        int m3 = dv.w > 256 ? 256 : dv.w; if (dv.w < 0) m3 = 257;
        int e0 = ev.x > 25 ? 25 : ev.x; if (ev.x < 0) e0 = 26;
        int e1 = ev.y > 25 ? 25 : ev.y; if (ev.y < 0) e1 = 26;
        int e2 = ev.z > 25 ? 25 : ev.z; if (ev.z < 0) e2 = 26;
        int e3 = ev.w > 25 ? 25 : ev.w; if (ev.w < 0) e3 = 26;
        mje[row][c4*4+0] = (unsigned short)(m0 | (e0 << 9));
        mje[row][c4*4+1] = (unsigned short)(m1 | (e1 << 9));
        mje[row][c4*4+2] = (unsigned short)(m2 | (e2 << 9));
        mje[row][c4*4+3] = (unsigned short)(m3 | (e3 << 9));
        #pragma unroll
        for (int rep = 0; rep < 2; ++rep) {
            int i = rep*2 + (l >> 5), d = l & 31;
            qv[w][i][d] = q[((size_t)bh*NN + i0 + i)*DH + d];
        }
        for (int s = l; s < 292; s += 64) bins[w][s] = 0.f;
    }
    __syncthreads();

    // ---- d-loop: QK^T for 4 rows, lane-contiguous kT reads ----
    float sc[4][8];
    #pragma unroll
    for (int i = 0; i < 4; ++i)
        #pragma unroll
        for (int s = 0; s < 8; ++s) sc[i][s] = 0.f;
    {
        const float* kTb = kT + (size_t)bh*DH*NN;
        for (int d = 0; d < 32; ++d) {
            const float* kr = kTb + (size_t)d*NN + l;
            float k0 = kr[0],   k1 = kr[64],  k2 = kr[128], k3 = kr[192];
            float k4 = kr[256], k5 = kr[320], k6 = kr[384], k7 = kr[448];
            float qa = qv[w][0][d], qb = qv[w][1][d], qc = qv[w][2][d], qd = qv[w][3][d];
            sc[0][0]+=qa*k0; sc[0][1]+=qa*k1; sc[0][2]+=qa*k2; sc[0][3]+=qa*k3;
            sc[0][4]+=qa*k4; sc[0][5]+=qa*k5; sc[0][6]+=qa*k6; sc[0][7]+=qa*k7;
            sc[1][0]+=qb*k0; sc[1][1]+=qb*k1; sc[1][2]+=qb*k2; sc[1][3]+=qb*k3;
            sc[1][4]+=qb*k4; sc[1][5]+=qb*k5; sc[1][6]+=qb*k6; sc[1][7]+=qb*k7;
            sc[2][0]+=qc*k0; sc[2][1]+=qc*k1; sc[2][2]+=qc*k2; sc[2][3]+=qc*k3;
            sc[2][4]+=qc*k4; sc[2][5]+=qc*k5; sc[2][6]+=qc*k6; sc[2][7]+=qc*k7;
            sc[3][0]+=qd*k0; sc[3][1]+=qd*k1; sc[3][2]+=qd*k2; sc[3][3]+=qd*k3;
            sc[3][4]+=qd*k4; sc[3][5]+=qd*k5; sc[3][6]+=qd*k6; sc[3][7]+=qd*k7;
        }
    }

    const __hip_bfloat16* khtb = kht + (size_t)bh*NHOP*NN;
    const unsigned char* mrow = mask + (size_t)b*NN;
    unsigned char msk[8];
    #pragma unroll
    for (int s = 0; s < 8; ++s) msk[s] = mrow[l + 64*s];

    int jc = l >> 3, d4 = l & 7;
    const float* vhb = Vh_t + (size_t)w*NHOP*DH + d4*4;
    const float* veb = Ve_t + (size_t)w*NEDGE*DH + d4*4;
    const float scale = 0.17677669529663687f;
    float4 acc[4];

    // ---- per-i: bias gather + softmax + bins + D2 ----
    #pragma unroll
    for (int i = 0; i < 4; ++i) {
        const unsigned short* qhr = qhe + ((size_t)bh*NN + i0 + i)*QHE_S;
        int mv[8], ev[8];
        #pragma unroll
        for (int s = 0; s < 8; ++s) { int pk = mje[i][l + 64*s]; mv[s] = pk & 511; ev[s] = pk >> 9; }
        unsigned short raw[8];
        #pragma unroll
        for (int s = 0; s < 8; ++s) raw[s] = ((const unsigned short*)khtb)[(size_t)mv[s]*NN + l + 64*s];
        unsigned short qhv[8], qev[8];
        #pragma unroll
        for (int s = 0; s < 8; ++s) qhv[s] = qhr[mv[s]];
        #pragma unroll
        for (int s = 0; s < 8; ++s) qev[s] = qhr[264 + ev[s]];
        float x[8];
        #pragma unroll
        for (int s = 0; s < 8; ++s) {
            float a = (sc[i][s] + bf2f(qhv[s]) + bf2f(raw[s]) + bf2f(qev[s])) * scale;
            if (msk[s]) a = -INFINITY;
            x[s] = a;
        }
        float mx = x[0];
        #pragma unroll
        for (int s = 1; s < 8; ++s) mx = fmaxf(mx, x[s]);
        #pragma unroll
        for (int o = 32; o > 0; o >>= 1) mx = fmaxf(mx, __shfl_xor(mx, o, 64));
        float sum = 0.f;
        #pragma unroll
        for (int s = 0; s < 8; ++s) { x[s] = __expf(x[s] - mx); sum += x[s]; }
        #pragma unroll
        for (int o = 32; o > 0; o >>= 1) sum += __shfl_xor(sum, o, 64);
        float inv = 1.0f / sum;
        #pragma unroll
        for (int s = 0; s < 8; ++s) {
            float ps = x[s] * inv;
            pb[w][i][l + 64*s] = __float2bfloat16(ps);
            atomicAdd(&bins[w][mv[s]], ps);
            atomicAdd(&bins[w][264 + ev[s]], ps);
        }
        // D2: bin-weighted Vh/Ve sums (wave-local program order guarantees atomics done)
        float4 a4; a4.x = a4.y = a4.z = a4.w = 0.f;
        for (int t = 0; t < 33; ++t) {
            int m = 8*t + jc;
            if (m < NHOP) {
                float bw = bins[w][m];
                float4 vv = *(const float4*)(vhb + (size_t)m*DH);
                a4.x += bw*vv.x; a4.y += bw*vv.y; a4.z += bw*vv.z; a4.w += bw*vv.w;
            }
        }
        #pragma unroll
        for (int t = 0; t < 4; ++t) {
            int e = 8*t + jc;
            if (e < NEDGE) {
                float bw = bins[w][264 + e];
                float4 vv = *(const float4*)(veb + (size_t)e*DH);
                a4.x += bw*vv.x; a4.y += bw*vv.y; a4.z += bw*vv.z; a4.w += bw*vv.w;
            }
        }
        acc[i] = a4;
        if (i < 3) {
            for (int s2 = l; s2 < 292; s2 += 64) bins[w][s2] = 0.f;
        }
    }

    // ---- D1: dense AV, v loads shared across the 4 rows ----
    {
        const float* vb = v + (size_t)bh*NN*DH + d4*4;
        for (int off = 0; off < 64; ++off) {
            int j = 8*off + jc;
            float4 vv = *(const float4*)(vb + (size_t)j*DH);
            #pragma unroll
            for (int i = 0; i < 4; ++i) {
                float p = bf2f(*(const unsigned short*)&pb[w][i][j]);
                acc[i].x += p*vv.x; acc[i].y += p*vv.y; acc[i].z += p*vv.z; acc[i].w += p*vv.w;
            }
        }
    }
    #pragma unroll
    for (int i = 0; i < 4; ++i) {
        #pragma unroll
        for (int o = 8; o <= 32; o <<= 1) {
            acc[i].x += __shfl_xor(acc[i].x, o, 64);
            acc[i].y += __shfl_xor(acc[i].y, o, 64);
            acc[i].z += __shfl_xor(acc[i].z, o, 64);
            acc[i].w += __shfl_xor(acc[i].w, o, 64);
        }
        if (jc == 0) {
            *(float4*)(ctx + ((size_t)b*NN + i0 + i)*DM + w*DH + d4*4) = acc[i];
        }
    }
}

extern "C" void kernel_launch(void* const* d_in, const int* in_sizes, int n_in,
                              void* d_out, int out_size, void* d_ws, size_t ws_size,
                              hipStream_t stream) {
    const float* x     = (const float*)d_in[0];
    const unsigned char* mask = (const unsigned char*)d_in[1];
    const int*   dist  = (const int*)d_in[2];
    const int*   edge  = (const int*)d_in[3];
    const float* node_W = (const float*)d_in[4];
    const float* node_b = (const float*)d_in[5];
    const float* ln1_g = (const float*)d_in[6];
    const float* ln1_b = (const float*)d_in[7];
    const float* Wq = (const float*)d_in[8];
    const float* bq = (const float*)d_in[9];
    const float* Wk = (const float*)d_in[10];
    const float* bk = (const float*)d_in[11];
    const float* Wv = (const float*)d_in[12];
    const float* bv = (const float*)d_in[13];
    const float* Wo = (const float*)d_in[14];
    const float* bo = (const float*)d_in[15];
    const float* ln2_g = (const float*)d_in[16];
    const float* ln2_b = (const float*)d_in[17];
    const float* W1 = (const float*)d_in[18];
    const float* b1 = (const float*)d_in[19];
    const float* W2 = (const float*)d_in[20];
    const float* b2 = (const float*)d_in[21];
    const float* q_hop  = (const float*)d_in[22];
    const float* q_edge = (const float*)d_in[23];
    const float* k_hop  = (const float*)d_in[24];
    const float* k_edge = (const float*)d_in[25];
    const float* v_hop  = (const float*)d_in[26];
    const float* v_edge = (const float*)d_in[27];
    const float* fln_g = (const float*)d_in[28];
    const float* fln_b = (const float*)d_in[29];
    const float* out_W = (const float*)d_in[30];
    const float* out_b = (const float*)d_in[31];
    float* out = (float*)d_out;

    float* ws = (float*)d_ws;
    float* h   = ws + 0;                         //  2,097,152
    float* y   = ws + 2097152;                   //  2,097,152
    float* q   = ws + 4194304;                   //  2,097,152  [B,H,N,DH]
    float* k   = ws + 6291456;                   //  2,097,152
    float* v   = ws + 8388608;                   //  2,097,152
    float* ctx = ws + 10485760;                  //  2,097,152
    __hip_bfloat16* kht = (__hip_bfloat16*)(ws + 12582912);  // 16,908,288 bf16 (8,454,144 floats)
    float* ffn = ws + 12582912;                  //  8,388,608 floats (aliases kht, dead by then)
    float* kT  = ws + 21037056;                  //  2,097,152  [B,H,DH,NN]
    unsigned short* qhe = (unsigned short*)(ws + 23134208);  // 128*512*296 ushort = 9,699,328 floats
    // tables alias y (y dead between qkv-projection and ln2)
    float* Vh_t = y + 0;                         // 8*258*32 = 66,048
    float* Ve_t = y + 66048;                     // 8*27*32 = 6,912
    float* Qh_d = y + 72960;                     // 8*32*258 = 66,048
    float* Qe_d = y + 139008;                    // 8*32*27 = 6,912
    float* Ke_d = y + 145920;                    // 6,912

    k_gemm<DIN, DM, 0, 0, 0><<<dim3(ROWS/16, 1), 256, 0, stream>>>(x, node_W, node_b, h);
    k_ln<<<ROWS/4, 256, 0, stream>>>(h, ln1_g, ln1_b, y);
    k_gemm<DM, DM, 0, 0, 1><<<dim3(ROWS/16, 1), 256, 0, stream>>>(y, Wq, bq, q);
    k_gemm<DM, DM, 0, 0, 1><<<dim3(ROWS/16, 1), 256, 0, stream>>>(y, Wk, bk, k);
    k_gemm<DM, DM, 0, 0, 1><<<dim3(ROWS/16, 1), 256, 0, stream>>>(y, Wv, bv, v);
    // y now dead -> build tables
    k_tr <<<NHOP, 256, 0, stream>>>(v_hop, Vh_t, NHOP);
    k_tr <<<NEDGE, 256, 0, stream>>>(v_edge, Ve_t, NEDGE);
    k_trd<<<NHOP, 256, 0, stream>>>(q_hop, Qh_d, NHOP);
    k_trd<<<NEDGE, 256, 0, stream>>>(q_edge, Qe_d, NEDGE);
    k_trd<<<NEDGE, 256, 0, stream>>>(k_edge, Ke_d, NEDGE);
    k_tx<<<dim3(BB*NH, 8), 256, 0, stream>>>(k, kT);
    k_kht<<<BB*NH*NHOP, 256, 0, stream>>>(kT, k_hop, kht);
    k_qhe<<<dim3(BB*NH, NN/16), 256, 0, stream>>>(q, k, Qh_d, Qe_d, Ke_d, qhe);
    k_attn<<<BB*(NN/4), 512, 0, stream>>>(q, kT, v, kht, dist, edge, mask, qhe,
                                          Vh_t, Ve_t, ctx);
    k_gemm<DM, DM, 0, 1, 0><<<dim3(ROWS/16, 1), 256, 0, stream>>>(ctx, Wo, bo, h);
    k_ln<<<ROWS/4, 256, 0, stream>>>(h, ln2_g, ln2_b, y);
    k_gemm<DM, FF, 1, 0, 0><<<dim3(ROWS/16, 4), 256, 0, stream>>>(y, W1, b1, ffn);
    k_gemm<FF, DM, 0, 1, 0><<<dim3(ROWS/16, 1), 256, 0, stream>>>(ffn, W2, b2, h);
    k_ln<<<ROWS/4, 256, 0, stream>>>(h, fln_g, fln_b, y);
    k_gemm<DM, DOUT, 0, 0, 0><<<dim3(ROWS/16, 1), 256, 0, stream>>>(y, out_W, out_b, out);
}

// Round 8
// 873.170 us; speedup vs baseline: 3.4327x; 1.3184x over previous
//
#include <hip/hip_runtime.h>
#include <hip/hip_bf16.h>
#include <math.h>

#define BB 16
#define NN 512
#define DIN 128
#define DM 256
#define NH 8
#define DH 32
#define FF 1024
#define DOUT 128
#define NHOP 258
#define NEDGE 27
#define ROWS (BB*NN)   // 8192
#define QHE_S 296      // qhe row stride (ushorts): qh 0..257, qec at 264..290

typedef short short8 __attribute__((ext_vector_type(8)));
typedef float f32x4 __attribute__((ext_vector_type(4)));

static __device__ __forceinline__ float bf2f(unsigned short u) {
    union { float f; unsigned int i; } c; c.i = ((unsigned int)u) << 16; return c.f;
}
static __device__ __forceinline__ short f2bs(float f) {
    __hip_bfloat16 h = __float2bfloat16(f);
    return *reinterpret_cast<short*>(&h);
}

// ---------------- layernorm: one wave per row, float4 + shuffle ----------------
__global__ __launch_bounds__(256) void k_ln(const float* __restrict__ in, const float* __restrict__ g,
                                            const float* __restrict__ bta, float* __restrict__ out) {
    int row = blockIdx.x * 4 + (threadIdx.x >> 6);
    int l = threadIdx.x & 63;
    float4 xv = ((const float4*)(in + (size_t)row*DM))[l];
    float s = xv.x + xv.y + xv.z + xv.w;
    #pragma unroll
    for (int o = 32; o > 0; o >>= 1) s += __shfl_xor(s, o, 64);
    float mean = s * (1.0f/DM);
    float dx = xv.x-mean, dy = xv.y-mean, dz = xv.z-mean, dw = xv.w-mean;
    float vs = dx*dx + dy*dy + dz*dz + dw*dw;
    #pragma unroll
    for (int o = 32; o > 0; o >>= 1) vs += __shfl_xor(vs, o, 64);
    float r = rsqrtf(vs * (1.0f/DM) + 1e-5f);
    float4 gg = ((const float4*)g)[l];
    float4 bb = ((const float4*)bta)[l];
    float4 ov; ov.x = dx*r*gg.x+bb.x; ov.y = dy*r*gg.y+bb.y; ov.z = dz*r*gg.z+bb.z; ov.w = dw*r*gg.w+bb.w;
    ((float4*)(out + (size_t)row*DM))[l] = ov;
}

// ---------------- MFMA bf16 GEMM: 64x64 tile, fp32 in/out, bf16 staging ----------------
// out = op(A @ W + bias); ACT=gelu, RES=accumulate into out, QKV=[B,H,N,DH] scatter
template<int K, int N, int ACT, int RES, int QKV>
__global__ __launch_bounds__(256) void k_mgemm(const float* __restrict__ A, const float* __restrict__ W,
                                               const float* __restrict__ bias, float* __restrict__ out) {
    __shared__ __align__(16) short As[64][40];   // [m][k] bf16
    __shared__ __align__(16) short Bs[64][40];   // [n][k] bf16
    int r0 = blockIdx.x * 64;
    int n0 = blockIdx.y * 64;
    int tid = threadIdx.x;
    int w = tid >> 6, l = tid & 63;

    f32x4 acc[4];
    #pragma unroll
    for (int c = 0; c < 4; ++c) acc[c] = (f32x4){0.f,0.f,0.f,0.f};

    for (int k0 = 0; k0 < K; k0 += 32) {
        __syncthreads();
        // stage A tile (64 x 32) -> bf16
        {
            int m = tid >> 2, ks = (tid & 3) * 8;
            const float* src = A + (size_t)(r0 + m)*K + k0 + ks;
            float4 f0 = *(const float4*)src;
            float4 f1 = *(const float4*)(src + 4);
            short8 pk;
            pk[0]=f2bs(f0.x); pk[1]=f2bs(f0.y); pk[2]=f2bs(f0.z); pk[3]=f2bs(f0.w);
            pk[4]=f2bs(f1.x); pk[5]=f2bs(f1.y); pk[6]=f2bs(f1.z); pk[7]=f2bs(f1.w);
            *(short8*)&As[m][ks] = pk;
        }
        // stage B tile (32 x 64) transposed -> Bs[n][k] bf16
        {
            int n = tid & 63, kg = tid >> 6;
            const float* wp = W + (size_t)(k0 + kg*8)*N + n0 + n;
            short8 pk;
            #pragma unroll
            for (int j = 0; j < 8; ++j) pk[j] = f2bs(wp[(size_t)j*N]);
            *(short8*)&Bs[n][kg*8] = pk;
        }
        __syncthreads();
        short8 af = *(short8*)&As[w*16 + (l & 15)][(l >> 4)*8];
        #pragma unroll
        for (int c = 0; c < 4; ++c) {
            short8 bf = *(short8*)&Bs[c*16 + (l & 15)][(l >> 4)*8];
            acc[c] = __builtin_amdgcn_mfma_f32_16x16x32_bf16(af, bf, acc[c], 0, 0, 0);
        }
    }

    // epilogue: row = r0 + w*16 + quad*4 + reg, col = n0 + c*16 + (l&15)
    int quad = l >> 4;
    #pragma unroll
    for (int c = 0; c < 4; ++c) {
        int col = n0 + c*16 + (l & 15);
        float bv = bias[col];
        #pragma unroll
        for (int reg = 0; reg < 4; ++reg) {
            int row = r0 + w*16 + quad*4 + reg;
            float val = acc[c][reg] + bv;
            if (ACT) val = 0.5f * val * (1.0f + erff(val * 0.70710678118654752f));
            if (QKV) {
                int b = row >> 9, n = row & (NN-1);
                int hh = col >> 5, d = col & (DH-1);
                out[(size_t)((b*NH + hh)*NN + n)*DH + d] = val;
            } else if (RES) {
                out[(size_t)row*N + col] += val;
            } else {
                out[(size_t)row*N + col] = val;
            }
        }
    }
}

// ---------------- transpose bias table [M][256] -> [8][M][32] (for Vh/Ve) ----------------
__global__ __launch_bounds__(256) void k_tr(const float* __restrict__ in, float* __restrict__ out, int M) {
    int m = blockIdx.x, t = threadIdx.x;
    out[((size_t)(t >> 5)*M + m)*DH + (t & 31)] = in[(size_t)m*DM + t];
}

// ---------------- transpose bias table [M][256] -> [8][32][M] (d-major, for k_qhe) ----------------
__global__ __launch_bounds__(256) void k_trd(const float* __restrict__ in, float* __restrict__ out, int M) {
    int m = blockIdx.x, t = threadIdx.x;
    out[(size_t)t*M + m] = in[(size_t)m*DM + t];
}

// ---------------- k [bh][j][d] -> kT [bh][d][j] (64-j tile per block) ----------------
__global__ __launch_bounds__(256) void k_tx(const float* __restrict__ k, float* __restrict__ kT) {
    __shared__ float lds[64*33];
    int bh = blockIdx.x;
    int j0 = blockIdx.y * 64;
    int tid = threadIdx.x;
    {
        int jj = tid >> 2, d8 = tid & 3;
        const float* src = k + ((size_t)bh*NN + j0 + jj)*DH + d8*8;
        float4 a = *(const float4*)(src);
        float4 b = *(const float4*)(src + 4);
        float* dst = lds + jj*33 + d8*8;
        dst[0]=a.x; dst[1]=a.y; dst[2]=a.z; dst[3]=a.w;
        dst[4]=b.x; dst[5]=b.y; dst[6]=b.z; dst[7]=b.w;
    }
    __syncthreads();
    {
        int d = tid >> 3, jg = tid & 7;
        float* dst = kT + ((size_t)bh*DH + d)*NN + j0;
        #pragma unroll
        for (int jj2 = 0; jj2 < 8; ++jj2) {
            int j = jg*8 + jj2;
            dst[j] = lds[j*33 + d];
        }
    }
}

// ---------------- khT[bh,m,j] = sum_d kT[bh,d,j] * Kh[h,m,d]  (stored bf16) ----------------
__global__ __launch_bounds__(256) void k_kht(const float* __restrict__ kT, const float* __restrict__ k_hop,
                                             __hip_bfloat16* __restrict__ kht) {
    int bm = blockIdx.x;             // bh*NHOP + m
    int m = bm % NHOP;
    int bh = bm / NHOP;
    int hh = bh & (NH-1);
    float kh[32];
    {
        const float4* khp = (const float4*)(k_hop + (size_t)m*DM + hh*DH);
        #pragma unroll
        for (int c = 0; c < 8; ++c) *(float4*)&kh[c*4] = khp[c];
    }
    const float* kTb = kT + (size_t)bh*DH*NN;
    #pragma unroll
    for (int it = 0; it < 2; ++it) {
        int j = threadIdx.x + it*256;
        float acc = 0.f;
        #pragma unroll
        for (int d = 0; d < DH; ++d) acc += kh[d] * kTb[(size_t)d*NN + j];
        kht[(size_t)bm*NN + j] = __float2bfloat16(acc);
    }
}

// ---------------- qhe[bh][i][m] = q_i . Qh[m] (m<258) ; q_i.Qe[e] + k_i.Ke[e] (m=264+e) ----------------
__global__ __launch_bounds__(256) void k_qhe(const float* __restrict__ q, const float* __restrict__ k,
                                             const float* __restrict__ Qh_d, const float* __restrict__ Qe_d,
                                             const float* __restrict__ Ke_d, unsigned short* __restrict__ qhe) {
    int bh = blockIdx.x;
    int hh = bh & (NH-1);
    int i0 = blockIdx.y * 16;
    int tid = threadIdx.x;
    __shared__ __align__(16) float As[16][32];
    __shared__ __align__(16) float Ks[16][32];
    {
        int r = (tid & 127) >> 3, c4 = tid & 7;
        const float* src = ((tid < 128) ? q : k) + ((size_t)bh*NN + i0 + r)*DH + c4*4;
        float4 vv = *(const float4*)src;
        float* dst = (tid < 128) ? &As[r][c4*4] : &Ks[r][c4*4];
        *(float4*)dst = vv;
    }
    __syncthreads();
    {
        float acc[16];
        #pragma unroll
        for (int r = 0; r < 16; ++r) acc[r] = 0.f;
        const float* wb = Qh_d + (size_t)hh*32*NHOP + tid;
        for (int d = 0; d < 32; ++d) {
            float wv = wb[(size_t)d*NHOP];
            #pragma unroll
            for (int r = 0; r < 16; ++r) acc[r] += As[r][d] * wv;
        }
        #pragma unroll
        for (int r = 0; r < 16; ++r) {
            __hip_bfloat16 bv = __float2bfloat16(acc[r]);
            qhe[((size_t)bh*NN + i0 + r)*QHE_S + tid] = *(unsigned short*)&bv;
        }
    }
    if (tid < 2) {
        int m = 256 + tid;
        float acc[16];
        #pragma unroll
        for (int r = 0; r < 16; ++r) acc[r] = 0.f;
        const float* wb = Qh_d + (size_t)hh*32*NHOP + m;
        for (int d = 0; d < 32; ++d) {
            float wv = wb[(size_t)d*NHOP];
            #pragma unroll
            for (int r = 0; r < 16; ++r) acc[r] += As[r][d] * wv;
        }
        #pragma unroll
        for (int r = 0; r < 16; ++r) {
            __hip_bfloat16 bv = __float2bfloat16(acc[r]);
            qhe[((size_t)bh*NN + i0 + r)*QHE_S + m] = *(unsigned short*)&bv;
        }
    } else if (tid >= 8 && tid < 8 + NEDGE) {
        int e = tid - 8;
        float acc[16];
        #pragma unroll
        for (int r = 0; r < 16; ++r) acc[r] = 0.f;
        const float* wq = Qe_d + (size_t)hh*32*NEDGE + e;
        const float* wk = Ke_d + (size_t)hh*32*NEDGE + e;
        for (int d = 0; d < 32; ++d) {
            float a = wq[(size_t)d*NEDGE], bbw = wk[(size_t)d*NEDGE];
            #pragma unroll
            for (int r = 0; r < 16; ++r) acc[r] += As[r][d]*a + Ks[r][d]*bbw;
        }
        #pragma unroll
        for (int r = 0; r < 16; ++r) {
            __hip_bfloat16 bv = __float2bfloat16(acc[r]);
            qhe[((size_t)bh*NN + i0 + r)*QHE_S + 264 + e] = *(unsigned short*)&bv;
        }
    }
}

// ---------------- fused attention: block = (b, 4-i tile); 8 waves = 8 heads x 4 rows ----------------
__global__ __launch_bounds__(512) void k_attn(
    const float* __restrict__ q, const float* __restrict__ kT, const float* __restrict__ v,
    const __hip_bfloat16* __restrict__ kht, const int* __restrict__ dist, const int* __restrict__ edge,
    const unsigned char* __restrict__ mask, const unsigned short* __restrict__ qhe,
    const float* __restrict__ Vh_t, const float* __restrict__ Ve_t,
    float* __restrict__ ctx)
{
    int g  = blockIdx.x;
    int rr = g >> 3;
    int b  = (g & 7) + ((rr >> 7) << 3);
    int i0 = (rr & 127) * 4;
    int w  = threadIdx.x >> 6;
    int l  = threadIdx.x & 63;
    int bh = b*NH + w;

    __shared__ unsigned short mje[4][NN];
    __shared__ float qv[NH][4][DH];
    __shared__ __hip_bfloat16 pb[NH][4][NN];
    __shared__ float bins[NH][292];

    {
        int t = threadIdx.x;
        int row = t >> 7, c4 = t & 127;
        int4 dv = ((const int4*)(dist + ((size_t)(b*NN) + i0 + row)*NN))[c4];
        int4 ev = ((const int4*)(edge + ((size_t)(b*NN) + i0 + row)*NN))[c4];
        int m0 = dv.x > 256 ? 256 : dv.x; if (dv.x < 0) m0 = 257;
        int m1 = dv.y > 256 ? 256 : dv.y; if (dv.y < 0) m1 = 257;
        int m2 = dv.z > 256 ? 256 : dv.z; if (dv.z < 0) m2 = 257;
        int m3 = dv.w > 256 ? 256 : dv.w; if (dv.w < 0) m3 = 257;
        int e0 = ev.x > 25 ? 25 : ev.x; if (ev.x < 0) e0 = 26;
        int e1 = ev.y > 25 ? 25 : ev.y; if (ev.y < 0) e1 = 26;
        int e2 = ev.z > 25 ? 25 : ev.z; if (ev.z < 0) e2 = 26;
        int e3 = ev.w > 25 ? 25 : ev.w; if (ev.w < 0) e3 = 26;
        mje[row][c4*4+0] = (unsigned short)(m0 | (e0 << 9));
        mje[row][c4*4+1] = (unsigned short)(m1 | (e1 << 9));
        mje[row][c4*4+2] = (unsigned short)(m2 | (e2 << 9));
        mje[row][c4*4+3] = (unsigned short)(m3 | (e3 << 9));
        #pragma unroll
        for (int rep = 0; rep < 2; ++rep) {
            int i = rep*2 + (l >> 5), d = l & 31;
            qv[w][i][d] = q[((size_t)bh*NN + i0 + i)*DH + d];
        }
        for (int s = l; s < 292; s += 64) bins[w][s] = 0.f;
    }
    __syncthreads();

    float sc[4][8];
    #pragma unroll
    for (int i = 0; i < 4; ++i)
        #pragma unroll
        for (int s = 0; s < 8; ++s) sc[i][s] = 0.f;
    {
        const float* kTb = kT + (size_t)bh*DH*NN;
        for (int d = 0; d < 32; ++d) {
            const float* kr = kTb + (size_t)d*NN + l;
            float k0 = kr[0],   k1 = kr[64],  k2 = kr[128], k3 = kr[192];
            float k4 = kr[256], k5 = kr[320], k6 = kr[384], k7 = kr[448];
            float qa = qv[w][0][d], qb = qv[w][1][d], qc = qv[w][2][d], qd = qv[w][3][d];
            sc[0][0]+=qa*k0; sc[0][1]+=qa*k1; sc[0][2]+=qa*k2; sc[0][3]+=qa*k3;
            sc[0][4]+=qa*k4; sc[0][5]+=qa*k5; sc[0][6]+=qa*k6; sc[0][7]+=qa*k7;
            sc[1][0]+=qb*k0; sc[1][1]+=qb*k1; sc[1][2]+=qb*k2; sc[1][3]+=qb*k3;
            sc[1][4]+=qb*k4; sc[1][5]+=qb*k5; sc[1][6]+=qb*k6; sc[1][7]+=qb*k7;
            sc[2][0]+=qc*k0; sc[2][1]+=qc*k1; sc[2][2]+=qc*k2; sc[2][3]+=qc*k3;
            sc[2][4]+=qc*k4; sc[2][5]+=qc*k5; sc[2][6]+=qc*k6; sc[2][7]+=qc*k7;
            sc[3][0]+=qd*k0; sc[3][1]+=qd*k1; sc[3][2]+=qd*k2; sc[3][3]+=qd*k3;
            sc[3][4]+=qd*k4; sc[3][5]+=qd*k5; sc[3][6]+=qd*k6; sc[3][7]+=qd*k7;
        }
    }

    const __hip_bfloat16* khtb = kht + (size_t)bh*NHOP*NN;
    const unsigned char* mrow = mask + (size_t)b*NN;
    unsigned char msk[8];
    #pragma unroll
    for (int s = 0; s < 8; ++s) msk[s] = mrow[l + 64*s];

    int jc = l >> 3, d4 = l & 7;
    const float* vhb = Vh_t + (size_t)w*NHOP*DH + d4*4;
    const float* veb = Ve_t + (size_t)w*NEDGE*DH + d4*4;
    const float scale = 0.17677669529663687f;
    float4 acc[4];

    #pragma unroll
    for (int i = 0; i < 4; ++i) {
        const unsigned short* qhr = qhe + ((size_t)bh*NN + i0 + i)*QHE_S;
        int mv[8], ev[8];
        #pragma unroll
        for (int s = 0; s < 8; ++s) { int pk = mje[i][l + 64*s]; mv[s] = pk & 511; ev[s] = pk >> 9; }
        unsigned short raw[8];
        #pragma unroll
        for (int s = 0; s < 8; ++s) raw[s] = ((const unsigned short*)khtb)[(size_t)mv[s]*NN + l + 64*s];
        unsigned short qhv[8], qev[8];
        #pragma unroll
        for (int s = 0; s < 8; ++s) qhv[s] = qhr[mv[s]];
        #pragma unroll
        for (int s = 0; s < 8; ++s) qev[s] = qhr[264 + ev[s]];
        float x[8];
        #pragma unroll
        for (int s = 0; s < 8; ++s) {
            float a = (sc[i][s] + bf2f(qhv[s]) + bf2f(raw[s]) + bf2f(qev[s])) * scale;
            if (msk[s]) a = -INFINITY;
            x[s] = a;
        }
        float mx = x[0];
        #pragma unroll
        for (int s = 1; s < 8; ++s) mx = fmaxf(mx, x[s]);
        #pragma unroll
        for (int o = 32; o > 0; o >>= 1) mx = fmaxf(mx, __shfl_xor(mx, o, 64));
        float sum = 0.f;
        #pragma unroll
        for (int s = 0; s < 8; ++s) { x[s] = __expf(x[s] - mx); sum += x[s]; }
        #pragma unroll
        for (int o = 32; o > 0; o >>= 1) sum += __shfl_xor(sum, o, 64);
        float inv = 1.0f / sum;
        #pragma unroll
        for (int s = 0; s < 8; ++s) {
            float ps = x[s] * inv;
            pb[w][i][l + 64*s] = __float2bfloat16(ps);
            atomicAdd(&bins[w][mv[s]], ps);
            atomicAdd(&bins[w][264 + ev[s]], ps);
        }
        float4 a4; a4.x = a4.y = a4.z = a4.w = 0.f;
        for (int t = 0; t < 33; ++t) {
            int m = 8*t + jc;
            if (m < NHOP) {
                float bw = bins[w][m];
                float4 vv = *(const float4*)(vhb + (size_t)m*DH);
                a4.x += bw*vv.x; a4.y += bw*vv.y; a4.z += bw*vv.z; a4.w += bw*vv.w;
            }
        }
        #pragma unroll
        for (int t = 0; t < 4; ++t) {
            int e = 8*t + jc;
            if (e < NEDGE) {
                float bw = bins[w][264 + e];
                float4 vv = *(const float4*)(veb + (size_t)e*DH);
                a4.x += bw*vv.x; a4.y += bw*vv.y; a4.z += bw*vv.z; a4.w += bw*vv.w;
            }
        }
        acc[i] = a4;
        if (i < 3) {
            for (int s2 = l; s2 < 292; s2 += 64) bins[w][s2] = 0.f;
        }
    }

    {
        const float* vb = v + (size_t)bh*NN*DH + d4*4;
        for (int off = 0; off < 64; ++off) {
            int j = 8*off + jc;
            float4 vv = *(const float4*)(vb + (size_t)j*DH);
            #pragma unroll
            for (int i = 0; i < 4; ++i) {
                float p = bf2f(*(const unsigned short*)&pb[w][i][j]);
                acc[i].x += p*vv.x; acc[i].y += p*vv.y; acc[i].z += p*vv.z; acc[i].w += p*vv.w;
            }
        }
    }
    #pragma unroll
    for (int i = 0; i < 4; ++i) {
        #pragma unroll
        for (int o = 8; o <= 32; o <<= 1) {
            acc[i].x += __shfl_xor(acc[i].x, o, 64);
            acc[i].y += __shfl_xor(acc[i].y, o, 64);
            acc[i].z += __shfl_xor(acc[i].z, o, 64);
            acc[i].w += __shfl_xor(acc[i].w, o, 64);
        }
        if (jc == 0) {
            *(float4*)(ctx + ((size_t)b*NN + i0 + i)*DM + w*DH + d4*4) = acc[i];
        }
    }
}

extern "C" void kernel_launch(void* const* d_in, const int* in_sizes, int n_in,
                              void* d_out, int out_size, void* d_ws, size_t ws_size,
                              hipStream_t stream) {
    const float* x     = (const float*)d_in[0];
    const unsigned char* mask = (const unsigned char*)d_in[1];
    const int*   dist  = (const int*)d_in[2];
    const int*   edge  = (const int*)d_in[3];
    const float* node_W = (const float*)d_in[4];
    const float* node_b = (const float*)d_in[5];
    const float* ln1_g = (const float*)d_in[6];
    const float* ln1_b = (const float*)d_in[7];
    const float* Wq = (const float*)d_in[8];
    const float* bq = (const float*)d_in[9];
    const float* Wk = (const float*)d_in[10];
    const float* bk = (const float*)d_in[11];
    const float* Wv = (const float*)d_in[12];
    const float* bv = (const float*)d_in[13];
    const float* Wo = (const float*)d_in[14];
    const float* bo = (const float*)d_in[15];
    const float* ln2_g = (const float*)d_in[16];
    const float* ln2_b = (const float*)d_in[17];
    const float* W1 = (const float*)d_in[18];
    const float* b1 = (const float*)d_in[19];
    const float* W2 = (const float*)d_in[20];
    const float* b2 = (const float*)d_in[21];
    const float* q_hop  = (const float*)d_in[22];
    const float* q_edge = (const float*)d_in[23];
    const float* k_hop  = (const float*)d_in[24];
    const float* k_edge = (const float*)d_in[25];
    const float* v_hop  = (const float*)d_in[26];
    const float* v_edge = (const float*)d_in[27];
    const float* fln_g = (const float*)d_in[28];
    const float* fln_b = (const float*)d_in[29];
    const float* out_W = (const float*)d_in[30];
    const float* out_b = (const float*)d_in[31];
    float* out = (float*)d_out;

    float* ws = (float*)d_ws;
    float* h   = ws + 0;                         //  2,097,152
    float* y   = ws + 2097152;                   //  2,097,152
    float* q   = ws + 4194304;                   //  2,097,152  [B,H,N,DH]
    float* k   = ws + 6291456;                   //  2,097,152
    float* v   = ws + 8388608;                   //  2,097,152
    float* ctx = ws + 10485760;                  //  2,097,152
    __hip_bfloat16* kht = (__hip_bfloat16*)(ws + 12582912);  // 16,908,288 bf16 (8,454,144 floats)
    float* ffn = ws + 12582912;                  //  8,388,608 floats (aliases kht, dead by then)
    float* kT  = ws + 21037056;                  //  2,097,152  [B,H,DH,NN]
    unsigned short* qhe = (unsigned short*)(ws + 23134208);  // 128*512*296 ushort
    float* Vh_t = y + 0;                         // tables alias y (dead between qkv and ln2)
    float* Ve_t = y + 66048;
    float* Qh_d = y + 72960;
    float* Qe_d = y + 139008;
    float* Ke_d = y + 145920;

    k_mgemm<DIN, DM, 0, 0, 0><<<dim3(ROWS/64, DM/64), 256, 0, stream>>>(x, node_W, node_b, h);
    k_ln<<<ROWS/4, 256, 0, stream>>>(h, ln1_g, ln1_b, y);
    k_mgemm<DM, DM, 0, 0, 1><<<dim3(ROWS/64, DM/64), 256, 0, stream>>>(y, Wq, bq, q);
    k_mgemm<DM, DM, 0, 0, 1><<<dim3(ROWS/64, DM/64), 256, 0, stream>>>(y, Wk, bk, k);
    k_mgemm<DM, DM, 0, 0, 1><<<dim3(ROWS/64, DM/64), 256, 0, stream>>>(y, Wv, bv, v);
    // y now dead -> build tables
    k_tr <<<NHOP, 256, 0, stream>>>(v_hop, Vh_t, NHOP);
    k_tr <<<NEDGE, 256, 0, stream>>>(v_edge, Ve_t, NEDGE);
    k_trd<<<NHOP, 256, 0, stream>>>(q_hop, Qh_d, NHOP);
    k_trd<<<NEDGE, 256, 0, stream>>>(q_edge, Qe_d, NEDGE);
    k_trd<<<NEDGE, 256, 0, stream>>>(k_edge, Ke_d, NEDGE);
    k_tx<<<dim3(BB*NH, 8), 256, 0, stream>>>(k, kT);
    k_kht<<<BB*NH*NHOP, 256, 0, stream>>>(kT, k_hop, kht);
    k_qhe<<<dim3(BB*NH, NN/16), 256, 0, stream>>>(q, k, Qh_d, Qe_d, Ke_d, qhe);
    k_attn<<<BB*(NN/4), 512, 0, stream>>>(q, kT, v, kht, dist, edge, mask, qhe,
                                          Vh_t, Ve_t, ctx);
    k_mgemm<DM, DM, 0, 1, 0><<<dim3(ROWS/64, DM/64), 256, 0, stream>>>(ctx, Wo, bo, h);
    k_ln<<<ROWS/4, 256, 0, stream>>>(h, ln2_g, ln2_b, y);
    k_mgemm<DM, FF, 1, 0, 0><<<dim3(ROWS/64, FF/64), 256, 0, stream>>>(y, W1, b1, ffn);
    k_mgemm<FF, DM, 0, 1, 0><<<dim3(ROWS/64, DM/64), 256, 0, stream>>>(ffn, W2, b2, h);
    k_ln<<<ROWS/4, 256, 0, stream>>>(h, fln_g, fln_b, y);
    k_mgemm<DM, DOUT, 0, 0, 0><<<dim3(ROWS/64, DOUT/64), 256, 0, stream>>>(y, out_W, out_b, out);
}

// Round 9
// 866.532 us; speedup vs baseline: 3.4590x; 1.0077x over previous
//
#include <hip/hip_runtime.h>
#include <hip/hip_bf16.h>
#include <math.h>

#define BB 16
#define NN 512
#define DIN 128
#define DM 256
#define NH 8
#define DH 32
#define FF 1024
#define DOUT 128
#define NHOP 258
#define NEDGE 27
#define ROWS (BB*NN)   // 8192
#define QHE_S 296      // qhe row stride (ushorts): qh 0..257, qec at 264..290; reused as vha bins after k_score

typedef short short8 __attribute__((ext_vector_type(8)));
typedef float f32x4 __attribute__((ext_vector_type(4)));

static __device__ __forceinline__ float bf2f(unsigned short u) {
    union { float f; unsigned int i; } c; c.i = ((unsigned int)u) << 16; return c.f;
}
static __device__ __forceinline__ short f2bs(float f) {
    __hip_bfloat16 h = __float2bfloat16(f);
    return *reinterpret_cast<short*>(&h);
}

// ---------------- layernorm: one wave per row, float4 + shuffle ----------------
__global__ __launch_bounds__(256) void k_ln(const float* __restrict__ in, const float* __restrict__ g,
                                            const float* __restrict__ bta, float* __restrict__ out) {
    int row = blockIdx.x * 4 + (threadIdx.x >> 6);
    int l = threadIdx.x & 63;
    float4 xv = ((const float4*)(in + (size_t)row*DM))[l];
    float s = xv.x + xv.y + xv.z + xv.w;
    #pragma unroll
    for (int o = 32; o > 0; o >>= 1) s += __shfl_xor(s, o, 64);
    float mean = s * (1.0f/DM);
    float dx = xv.x-mean, dy = xv.y-mean, dz = xv.z-mean, dw = xv.w-mean;
    float vs = dx*dx + dy*dy + dz*dz + dw*dw;
    #pragma unroll
    for (int o = 32; o > 0; o >>= 1) vs += __shfl_xor(vs, o, 64);
    float r = rsqrtf(vs * (1.0f/DM) + 1e-5f);
    float4 gg = ((const float4*)g)[l];
    float4 bb = ((const float4*)bta)[l];
    float4 ov; ov.x = dx*r*gg.x+bb.x; ov.y = dy*r*gg.y+bb.y; ov.z = dz*r*gg.z+bb.z; ov.w = dw*r*gg.w+bb.w;
    ((float4*)(out + (size_t)row*DM))[l] = ov;
}

// ---------------- MFMA bf16 GEMM: 64x64 tile, fp32 in/out, bf16 staging ----------------
template<int K, int N, int ACT, int RES, int QKV>
__global__ __launch_bounds__(256) void k_mgemm(const float* __restrict__ A, const float* __restrict__ W,
                                               const float* __restrict__ bias, float* __restrict__ out) {
    __shared__ __align__(16) short As[64][40];   // [m][k] bf16
    __shared__ __align__(16) short Bs[64][40];   // [n][k] bf16
    int r0 = blockIdx.x * 64;
    int n0 = blockIdx.y * 64;
    int tid = threadIdx.x;
    int w = tid >> 6, l = tid & 63;

    f32x4 acc[4];
    #pragma unroll
    for (int c = 0; c < 4; ++c) acc[c] = (f32x4){0.f,0.f,0.f,0.f};

    for (int k0 = 0; k0 < K; k0 += 32) {
        __syncthreads();
        {
            int m = tid >> 2, ks = (tid & 3) * 8;
            const float* src = A + (size_t)(r0 + m)*K + k0 + ks;
            float4 f0 = *(const float4*)src;
            float4 f1 = *(const float4*)(src + 4);
            short8 pk;
            pk[0]=f2bs(f0.x); pk[1]=f2bs(f0.y); pk[2]=f2bs(f0.z); pk[3]=f2bs(f0.w);
            pk[4]=f2bs(f1.x); pk[5]=f2bs(f1.y); pk[6]=f2bs(f1.z); pk[7]=f2bs(f1.w);
            *(short8*)&As[m][ks] = pk;
        }
        {
            int n = tid & 63, kg = tid >> 6;
            const float* wp = W + (size_t)(k0 + kg*8)*N + n0 + n;
            short8 pk;
            #pragma unroll
            for (int j = 0; j < 8; ++j) pk[j] = f2bs(wp[(size_t)j*N]);
            *(short8*)&Bs[n][kg*8] = pk;
        }
        __syncthreads();
        short8 af = *(short8*)&As[w*16 + (l & 15)][(l >> 4)*8];
        #pragma unroll
        for (int c = 0; c < 4; ++c) {
            short8 bf = *(short8*)&Bs[c*16 + (l & 15)][(l >> 4)*8];
            acc[c] = __builtin_amdgcn_mfma_f32_16x16x32_bf16(af, bf, acc[c], 0, 0, 0);
        }
    }

    int quad = l >> 4;
    #pragma unroll
    for (int c = 0; c < 4; ++c) {
        int col = n0 + c*16 + (l & 15);
        float bv = bias[col];
        #pragma unroll
        for (int reg = 0; reg < 4; ++reg) {
            int row = r0 + w*16 + quad*4 + reg;
            float val = acc[c][reg] + bv;
            if (ACT) val = 0.5f * val * (1.0f + erff(val * 0.70710678118654752f));
            if (QKV) {
                int b = row >> 9, n = row & (NN-1);
                int hh = col >> 5, d = col & (DH-1);
                out[(size_t)((b*NH + hh)*NN + n)*DH + d] = val;
            } else if (RES) {
                out[(size_t)row*N + col] += val;
            } else {
                out[(size_t)row*N + col] = val;
            }
        }
    }
}

// ---------------- transpose bias table [M][256] -> [8][32][M] (d-major, for k_qhe) ----------------
__global__ __launch_bounds__(256) void k_trd(const float* __restrict__ in, float* __restrict__ out, int M) {
    int m = blockIdx.x, t = threadIdx.x;
    out[(size_t)t*M + m] = in[(size_t)m*DM + t];
}

// ---------------- build vhve[h][296][32]: hop rows 0..257, edge rows 264..290, rest 0 ----------------
__global__ __launch_bounds__(256) void k_vhve(const float* __restrict__ vh, const float* __restrict__ ve,
                                              float* __restrict__ out) {
    int m = blockIdx.x;  // 0..295
    int t = threadIdx.x; // h*32+d
    float val = 0.f;
    if (m < NHOP) val = vh[(size_t)m*DM + t];
    else if (m >= 264 && m < 264 + NEDGE) val = ve[(size_t)(m - 264)*DM + t];
    out[((size_t)(t >> 5)*QHE_S + m)*DH + (t & 31)] = val;
}

// ---------------- k [bh][j][d] -> kT [bh][d][j] (64-j tile per block) ----------------
__global__ __launch_bounds__(256) void k_tx(const float* __restrict__ k, float* __restrict__ kT) {
    __shared__ float lds[64*33];
    int bh = blockIdx.x;
    int j0 = blockIdx.y * 64;
    int tid = threadIdx.x;
    {
        int jj = tid >> 2, d8 = tid & 3;
        const float* src = k + ((size_t)bh*NN + j0 + jj)*DH + d8*8;
        float4 a = *(const float4*)(src);
        float4 b = *(const float4*)(src + 4);
        float* dst = lds + jj*33 + d8*8;
        dst[0]=a.x; dst[1]=a.y; dst[2]=a.z; dst[3]=a.w;
        dst[4]=b.x; dst[5]=b.y; dst[6]=b.z; dst[7]=b.w;
    }
    __syncthreads();
    {
        int d = tid >> 3, jg = tid & 7;
        float* dst = kT + ((size_t)bh*DH + d)*NN + j0;
        #pragma unroll
        for (int jj2 = 0; jj2 < 8; ++jj2) {
            int j = jg*8 + jj2;
            dst[j] = lds[j*33 + d];
        }
    }
}

// ---------------- khT[bh,m,j] = sum_d kT[bh,d,j] * Kh[h,m,d]  (stored bf16) ----------------
__global__ __launch_bounds__(256) void k_kht(const float* __restrict__ kT, const float* __restrict__ k_hop,
                                             __hip_bfloat16* __restrict__ kht) {
    int bm = blockIdx.x;             // bh*NHOP + m
    int m = bm % NHOP;
    int bh = bm / NHOP;
    int hh = bh & (NH-1);
    float kh[32];
    {
        const float4* khp = (const float4*)(k_hop + (size_t)m*DM + hh*DH);
        #pragma unroll
        for (int c = 0; c < 8; ++c) *(float4*)&kh[c*4] = khp[c];
    }
    const float* kTb = kT + (size_t)bh*DH*NN;
    #pragma unroll
    for (int it = 0; it < 2; ++it) {
        int j = threadIdx.x + it*256;
        float acc = 0.f;
        #pragma unroll
        for (int d = 0; d < DH; ++d) acc += kh[d] * kTb[(size_t)d*NN + j];
        kht[(size_t)bm*NN + j] = __float2bfloat16(acc);
    }
}

// ---------------- qhe[bh][i][m] = q_i . Qh[m] (m<258) ; q_i.Qe[e] + k_i.Ke[e] (m=264+e) ----------------
__global__ __launch_bounds__(256) void k_qhe(const float* __restrict__ q, const float* __restrict__ k,
                                             const float* __restrict__ Qh_d, const float* __restrict__ Qe_d,
                                             const float* __restrict__ Ke_d, unsigned short* __restrict__ qhe) {
    int bh = blockIdx.x;
    int hh = bh & (NH-1);
    int i0 = blockIdx.y * 16;
    int tid = threadIdx.x;
    __shared__ __align__(16) float As[16][32];
    __shared__ __align__(16) float Ks[16][32];
    {
        int r = (tid & 127) >> 3, c4 = tid & 7;
        const float* src = ((tid < 128) ? q : k) + ((size_t)bh*NN + i0 + r)*DH + c4*4;
        float4 vv = *(const float4*)src;
        float* dst = (tid < 128) ? &As[r][c4*4] : &Ks[r][c4*4];
        *(float4*)dst = vv;
    }
    __syncthreads();
    {
        float acc[16];
        #pragma unroll
        for (int r = 0; r < 16; ++r) acc[r] = 0.f;
        const float* wb = Qh_d + (size_t)hh*32*NHOP + tid;
        for (int d = 0; d < 32; ++d) {
            float wv = wb[(size_t)d*NHOP];
            #pragma unroll
            for (int r = 0; r < 16; ++r) acc[r] += As[r][d] * wv;
        }
        #pragma unroll
        for (int r = 0; r < 16; ++r)
            qhe[((size_t)bh*NN + i0 + r)*QHE_S + tid] = (unsigned short)f2bs(acc[r]);
    }
    if (tid < 2) {
        int m = 256 + tid;
        float acc[16];
        #pragma unroll
        for (int r = 0; r < 16; ++r) acc[r] = 0.f;
        const float* wb = Qh_d + (size_t)hh*32*NHOP + m;
        for (int d = 0; d < 32; ++d) {
            float wv = wb[(size_t)d*NHOP];
            #pragma unroll
            for (int r = 0; r < 16; ++r) acc[r] += As[r][d] * wv;
        }
        #pragma unroll
        for (int r = 0; r < 16; ++r)
            qhe[((size_t)bh*NN + i0 + r)*QHE_S + m] = (unsigned short)f2bs(acc[r]);
    } else if (tid >= 8 && tid < 8 + NEDGE) {
        int e = tid - 8;
        float acc[16];
        #pragma unroll
        for (int r = 0; r < 16; ++r) acc[r] = 0.f;
        const float* wq = Qe_d + (size_t)hh*32*NEDGE + e;
        const float* wk = Ke_d + (size_t)hh*32*NEDGE + e;
        for (int d = 0; d < 32; ++d) {
            float a = wq[(size_t)d*NEDGE], bbw = wk[(size_t)d*NEDGE];
            #pragma unroll
            for (int r = 0; r < 16; ++r) acc[r] += As[r][d]*a + Ks[r][d]*bbw;
        }
        #pragma unroll
        for (int r = 0; r < 16; ++r)
            qhe[((size_t)bh*NN + i0 + r)*QHE_S + 264 + e] = (unsigned short)f2bs(acc[r]);
    }
}

// ---------------- k_score: block = (b, 4-i tile, head-half); 4 waves = 4 heads ----------------
// Produces: ctx (dense AV part) and vha bins written OVER the qhe rows it consumed.
__global__ __launch_bounds__(256) void k_score(
    const float* __restrict__ q, const float* __restrict__ kT, const float* __restrict__ v,
    const __hip_bfloat16* __restrict__ kht, const int* __restrict__ dist, const int* __restrict__ edge,
    const unsigned char* __restrict__ mask, unsigned short* __restrict__ qhe,
    float* __restrict__ ctx)
{
    int g   = blockIdx.x;            // 4096
    int r   = g >> 3;                // 0..511
    int b   = (g & 7) + ((r >> 8) << 3);
    int rem = r & 255;
    int i0  = (rem >> 1) * 4;
    int hg  = rem & 1;
    int w   = threadIdx.x >> 6;
    int l   = threadIdx.x & 63;
    int hh  = hg*4 + w;
    int bh  = b*NH + hh;

    __shared__ unsigned short mje[4][NN];        // m | (e<<9)
    __shared__ float qv[4][4][DH];
    __shared__ __hip_bfloat16 pb[4][4][NN];
    __shared__ float bins[4][292];

    // ---- phase A ----
    {
        int t = threadIdx.x;
        int row = t >> 6, c0 = t & 63;
        #pragma unroll
        for (int rep = 0; rep < 2; ++rep) {
            int c4 = c0 + rep*64;
            int4 dv = ((const int4*)(dist + ((size_t)(b*NN) + i0 + row)*NN))[c4];
            int4 ev = ((const int4*)(edge + ((size_t)(b*NN) + i0 + row)*NN))[c4];
            int m0 = dv.x > 256 ? 256 : dv.x; if (dv.x < 0) m0 = 257;
            int m1 = dv.y > 256 ? 256 : dv.y; if (dv.y < 0) m1 = 257;
            int m2 = dv.z > 256 ? 256 : dv.z; if (dv.z < 0) m2 = 257;
            int m3 = dv.w > 256 ? 256 : dv.w; if (dv.w < 0) m3 = 257;
            int e0 = ev.x > 25 ? 25 : ev.x; if (ev.x < 0) e0 = 26;
            int e1 = ev.y > 25 ? 25 : ev.y; if (ev.y < 0) e1 = 26;
            int e2 = ev.z > 25 ? 25 : ev.z; if (ev.z < 0) e2 = 26;
            int e3 = ev.w > 25 ? 25 : ev.w; if (ev.w < 0) e3 = 26;
            mje[row][c4*4+0] = (unsigned short)(m0 | (e0 << 9));
            mje[row][c4*4+1] = (unsigned short)(m1 | (e1 << 9));
            mje[row][c4*4+2] = (unsigned short)(m2 | (e2 << 9));
            mje[row][c4*4+3] = (unsigned short)(m3 | (e3 << 9));
        }
        #pragma unroll
        for (int rep = 0; rep < 2; ++rep) {
            int i = rep*2 + (l >> 5), d = l & 31;
            qv[w][i][d] = q[((size_t)bh*NN + i0 + i)*DH + d];
        }
        for (int s = l; s < 292; s += 64) bins[w][s] = 0.f;
    }
    __syncthreads();

    // ---- d-loop: QK^T for 4 rows, lane-contiguous kT reads ----
    float sc[4][8];
    #pragma unroll
    for (int i = 0; i < 4; ++i)
        #pragma unroll
        for (int s = 0; s < 8; ++s) sc[i][s] = 0.f;
    {
        const float* kTb = kT + (size_t)bh*DH*NN;
        for (int d = 0; d < 32; ++d) {
            const float* kr = kTb + (size_t)d*NN + l;
            float k0 = kr[0],   k1 = kr[64],  k2 = kr[128], k3 = kr[192];
            float k4 = kr[256], k5 = kr[320], k6 = kr[384], k7 = kr[448];
            float qa = qv[w][0][d], qb = qv[w][1][d], qc = qv[w][2][d], qd = qv[w][3][d];
            sc[0][0]+=qa*k0; sc[0][1]+=qa*k1; sc[0][2]+=qa*k2; sc[0][3]+=qa*k3;
            sc[0][4]+=qa*k4; sc[0][5]+=qa*k5; sc[0][6]+=qa*k6; sc[0][7]+=qa*k7;
            sc[1][0]+=qb*k0; sc[1][1]+=qb*k1; sc[1][2]+=qb*k2; sc[1][3]+=qb*k3;
            sc[1][4]+=qb*k4; sc[1][5]+=qb*k5; sc[1][6]+=qb*k6; sc[1][7]+=qb*k7;
            sc[2][0]+=qc*k0; sc[2][1]+=qc*k1; sc[2][2]+=qc*k2; sc[2][3]+=qc*k3;
            sc[2][4]+=qc*k4; sc[2][5]+=qc*k5; sc[2][6]+=qc*k6; sc[2][7]+=qc*k7;
            sc[3][0]+=qd*k0; sc[3][1]+=qd*k1; sc[3][2]+=qd*k2; sc[3][3]+=qd*k3;
            sc[3][4]+=qd*k4; sc[3][5]+=qd*k5; sc[3][6]+=qd*k6; sc[3][7]+=qd*k7;
        }
    }

    const __hip_bfloat16* khtb = kht + (size_t)bh*NHOP*NN;
    const unsigned char* mrow = mask + (size_t)b*NN;
    unsigned char msk[8];
    #pragma unroll
    for (int s = 0; s < 8; ++s) msk[s] = mrow[l + 64*s];
    const float scale = 0.17677669529663687f;

    // ---- per-i: bias gather + softmax + bins -> vha row ----
    #pragma unroll
    for (int i = 0; i < 4; ++i) {
        unsigned short* qhr = qhe + ((size_t)bh*NN + i0 + i)*QHE_S;
        int pk[8];
        #pragma unroll
        for (int s = 0; s < 8; ++s) pk[s] = mje[i][l + 64*s];
        unsigned short raw[8];
        #pragma unroll
        for (int s = 0; s < 8; ++s)
            raw[s] = ((const unsigned short*)khtb)[(size_t)(pk[s] & 511)*NN + l + 64*s];
        unsigned short qhv[8], qev[8];
        #pragma unroll
        for (int s = 0; s < 8; ++s) qhv[s] = qhr[pk[s] & 511];
        #pragma unroll
        for (int s = 0; s < 8; ++s) qev[s] = qhr[264 + (pk[s] >> 9)];
        float x[8];
        #pragma unroll
        for (int s = 0; s < 8; ++s) {
            float a = (sc[i][s] + bf2f(qhv[s]) + bf2f(raw[s]) + bf2f(qev[s])) * scale;
            if (msk[s]) a = -INFINITY;
            x[s] = a;
        }
        float mx = x[0];
        #pragma unroll
        for (int s = 1; s < 8; ++s) mx = fmaxf(mx, x[s]);
        #pragma unroll
        for (int o = 32; o > 0; o >>= 1) mx = fmaxf(mx, __shfl_xor(mx, o, 64));
        float sum = 0.f;
        #pragma unroll
        for (int s = 0; s < 8; ++s) { x[s] = __expf(x[s] - mx); sum += x[s]; }
        #pragma unroll
        for (int o = 32; o > 0; o >>= 1) sum += __shfl_xor(sum, o, 64);
        float inv = 1.0f / sum;
        #pragma unroll
        for (int s = 0; s < 8; ++s) {
            float ps = x[s] * inv;
            pb[w][i][l + 64*s] = __float2bfloat16(ps);
            atomicAdd(&bins[w][pk[s] & 511], ps);
            atomicAdd(&bins[w][264 + (pk[s] >> 9)], ps);
        }
        // write bins over the (now fully consumed) qhe row -> vha row; then reset
        #pragma unroll
        for (int s5 = 0; s5 < 5; ++s5) {
            int idx = l + 64*s5;
            if (idx < 292) {
                qhr[idx] = (unsigned short)f2bs(bins[w][idx]);
                if (i < 3) bins[w][idx] = 0.f;
            }
        }
    }

    // ---- D1: dense AV, v loads shared across the 4 rows ----
    int jc = l >> 3, d4 = l & 7;
    float4 acc[4];
    #pragma unroll
    for (int i = 0; i < 4; ++i) { acc[i].x = acc[i].y = acc[i].z = acc[i].w = 0.f; }
    {
        const float* vb = v + (size_t)bh*NN*DH + d4*4;
        for (int off = 0; off < 64; ++off) {
            int j = 8*off + jc;
            float4 vv = *(const float4*)(vb + (size_t)j*DH);
            #pragma unroll
            for (int i = 0; i < 4; ++i) {
                float p = bf2f(*(const unsigned short*)&pb[w][i][j]);
                acc[i].x += p*vv.x; acc[i].y += p*vv.y; acc[i].z += p*vv.z; acc[i].w += p*vv.w;
            }
        }
    }
    #pragma unroll
    for (int i = 0; i < 4; ++i) {
        #pragma unroll
        for (int o = 8; o <= 32; o <<= 1) {
            acc[i].x += __shfl_xor(acc[i].x, o, 64);
            acc[i].y += __shfl_xor(acc[i].y, o, 64);
            acc[i].z += __shfl_xor(acc[i].z, o, 64);
            acc[i].w += __shfl_xor(acc[i].w, o, 64);
        }
        if (jc == 0) {
            *(float4*)(ctx + ((size_t)b*NN + i0 + i)*DM + hh*DH + d4*4) = acc[i];
        }
    }
}

// ---------------- k_av: ctx[b,i,h*32+d] += sum_m vha[bh,i,m] * vhve[h][m][d] ----------------
__global__ __launch_bounds__(512) void k_av(const unsigned short* __restrict__ vha,
                                            const float* __restrict__ vhve, float* __restrict__ ctx) {
    int bh = blockIdx.x;          // 0..127
    int hh = bh & (NH-1);
    int b  = bh >> 3;
    int i0 = blockIdx.y * 16;
    __shared__ unsigned short lds[16*QHE_S];
    int tid = threadIdx.x;
    for (int idx = tid; idx < 16*QHE_S; idx += 512) {
        int rr = idx / QHE_S, c = idx - rr*QHE_S;
        lds[idx] = vha[((size_t)bh*NN + i0 + rr)*QHE_S + c];
    }
    __syncthreads();
    int i = tid >> 5, d = tid & 31;
    const float* tb = vhve + (size_t)hh*QHE_S*DH + d;
    const unsigned short* pr = &lds[i*QHE_S];
    float acc = 0.f;
    #pragma unroll 4
    for (int m = 0; m < 292; ++m) {
        acc += bf2f(pr[m]) * tb[(size_t)m*DH];
    }
    ctx[((size_t)b*NN + i0 + i)*DM + hh*DH + d] += acc;
}

extern "C" void kernel_launch(void* const* d_in, const int* in_sizes, int n_in,
                              void* d_out, int out_size, void* d_ws, size_t ws_size,
                              hipStream_t stream) {
    const float* x     = (const float*)d_in[0];
    const unsigned char* mask = (const unsigned char*)d_in[1];
    const int*   dist  = (const int*)d_in[2];
    const int*   edge  = (const int*)d_in[3];
    const float* node_W = (const float*)d_in[4];
    const float* node_b = (const float*)d_in[5];
    const float* ln1_g = (const float*)d_in[6];
    const float* ln1_b = (const float*)d_in[7];
    const float* Wq = (const float*)d_in[8];
    const float* bq = (const float*)d_in[9];
    const float* Wk = (const float*)d_in[10];
    const float* bk = (const float*)d_in[11];
    const float* Wv = (const float*)d_in[12];
    const float* bv = (const float*)d_in[13];
    const float* Wo = (const float*)d_in[14];
    const float* bo = (const float*)d_in[15];
    const float* ln2_g = (const float*)d_in[16];
    const float* ln2_b = (const float*)d_in[17];
    const float* W1 = (const float*)d_in[18];
    const float* b1 = (const float*)d_in[19];
    const float* W2 = (const float*)d_in[20];
    const float* b2 = (const float*)d_in[21];
    const float* q_hop  = (const float*)d_in[22];
    const float* q_edge = (const float*)d_in[23];
    const float* k_hop  = (const float*)d_in[24];
    const float* k_edge = (const float*)d_in[25];
    const float* v_hop  = (const float*)d_in[26];
    const float* v_edge = (const float*)d_in[27];
    const float* fln_g = (const float*)d_in[28];
    const float* fln_b = (const float*)d_in[29];
    const float* out_W = (const float*)d_in[30];
    const float* out_b = (const float*)d_in[31];
    float* out = (float*)d_out;

    float* ws = (float*)d_ws;
    float* h   = ws + 0;                         //  2,097,152
    float* y   = ws + 2097152;                   //  2,097,152
    float* q   = ws + 4194304;                   //  2,097,152  [B,H,N,DH]
    float* k   = ws + 6291456;                   //  2,097,152
    float* v   = ws + 8388608;                   //  2,097,152
    float* ctx = ws + 10485760;                  //  2,097,152
    __hip_bfloat16* kht = (__hip_bfloat16*)(ws + 12582912);  // 16,908,288 bf16 (8,454,144 floats)
    float* ffn = ws + 12582912;                  //  8,388,608 floats (aliases kht, dead by then)
    float* kT  = ws + 21037056;                  //  2,097,152  [B,H,DH,NN]
    unsigned short* qhe = (unsigned short*)(ws + 23134208);  // 128*512*296 ushort; becomes vha in k_score
    float* Qh_d = y + 0;                         // tables alias y (dead between qkv and ln2)
    float* Qe_d = y + 66048;
    float* Ke_d = y + 72960;
    float* vhve = y + 81920;                     // 8*296*32 = 75,776 floats

    k_mgemm<DIN, DM, 0, 0, 0><<<dim3(ROWS/64, DM/64), 256, 0, stream>>>(x, node_W, node_b, h);
    k_ln<<<ROWS/4, 256, 0, stream>>>(h, ln1_g, ln1_b, y);
    k_mgemm<DM, DM, 0, 0, 1><<<dim3(ROWS/64, DM/64), 256, 0, stream>>>(y, Wq, bq, q);
    k_mgemm<DM, DM, 0, 0, 1><<<dim3(ROWS/64, DM/64), 256, 0, stream>>>(y, Wk, bk, k);
    k_mgemm<DM, DM, 0, 0, 1><<<dim3(ROWS/64, DM/64), 256, 0, stream>>>(y, Wv, bv, v);
    // y now dead -> build tables
    k_trd<<<NHOP, 256, 0, stream>>>(q_hop, Qh_d, NHOP);
    k_trd<<<NEDGE, 256, 0, stream>>>(q_edge, Qe_d, NEDGE);
    k_trd<<<NEDGE, 256, 0, stream>>>(k_edge, Ke_d, NEDGE);
    k_vhve<<<QHE_S, 256, 0, stream>>>(v_hop, v_edge, vhve);
    k_tx<<<dim3(BB*NH, 8), 256, 0, stream>>>(k, kT);
    k_kht<<<BB*NH*NHOP, 256, 0, stream>>>(kT, k_hop, kht);
    k_qhe<<<dim3(BB*NH, NN/16), 256, 0, stream>>>(q, k, Qh_d, Qe_d, Ke_d, qhe);
    k_score<<<BB*(NN/4)*2, 256, 0, stream>>>(q, kT, v, kht, dist, edge, mask, qhe, ctx);
    k_av<<<dim3(BB*NH, NN/16), 512, 0, stream>>>(qhe, vhve, ctx);
    k_mgemm<DM, DM, 0, 1, 0><<<dim3(ROWS/64, DM/64), 256, 0, stream>>>(ctx, Wo, bo, h);
    k_ln<<<ROWS/4, 256, 0, stream>>>(h, ln2_g, ln2_b, y);
    k_mgemm<DM, FF, 1, 0, 0><<<dim3(ROWS/64, FF/64), 256, 0, stream>>>(y, W1, b1, ffn);
    k_mgemm<FF, DM, 0, 1, 0><<<dim3(ROWS/64, DM/64), 256, 0, stream>>>(ffn, W2, b2, h);
    k_ln<<<ROWS/4, 256, 0, stream>>>(h, fln_g, fln_b, y);
    k_mgemm<DM, DOUT, 0, 0, 0><<<dim3(ROWS/64, DOUT/64), 256, 0, stream>>>(y, out_W, out_b, out);
}

// Round 10
// 739.522 us; speedup vs baseline: 4.0530x; 1.1717x over previous
//
#include <hip/hip_runtime.h>
#include <hip/hip_bf16.h>
#include <math.h>

#define BB 16
#define NN 512
#define DIN 128
#define DM 256
#define NH 8
#define DH 32
#define FF 1024
#define DOUT 128
#define NHOP 258
#define NEDGE 27
#define ROWS (BB*NN)   // 8192
#define QHE_S 296      // qhe row stride (ushorts): qh 0..257, qec at 264..290; becomes vha bins after k_score

typedef short short8 __attribute__((ext_vector_type(8)));
typedef float f32x4 __attribute__((ext_vector_type(4)));

static __device__ __forceinline__ float bf2f(unsigned short u) {
    union { float f; unsigned int i; } c; c.i = ((unsigned int)u) << 16; return c.f;
}
static __device__ __forceinline__ short f2bs(float f) {
    __hip_bfloat16 h = __float2bfloat16(f);
    return *reinterpret_cast<short*>(&h);
}

// ---------------- layernorm: one wave per row, float4 + shuffle ----------------
__global__ __launch_bounds__(256) void k_ln(const float* __restrict__ in, const float* __restrict__ g,
                                            const float* __restrict__ bta, float* __restrict__ out) {
    int row = blockIdx.x * 4 + (threadIdx.x >> 6);
    int l = threadIdx.x & 63;
    float4 xv = ((const float4*)(in + (size_t)row*DM))[l];
    float s = xv.x + xv.y + xv.z + xv.w;
    #pragma unroll
    for (int o = 32; o > 0; o >>= 1) s += __shfl_xor(s, o, 64);
    float mean = s * (1.0f/DM);
    float dx = xv.x-mean, dy = xv.y-mean, dz = xv.z-mean, dw = xv.w-mean;
    float vs = dx*dx + dy*dy + dz*dz + dw*dw;
    #pragma unroll
    for (int o = 32; o > 0; o >>= 1) vs += __shfl_xor(vs, o, 64);
    float r = rsqrtf(vs * (1.0f/DM) + 1e-5f);
    float4 gg = ((const float4*)g)[l];
    float4 bb = ((const float4*)bta)[l];
    float4 ov; ov.x = dx*r*gg.x+bb.x; ov.y = dy*r*gg.y+bb.y; ov.z = dz*r*gg.z+bb.z; ov.w = dw*r*gg.w+bb.w;
    ((float4*)(out + (size_t)row*DM))[l] = ov;
}

// ---------------- MFMA bf16 GEMM: 64x64 tile, fp32 in/out, bf16 staging ----------------
template<int K, int N, int ACT, int RES, int QKV>
__global__ __launch_bounds__(256) void k_mgemm(const float* __restrict__ A, const float* __restrict__ W,
                                               const float* __restrict__ bias, float* __restrict__ out) {
    __shared__ __align__(16) short As[64][40];   // [m][k] bf16
    __shared__ __align__(16) short Bs[64][40];   // [n][k] bf16
    int r0 = blockIdx.x * 64;
    int n0 = blockIdx.y * 64;
    int tid = threadIdx.x;
    int w = tid >> 6, l = tid & 63;

    f32x4 acc[4];
    #pragma unroll
    for (int c = 0; c < 4; ++c) acc[c] = (f32x4){0.f,0.f,0.f,0.f};

    for (int k0 = 0; k0 < K; k0 += 32) {
        __syncthreads();
        {
            int m = tid >> 2, ks = (tid & 3) * 8;
            const float* src = A + (size_t)(r0 + m)*K + k0 + ks;
            float4 f0 = *(const float4*)src;
            float4 f1 = *(const float4*)(src + 4);
            short8 pk;
            pk[0]=f2bs(f0.x); pk[1]=f2bs(f0.y); pk[2]=f2bs(f0.z); pk[3]=f2bs(f0.w);
            pk[4]=f2bs(f1.x); pk[5]=f2bs(f1.y); pk[6]=f2bs(f1.z); pk[7]=f2bs(f1.w);
            *(short8*)&As[m][ks] = pk;
        }
        {
            int n = tid & 63, kg = tid >> 6;
            const float* wp = W + (size_t)(k0 + kg*8)*N + n0 + n;
            short8 pk;
            #pragma unroll
            for (int j = 0; j < 8; ++j) pk[j] = f2bs(wp[(size_t)j*N]);
            *(short8*)&Bs[n][kg*8] = pk;
        }
        __syncthreads();
        short8 af = *(short8*)&As[w*16 + (l & 15)][(l >> 4)*8];
        #pragma unroll
        for (int c = 0; c < 4; ++c) {
            short8 bf = *(short8*)&Bs[c*16 + (l & 15)][(l >> 4)*8];
            acc[c] = __builtin_amdgcn_mfma_f32_16x16x32_bf16(af, bf, acc[c], 0, 0, 0);
        }
    }

    int quad = l >> 4;
    #pragma unroll
    for (int c = 0; c < 4; ++c) {
        int col = n0 + c*16 + (l & 15);
        float bv = bias[col];
        #pragma unroll
        for (int reg = 0; reg < 4; ++reg) {
            int row = r0 + w*16 + quad*4 + reg;
            float val = acc[c][reg] + bv;
            if (ACT) val = 0.5f * val * (1.0f + erff(val * 0.70710678118654752f));
            if (QKV) {
                int b = row >> 9, n = row & (NN-1);
                int hh = col >> 5, d = col & (DH-1);
                out[(size_t)((b*NH + hh)*NN + n)*DH + d] = val;
            } else if (RES) {
                out[(size_t)row*N + col] += val;
            } else {
                out[(size_t)row*N + col] = val;
            }
        }
    }
}

// ---------------- k_prep: build w2[8][304][64] bf16 and vhve_d[8][32][320] bf16 ----------------
// w2[h][n][kk]: n<258 & kk<32 -> Qh[n][h*32+kk]; n in [264,291) -> kk<32 ? Qe[n-264] : Ke[n-264]; else 0
// vhve_d[h][d][kk]: kk<258 -> Vh[kk][h*32+d]; kk in [264,291) -> Ve[kk-264][h*32+d]; else 0
__global__ __launch_bounds__(256) void k_prep(const float* __restrict__ q_hop, const float* __restrict__ q_edge,
                                              const float* __restrict__ k_edge, const float* __restrict__ v_hop,
                                              const float* __restrict__ v_edge,
                                              unsigned short* __restrict__ w2, unsigned short* __restrict__ vhve_d) {
    int h = blockIdx.x;
    int tid = threadIdx.x;
    for (int idx = tid; idx < 304*64; idx += 256) {
        int n = idx >> 6, kk = idx & 63;
        float val = 0.f;
        if (n < NHOP && kk < 32) val = q_hop[(size_t)n*DM + h*DH + kk];
        else if (n >= 264 && n < 264 + NEDGE) {
            int e = n - 264;
            val = (kk < 32) ? q_edge[(size_t)e*DM + h*DH + kk]
                            : k_edge[(size_t)e*DM + h*DH + (kk - 32)];
        }
        w2[((size_t)h*304 + n)*64 + kk] = (unsigned short)f2bs(val);
    }
    for (int idx = tid; idx < 32*320; idx += 256) {
        int d = idx / 320, kk = idx - d*320;
        float val = 0.f;
        if (kk < NHOP) val = v_hop[(size_t)kk*DM + h*DH + d];
        else if (kk >= 264 && kk < 264 + NEDGE) val = v_edge[(size_t)(kk-264)*DM + h*DH + d];
        vhve_d[((size_t)h*32 + d)*320 + kk] = (unsigned short)f2bs(val);
    }
}

// ---------------- k [bh][j][d] -> kT [bh][d][j] (64-j tile per block) ----------------
__global__ __launch_bounds__(256) void k_tx(const float* __restrict__ k, float* __restrict__ kT) {
    __shared__ float lds[64*33];
    int bh = blockIdx.x;
    int j0 = blockIdx.y * 64;
    int tid = threadIdx.x;
    {
        int jj = tid >> 2, d8 = tid & 3;
        const float* src = k + ((size_t)bh*NN + j0 + jj)*DH + d8*8;
        float4 a = *(const float4*)(src);
        float4 b = *(const float4*)(src + 4);
        float* dst = lds + jj*33 + d8*8;
        dst[0]=a.x; dst[1]=a.y; dst[2]=a.z; dst[3]=a.w;
        dst[4]=b.x; dst[5]=b.y; dst[6]=b.z; dst[7]=b.w;
    }
    __syncthreads();
    {
        int d = tid >> 3, jg = tid & 7;
        float* dst = kT + ((size_t)bh*DH + d)*NN + j0;
        #pragma unroll
        for (int jj2 = 0; jj2 < 8; ++jj2) {
            int j = jg*8 + jj2;
            dst[j] = lds[j*33 + d];
        }
    }
}

// ---------------- k_kht2: kht[bh][m][j] = Kh[h][m][:] @ k[bh][j][:]  via MFMA ----------------
__global__ __launch_bounds__(256) void k_kht2(const float* __restrict__ k, const float* __restrict__ k_hop,
                                              __hip_bfloat16* __restrict__ kht) {
    __shared__ __align__(16) short kb[512][40];   // bf16 k[bh], padded stride
    int bh = blockIdx.x;
    int hh = bh & (NH-1);
    int r0 = blockIdx.y * 64;   // m tile
    int tid = threadIdx.x;
    int w = tid >> 6, l = tid & 63;
    int quad = l >> 4, lr = l & 15;

    // stage k[bh] -> LDS bf16
    #pragma unroll
    for (int t = 0; t < 8; ++t) {
        int idx = tid + t*256;           // 2048 chunks
        int row = idx >> 2, c = idx & 3;
        const float* src = k + ((size_t)bh*NN + row)*DH + c*8;
        float4 f0 = *(const float4*)src;
        float4 f1 = *(const float4*)(src + 4);
        short8 pk;
        pk[0]=f2bs(f0.x); pk[1]=f2bs(f0.y); pk[2]=f2bs(f0.z); pk[3]=f2bs(f0.w);
        pk[4]=f2bs(f1.x); pk[5]=f2bs(f1.y); pk[6]=f2bs(f1.z); pk[7]=f2bs(f1.w);
        *(short8*)&kb[row][c*8] = pk;
    }
    // A-frag: Kh row (clamped)
    int m = r0 + w*16 + lr;
    int mc = m < NHOP ? m : NHOP-1;
    const float* ar = k_hop + (size_t)mc*DM + hh*DH + quad*8;
    float4 a0 = *(const float4*)ar;
    float4 a1 = *(const float4*)(ar + 4);
    short8 af;
    af[0]=f2bs(a0.x); af[1]=f2bs(a0.y); af[2]=f2bs(a0.z); af[3]=f2bs(a0.w);
    af[4]=f2bs(a1.x); af[5]=f2bs(a1.y); af[6]=f2bs(a1.z); af[7]=f2bs(a1.w);
    __syncthreads();

    for (int ct = 0; ct < 32; ++ct) {
        short8 bf = *(short8*)&kb[ct*16 + lr][quad*8];
        f32x4 acc = (f32x4){0.f,0.f,0.f,0.f};
        acc = __builtin_amdgcn_mfma_f32_16x16x32_bf16(af, bf, acc, 0, 0, 0);
        #pragma unroll
        for (int reg = 0; reg < 4; ++reg) {
            int m2 = r0 + w*16 + quad*4 + reg;
            if (m2 < NHOP)
                kht[((size_t)bh*NHOP + m2)*NN + ct*16 + lr] = __float2bfloat16(acc[reg]);
        }
    }
}

// ---------------- k_qhe2: qhe rows via MFMA; A = [q | k] (K=64), B^T = w2 ----------------
__global__ __launch_bounds__(256) void k_qhe2(const float* __restrict__ q, const float* __restrict__ k,
                                              const unsigned short* __restrict__ w2,
                                              unsigned short* __restrict__ qhe) {
    int bh = blockIdx.x;
    int hh = bh & (NH-1);
    int r0 = blockIdx.y * 64;
    int tid = threadIdx.x;
    int w = tid >> 6, l = tid & 63;
    int quad = l >> 4, lr = l & 15;

    const float* qr = q + ((size_t)bh*NN + r0 + w*16 + lr)*DH + quad*8;
    const float* kr = k + ((size_t)bh*NN + r0 + w*16 + lr)*DH + quad*8;
    float4 f0 = *(const float4*)qr, f1 = *(const float4*)(qr + 4);
    short8 af0;
    af0[0]=f2bs(f0.x); af0[1]=f2bs(f0.y); af0[2]=f2bs(f0.z); af0[3]=f2bs(f0.w);
    af0[4]=f2bs(f1.x); af0[5]=f2bs(f1.y); af0[6]=f2bs(f1.z); af0[7]=f2bs(f1.w);
    f0 = *(const float4*)kr; f1 = *(const float4*)(kr + 4);
    short8 af1;
    af1[0]=f2bs(f0.x); af1[1]=f2bs(f0.y); af1[2]=f2bs(f0.z); af1[3]=f2bs(f0.w);
    af1[4]=f2bs(f1.x); af1[5]=f2bs(f1.y); af1[6]=f2bs(f1.z); af1[7]=f2bs(f1.w);

    const unsigned short* w2h = w2 + (size_t)hh*304*64;
    for (int ct = 0; ct < 19; ++ct) {
        int col = ct*16 + lr;
        short8 b0 = *(const short8*)(w2h + (size_t)col*64 + quad*8);
        short8 b1 = *(const short8*)(w2h + (size_t)col*64 + 32 + quad*8);
        f32x4 acc = (f32x4){0.f,0.f,0.f,0.f};
        acc = __builtin_amdgcn_mfma_f32_16x16x32_bf16(af0, b0, acc, 0, 0, 0);
        acc = __builtin_amdgcn_mfma_f32_16x16x32_bf16(af1, b1, acc, 0, 0, 0);
        if (col < QHE_S) {
            #pragma unroll
            for (int reg = 0; reg < 4; ++reg) {
                int row = r0 + w*16 + quad*4 + reg;
                qhe[((size_t)bh*NN + row)*QHE_S + col] = (unsigned short)f2bs(acc[reg]);
            }
        }
    }
}

// ---------------- k_score: block = (b, 4-i tile, head-half); 4 waves = 4 heads ----------------
// Produces: ctx (dense AV part) and vha bins written OVER the qhe rows it consumed.
__global__ __launch_bounds__(256) void k_score(
    const float* __restrict__ q, const float* __restrict__ kT, const float* __restrict__ v,
    const __hip_bfloat16* __restrict__ kht, const int* __restrict__ dist, const int* __restrict__ edge,
    const unsigned char* __restrict__ mask, unsigned short* __restrict__ qhe,
    float* __restrict__ ctx)
{
    int g   = blockIdx.x;            // 4096
    int r   = g >> 3;                // 0..511
    int b   = (g & 7) + ((r >> 8) << 3);
    int rem = r & 255;
    int i0  = (rem >> 1) * 4;
    int hg  = rem & 1;
    int w   = threadIdx.x >> 6;
    int l   = threadIdx.x & 63;
    int hh  = hg*4 + w;
    int bh  = b*NH + hh;

    __shared__ unsigned short mje[4][NN];        // m | (e<<9)
    __shared__ float qv[4][4][DH];
    __shared__ __hip_bfloat16 pb[4][4][NN];
    __shared__ float bins[4][292];

    {
        int t = threadIdx.x;
        int row = t >> 6, c0 = t & 63;
        #pragma unroll
        for (int rep = 0; rep < 2; ++rep) {
            int c4 = c0 + rep*64;
            int4 dv = ((const int4*)(dist + ((size_t)(b*NN) + i0 + row)*NN))[c4];
            int4 ev = ((const int4*)(edge + ((size_t)(b*NN) + i0 + row)*NN))[c4];
            int m0 = dv.x > 256 ? 256 : dv.x; if (dv.x < 0) m0 = 257;
            int m1 = dv.y > 256 ? 256 : dv.y; if (dv.y < 0) m1 = 257;
            int m2 = dv.z > 256 ? 256 : dv.z; if (dv.z < 0) m2 = 257;
            int m3 = dv.w > 256 ? 256 : dv.w; if (dv.w < 0) m3 = 257;
            int e0 = ev.x > 25 ? 25 : ev.x; if (ev.x < 0) e0 = 26;
            int e1 = ev.y > 25 ? 25 : ev.y; if (ev.y < 0) e1 = 26;
            int e2 = ev.z > 25 ? 25 : ev.z; if (ev.z < 0) e2 = 26;
            int e3 = ev.w > 25 ? 25 : ev.w; if (ev.w < 0) e3 = 26;
            mje[row][c4*4+0] = (unsigned short)(m0 | (e0 << 9));
            mje[row][c4*4+1] = (unsigned short)(m1 | (e1 << 9));
            mje[row][c4*4+2] = (unsigned short)(m2 | (e2 << 9));
            mje[row][c4*4+3] = (unsigned short)(m3 | (e3 << 9));
        }
        #pragma unroll
        for (int rep = 0; rep < 2; ++rep) {
            int i = rep*2 + (l >> 5), d = l & 31;
            qv[w][i][d] = q[((size_t)bh*NN + i0 + i)*DH + d];
        }
        for (int s = l; s < 292; s += 64) bins[w][s] = 0.f;
    }
    __syncthreads();

    float sc[4][8];
    #pragma unroll
    for (int i = 0; i < 4; ++i)
        #pragma unroll
        for (int s = 0; s < 8; ++s) sc[i][s] = 0.f;
    {
        const float* kTb = kT + (size_t)bh*DH*NN;
        for (int d = 0; d < 32; ++d) {
            const float* kr = kTb + (size_t)d*NN + l;
            float k0 = kr[0],   k1 = kr[64],  k2 = kr[128], k3 = kr[192];
            float k4 = kr[256], k5 = kr[320], k6 = kr[384], k7 = kr[448];
            float qa = qv[w][0][d], qb = qv[w][1][d], qc = qv[w][2][d], qd = qv[w][3][d];
            sc[0][0]+=qa*k0; sc[0][1]+=qa*k1; sc[0][2]+=qa*k2; sc[0][3]+=qa*k3;
            sc[0][4]+=qa*k4; sc[0][5]+=qa*k5; sc[0][6]+=qa*k6; sc[0][7]+=qa*k7;
            sc[1][0]+=qb*k0; sc[1][1]+=qb*k1; sc[1][2]+=qb*k2; sc[1][3]+=qb*k3;
            sc[1][4]+=qb*k4; sc[1][5]+=qb*k5; sc[1][6]+=qb*k6; sc[1][7]+=qb*k7;
            sc[2][0]+=qc*k0; sc[2][1]+=qc*k1; sc[2][2]+=qc*k2; sc[2][3]+=qc*k3;
            sc[2][4]+=qc*k4; sc[2][5]+=qc*k5; sc[2][6]+=qc*k6; sc[2][7]+=qc*k7;
            sc[3][0]+=qd*k0; sc[3][1]+=qd*k1; sc[3][2]+=qd*k2; sc[3][3]+=qd*k3;
            sc[3][4]+=qd*k4; sc[3][5]+=qd*k5; sc[3][6]+=qd*k6; sc[3][7]+=qd*k7;
        }
    }

    const __hip_bfloat16* khtb = kht + (size_t)bh*NHOP*NN;
    const unsigned char* mrow = mask + (size_t)b*NN;
    unsigned char msk[8];
    #pragma unroll
    for (int s = 0; s < 8; ++s) msk[s] = mrow[l + 64*s];
    const float scale = 0.17677669529663687f;

    #pragma unroll
    for (int i = 0; i < 4; ++i) {
        unsigned short* qhr = qhe + ((size_t)bh*NN + i0 + i)*QHE_S;
        int pk[8];
        #pragma unroll
        for (int s = 0; s < 8; ++s) pk[s] = mje[i][l + 64*s];
        unsigned short raw[8];
        #pragma unroll
        for (int s = 0; s < 8; ++s)
            raw[s] = ((const unsigned short*)khtb)[(size_t)(pk[s] & 511)*NN + l + 64*s];
        unsigned short qhv[8], qev[8];
        #pragma unroll
        for (int s = 0; s < 8; ++s) qhv[s] = qhr[pk[s] & 511];
        #pragma unroll
        for (int s = 0; s < 8; ++s) qev[s] = qhr[264 + (pk[s] >> 9)];
        float x[8];
        #pragma unroll
        for (int s = 0; s < 8; ++s) {
            float a = (sc[i][s] + bf2f(qhv[s]) + bf2f(raw[s]) + bf2f(qev[s])) * scale;
            if (msk[s]) a = -INFINITY;
            x[s] = a;
        }
        float mx = x[0];
        #pragma unroll
        for (int s = 1; s < 8; ++s) mx = fmaxf(mx, x[s]);
        #pragma unroll
        for (int o = 32; o > 0; o >>= 1) mx = fmaxf(mx, __shfl_xor(mx, o, 64));
        float sum = 0.f;
        #pragma unroll
        for (int s = 0; s < 8; ++s) { x[s] = __expf(x[s] - mx); sum += x[s]; }
        #pragma unroll
        for (int o = 32; o > 0; o >>= 1) sum += __shfl_xor(sum, o, 64);
        float inv = 1.0f / sum;
        #pragma unroll
        for (int s = 0; s < 8; ++s) {
            float ps = x[s] * inv;
            pb[w][i][l + 64*s] = __float2bfloat16(ps);
            atomicAdd(&bins[w][pk[s] & 511], ps);
            atomicAdd(&bins[w][264 + (pk[s] >> 9)], ps);
        }
        #pragma unroll
        for (int s5 = 0; s5 < 5; ++s5) {
            int idx = l + 64*s5;
            if (idx < 292) {
                qhr[idx] = (unsigned short)f2bs(bins[w][idx]);
                if (i < 3) bins[w][idx] = 0.f;
            }
        }
    }

    int jc = l >> 3, d4 = l & 7;
    float4 acc[4];
    #pragma unroll
    for (int i = 0; i < 4; ++i) { acc[i].x = acc[i].y = acc[i].z = acc[i].w = 0.f; }
    {
        const float* vb = v + (size_t)bh*NN*DH + d4*4;
        for (int off = 0; off < 64; ++off) {
            int j = 8*off + jc;
            float4 vv = *(const float4*)(vb + (size_t)j*DH);
            #pragma unroll
            for (int i = 0; i < 4; ++i) {
                float p = bf2f(*(const unsigned short*)&pb[w][i][j]);
                acc[i].x += p*vv.x; acc[i].y += p*vv.y; acc[i].z += p*vv.z; acc[i].w += p*vv.w;
            }
        }
    }
    #pragma unroll
    for (int i = 0; i < 4; ++i) {
        #pragma unroll
        for (int o = 8; o <= 32; o <<= 1) {
            acc[i].x += __shfl_xor(acc[i].x, o, 64);
            acc[i].y += __shfl_xor(acc[i].y, o, 64);
            acc[i].z += __shfl_xor(acc[i].z, o, 64);
            acc[i].w += __shfl_xor(acc[i].w, o, 64);
        }
        if (jc == 0) {
            *(float4*)(ctx + ((size_t)b*NN + i0 + i)*DM + hh*DH + d4*4) = acc[i];
        }
    }
}

// ---------------- k_av2: ctx[b,i,h*32+d] += vha[bh,i,:] @ vhve_d[h][d][:]  via MFMA (K=320) ----------------
__global__ __launch_bounds__(256) void k_av2(const unsigned short* __restrict__ vha,
                                             const unsigned short* __restrict__ vhve_d,
                                             float* __restrict__ ctx) {
    int bh = blockIdx.x;
    int hh = bh & (NH-1);
    int b  = bh >> 3;
    int r0 = blockIdx.y * 64;
    int tid = threadIdx.x;
    int w = tid >> 6, l = tid & 63;
    int quad = l >> 4, lr = l & 15;

    const unsigned short* arow = vha + ((size_t)bh*NN + r0 + w*16 + lr)*QHE_S + quad*8;
    const unsigned short* br0  = vhve_d + ((size_t)hh*32 + lr)*320 + quad*8;
    const unsigned short* br1  = vhve_d + ((size_t)hh*32 + 16 + lr)*320 + quad*8;

    f32x4 acc0 = (f32x4){0.f,0.f,0.f,0.f};
    f32x4 acc1 = (f32x4){0.f,0.f,0.f,0.f};
    #pragma unroll
    for (int k0 = 0; k0 < 320; k0 += 32) {
        short8 af = *(const short8*)(arow + k0);
        short8 b0 = *(const short8*)(br0 + k0);
        short8 b1 = *(const short8*)(br1 + k0);
        acc0 = __builtin_amdgcn_mfma_f32_16x16x32_bf16(af, b0, acc0, 0, 0, 0);
        acc1 = __builtin_amdgcn_mfma_f32_16x16x32_bf16(af, b1, acc1, 0, 0, 0);
    }
    #pragma unroll
    for (int reg = 0; reg < 4; ++reg) {
        int row = r0 + w*16 + quad*4 + reg;
        float* cp = ctx + ((size_t)b*NN + row)*DM + hh*DH;
        cp[lr]      += acc0[reg];
        cp[16 + lr] += acc1[reg];
    }
}

extern "C" void kernel_launch(void* const* d_in, const int* in_sizes, int n_in,
                              void* d_out, int out_size, void* d_ws, size_t ws_size,
                              hipStream_t stream) {
    const float* x     = (const float*)d_in[0];
    const unsigned char* mask = (const unsigned char*)d_in[1];
    const int*   dist  = (const int*)d_in[2];
    const int*   edge  = (const int*)d_in[3];
    const float* node_W = (const float*)d_in[4];
    const float* node_b = (const float*)d_in[5];
    const float* ln1_g = (const float*)d_in[6];
    const float* ln1_b = (const float*)d_in[7];
    const float* Wq = (const float*)d_in[8];
    const float* bq = (const float*)d_in[9];
    const float* Wk = (const float*)d_in[10];
    const float* bk = (const float*)d_in[11];
    const float* Wv = (const float*)d_in[12];
    const float* bv = (const float*)d_in[13];
    const float* Wo = (const float*)d_in[14];
    const float* bo = (const float*)d_in[15];
    const float* ln2_g = (const float*)d_in[16];
    const float* ln2_b = (const float*)d_in[17];
    const float* W1 = (const float*)d_in[18];
    const float* b1 = (const float*)d_in[19];
    const float* W2 = (const float*)d_in[20];
    const float* b2 = (const float*)d_in[21];
    const float* q_hop  = (const float*)d_in[22];
    const float* q_edge = (const float*)d_in[23];
    const float* k_hop  = (const float*)d_in[24];
    const float* k_edge = (const float*)d_in[25];
    const float* v_hop  = (const float*)d_in[26];
    const float* v_edge = (const float*)d_in[27];
    const float* fln_g = (const float*)d_in[28];
    const float* fln_b = (const float*)d_in[29];
    const float* out_W = (const float*)d_in[30];
    const float* out_b = (const float*)d_in[31];
    float* out = (float*)d_out;

    float* ws = (float*)d_ws;
    float* h   = ws + 0;                         //  2,097,152
    float* y   = ws + 2097152;                   //  2,097,152
    float* q   = ws + 4194304;                   //  2,097,152  [B,H,N,DH]
    float* k   = ws + 6291456;                   //  2,097,152
    float* v   = ws + 8388608;                   //  2,097,152
    float* ctx = ws + 10485760;                  //  2,097,152
    __hip_bfloat16* kht = (__hip_bfloat16*)(ws + 12582912);  // 128*258*512 bf16
    float* ffn = ws + 12582912;                  //  8,388,608 floats (aliases kht, dead by then)
    float* kT  = ws + 21037056;                  //  2,097,152  [B,H,DH,NN]
    unsigned short* qhe = (unsigned short*)(ws + 23134208);  // 128*512*296 ushort; becomes vha in k_score
    // tables alias y (y dead between qkv and ln2); k_av2 runs before ln2 rewrites y
    unsigned short* w2     = (unsigned short*)(y);            // 8*304*64 ushorts = 77,824 floats
    unsigned short* vhve_d = (unsigned short*)(y + 81920);    // 8*32*320 ushorts = 40,960 floats

    k_mgemm<DIN, DM, 0, 0, 0><<<dim3(ROWS/64, DM/64), 256, 0, stream>>>(x, node_W, node_b, h);
    k_ln<<<ROWS/4, 256, 0, stream>>>(h, ln1_g, ln1_b, y);
    k_mgemm<DM, DM, 0, 0, 1><<<dim3(ROWS/64, DM/64), 256, 0, stream>>>(y, Wq, bq, q);
    k_mgemm<DM, DM, 0, 0, 1><<<dim3(ROWS/64, DM/64), 256, 0, stream>>>(y, Wk, bk, k);
    k_mgemm<DM, DM, 0, 0, 1><<<dim3(ROWS/64, DM/64), 256, 0, stream>>>(y, Wv, bv, v);
    // y now dead -> build fused tables
    k_prep<<<NH, 256, 0, stream>>>(q_hop, q_edge, k_edge, v_hop, v_edge, w2, vhve_d);
    k_tx<<<dim3(BB*NH, 8), 256, 0, stream>>>(k, kT);
    k_kht2<<<dim3(BB*NH, 5), 256, 0, stream>>>(k, k_hop, kht);
    k_qhe2<<<dim3(BB*NH, NN/64), 256, 0, stream>>>(q, k, w2, qhe);
    k_score<<<BB*(NN/4)*2, 256, 0, stream>>>(q, kT, v, kht, dist, edge, mask, qhe, ctx);
    k_av2<<<dim3(BB*NH, NN/64), 256, 0, stream>>>(qhe, vhve_d, ctx);
    k_mgemm<DM, DM, 0, 1, 0><<<dim3(ROWS/64, DM/64), 256, 0, stream>>>(ctx, Wo, bo, h);
    k_ln<<<ROWS/4, 256, 0, stream>>>(h, ln2_g, ln2_b, y);
    k_mgemm<DM, FF, 1, 0, 0><<<dim3(ROWS/64, FF/64), 256, 0, stream>>>(y, W1, b1, ffn);
    k_mgemm<FF, DM, 0, 1, 0><<<dim3(ROWS/64, DM/64), 256, 0, stream>>>(ffn, W2, b2, h);
    k_ln<<<ROWS/4, 256, 0, stream>>>(h, fln_g, fln_b, y);
    k_mgemm<DM, DOUT, 0, 0, 0><<<dim3(ROWS/64, DOUT/64), 256, 0, stream>>>(y, out_W, out_b, out);
}

// Round 11
// 719.717 us; speedup vs baseline: 4.1645x; 1.0275x over previous
//
#include <hip/hip_runtime.h>
#include <hip/hip_bf16.h>
#include <math.h>

#define BB 16
#define NN 512
#define DIN 128
#define DM 256
#define NH 8
#define DH 32
#define FF 1024
#define DOUT 128
#define NHOP 258
#define NEDGE 27
#define ROWS (BB*NN)   // 8192
#define QHE_S 296      // qhe row stride (ushorts): qh 0..257, qec at 264..290; becomes vha bins after k_score

typedef short short8 __attribute__((ext_vector_type(8)));
typedef float f32x4 __attribute__((ext_vector_type(4)));

static __device__ __forceinline__ float bf2f(unsigned short u) {
    union { float f; unsigned int i; } c; c.i = ((unsigned int)u) << 16; return c.f;
}
static __device__ __forceinline__ short f2bs(float f) {
    __hip_bfloat16 h = __float2bfloat16(f);
    return *reinterpret_cast<short*>(&h);
}

// ---------------- layernorm: one wave per row, float4 + shuffle ----------------
__global__ __launch_bounds__(256) void k_ln(const float* __restrict__ in, const float* __restrict__ g,
                                            const float* __restrict__ bta, float* __restrict__ out) {
    int row = blockIdx.x * 4 + (threadIdx.x >> 6);
    int l = threadIdx.x & 63;
    float4 xv = ((const float4*)(in + (size_t)row*DM))[l];
    float s = xv.x + xv.y + xv.z + xv.w;
    #pragma unroll
    for (int o = 32; o > 0; o >>= 1) s += __shfl_xor(s, o, 64);
    float mean = s * (1.0f/DM);
    float dx = xv.x-mean, dy = xv.y-mean, dz = xv.z-mean, dw = xv.w-mean;
    float vs = dx*dx + dy*dy + dz*dz + dw*dw;
    #pragma unroll
    for (int o = 32; o > 0; o >>= 1) vs += __shfl_xor(vs, o, 64);
    float r = rsqrtf(vs * (1.0f/DM) + 1e-5f);
    float4 gg = ((const float4*)g)[l];
    float4 bb = ((const float4*)bta)[l];
    float4 ov; ov.x = dx*r*gg.x+bb.x; ov.y = dy*r*gg.y+bb.y; ov.z = dz*r*gg.z+bb.z; ov.w = dw*r*gg.w+bb.w;
    ((float4*)(out + (size_t)row*DM))[l] = ov;
}

// ---------------- MFMA bf16 GEMM: 64x64 tile, fp32 in, bf16 staging ----------------
// QKV=0: fp32 out (ACT=gelu, RES=+=). QKV=1: bf16 out [B,H,N,DH]. QKV=2: bf16 out transposed [B,H,DH,N].
template<int K, int N, int ACT, int RES, int QKV>
__global__ __launch_bounds__(256) void k_mgemm(const float* __restrict__ A, const float* __restrict__ W,
                                               const float* __restrict__ bias, void* __restrict__ outv) {
    __shared__ __align__(16) short As[64][40];   // [m][k] bf16
    __shared__ __align__(16) short Bs[64][40];   // [n][k] bf16
    int r0 = blockIdx.x * 64;
    int n0 = blockIdx.y * 64;
    int tid = threadIdx.x;
    int w = tid >> 6, l = tid & 63;

    f32x4 acc[4];
    #pragma unroll
    for (int c = 0; c < 4; ++c) acc[c] = (f32x4){0.f,0.f,0.f,0.f};

    for (int k0 = 0; k0 < K; k0 += 32) {
        __syncthreads();
        {
            int m = tid >> 2, ks = (tid & 3) * 8;
            const float* src = A + (size_t)(r0 + m)*K + k0 + ks;
            float4 f0 = *(const float4*)src;
            float4 f1 = *(const float4*)(src + 4);
            short8 pk;
            pk[0]=f2bs(f0.x); pk[1]=f2bs(f0.y); pk[2]=f2bs(f0.z); pk[3]=f2bs(f0.w);
            pk[4]=f2bs(f1.x); pk[5]=f2bs(f1.y); pk[6]=f2bs(f1.z); pk[7]=f2bs(f1.w);
            *(short8*)&As[m][ks] = pk;
        }
        {
            int n = tid & 63, kg = tid >> 6;
            const float* wp = W + (size_t)(k0 + kg*8)*N + n0 + n;
            short8 pk;
            #pragma unroll
            for (int j = 0; j < 8; ++j) pk[j] = f2bs(wp[(size_t)j*N]);
            *(short8*)&Bs[n][kg*8] = pk;
        }
        __syncthreads();
        short8 af = *(short8*)&As[w*16 + (l & 15)][(l >> 4)*8];
        #pragma unroll
        for (int c = 0; c < 4; ++c) {
            short8 bf = *(short8*)&Bs[c*16 + (l & 15)][(l >> 4)*8];
            acc[c] = __builtin_amdgcn_mfma_f32_16x16x32_bf16(af, bf, acc[c], 0, 0, 0);
        }
    }

    int quad = l >> 4;
    #pragma unroll
    for (int c = 0; c < 4; ++c) {
        int col = n0 + c*16 + (l & 15);
        float bv = bias[col];
        #pragma unroll
        for (int reg = 0; reg < 4; ++reg) {
            int row = r0 + w*16 + quad*4 + reg;
            float val = acc[c][reg] + bv;
            if (ACT) val = 0.5f * val * (1.0f + erff(val * 0.70710678118654752f));
            if (QKV == 1) {
                unsigned short* out = (unsigned short*)outv;
                int b = row >> 9, n = row & (NN-1);
                int hh = col >> 5, d = col & (DH-1);
                out[(size_t)((b*NH + hh)*NN + n)*DH + d] = (unsigned short)f2bs(val);
            } else if (QKV == 2) {
                unsigned short* out = (unsigned short*)outv;
                int b = row >> 9, n = row & (NN-1);
                int hh = col >> 5, d = col & (DH-1);
                out[(size_t)((b*NH + hh)*DH + d)*NN + n] = (unsigned short)f2bs(val);
            } else if (RES) {
                ((float*)outv)[(size_t)row*N + col] += val;
            } else {
                ((float*)outv)[(size_t)row*N + col] = val;
            }
        }
    }
}

// ---------------- k_prep: build w2[8][304][64] bf16 and vhve_d[8][32][320] bf16 ----------------
__global__ __launch_bounds__(256) void k_prep(const float* __restrict__ q_hop, const float* __restrict__ q_edge,
                                              const float* __restrict__ k_edge, const float* __restrict__ v_hop,
                                              const float* __restrict__ v_edge,
                                              unsigned short* __restrict__ w2, unsigned short* __restrict__ vhve_d) {
    int h = blockIdx.x;
    int tid = threadIdx.x;
    for (int idx = tid; idx < 304*64; idx += 256) {
        int n = idx >> 6, kk = idx & 63;
        float val = 0.f;
        if (n < NHOP && kk < 32) val = q_hop[(size_t)n*DM + h*DH + kk];
        else if (n >= 264 && n < 264 + NEDGE) {
            int e = n - 264;
            val = (kk < 32) ? q_edge[(size_t)e*DM + h*DH + kk]
                            : k_edge[(size_t)e*DM + h*DH + (kk - 32)];
        }
        w2[((size_t)h*304 + n)*64 + kk] = (unsigned short)f2bs(val);
    }
    for (int idx = tid; idx < 32*320; idx += 256) {
        int d = idx / 320, kk = idx - d*320;
        float val = 0.f;
        if (kk < NHOP) val = v_hop[(size_t)kk*DM + h*DH + d];
        else if (kk >= 264 && kk < 264 + NEDGE) val = v_edge[(size_t)(kk-264)*DM + h*DH + d];
        vhve_d[((size_t)h*32 + d)*320 + kk] = (unsigned short)f2bs(val);
    }
}

// ---------------- k_kht2: kht[bh][m][j] = Kh[h][m][:] @ k_bf[bh][j][:]  via MFMA ----------------
__global__ __launch_bounds__(256) void k_kht2(const unsigned short* __restrict__ k_bf,
                                              const float* __restrict__ k_hop,
                                              unsigned short* __restrict__ kht) {
    int bh = blockIdx.x;
    int hh = bh & (NH-1);
    int r0 = blockIdx.y * 64;   // m tile
    int tid = threadIdx.x;
    int w = tid >> 6, l = tid & 63;
    int quad = l >> 4, lr = l & 15;

    int m = r0 + w*16 + lr;
    int mc = m < NHOP ? m : NHOP-1;
    const float* ar = k_hop + (size_t)mc*DM + hh*DH + quad*8;
    float4 a0 = *(const float4*)ar;
    float4 a1 = *(const float4*)(ar + 4);
    short8 af;
    af[0]=f2bs(a0.x); af[1]=f2bs(a0.y); af[2]=f2bs(a0.z); af[3]=f2bs(a0.w);
    af[4]=f2bs(a1.x); af[5]=f2bs(a1.y); af[6]=f2bs(a1.z); af[7]=f2bs(a1.w);

    for (int ct = 0; ct < 32; ++ct) {
        short8 bf = *(const short8*)(k_bf + ((size_t)bh*NN + ct*16 + lr)*DH + quad*8);
        f32x4 acc = (f32x4){0.f,0.f,0.f,0.f};
        acc = __builtin_amdgcn_mfma_f32_16x16x32_bf16(af, bf, acc, 0, 0, 0);
        #pragma unroll
        for (int reg = 0; reg < 4; ++reg) {
            int m2 = r0 + w*16 + quad*4 + reg;
            if (m2 < NHOP)
                kht[((size_t)bh*NHOP + m2)*NN + ct*16 + lr] = (unsigned short)f2bs(acc[reg]);
        }
    }
}

// ---------------- k_qhe2: qhe rows via MFMA; A = [q_bf | k_bf] (K=64), B^T = w2 ----------------
__global__ __launch_bounds__(256) void k_qhe2(const unsigned short* __restrict__ q_bf,
                                              const unsigned short* __restrict__ k_bf,
                                              const unsigned short* __restrict__ w2,
                                              unsigned short* __restrict__ qhe) {
    int bh = blockIdx.x;
    int hh = bh & (NH-1);
    int r0 = blockIdx.y * 64;
    int tid = threadIdx.x;
    int w = tid >> 6, l = tid & 63;
    int quad = l >> 4, lr = l & 15;

    int row0 = r0 + w*16 + lr;
    short8 af0 = *(const short8*)(q_bf + ((size_t)bh*NN + row0)*DH + quad*8);
    short8 af1 = *(const short8*)(k_bf + ((size_t)bh*NN + row0)*DH + quad*8);

    const unsigned short* w2h = w2 + (size_t)hh*304*64;
    for (int ct = 0; ct < 19; ++ct) {
        int col = ct*16 + lr;
        short8 b0 = *(const short8*)(w2h + (size_t)col*64 + quad*8);
        short8 b1 = *(const short8*)(w2h + (size_t)col*64 + 32 + quad*8);
        f32x4 acc = (f32x4){0.f,0.f,0.f,0.f};
        acc = __builtin_amdgcn_mfma_f32_16x16x32_bf16(af0, b0, acc, 0, 0, 0);
        acc = __builtin_amdgcn_mfma_f32_16x16x32_bf16(af1, b1, acc, 0, 0, 0);
        if (col < QHE_S) {
            #pragma unroll
            for (int reg = 0; reg < 4; ++reg) {
                int row = r0 + w*16 + quad*4 + reg;
                qhe[((size_t)bh*NN + row)*QHE_S + col] = (unsigned short)f2bs(acc[reg]);
            }
        }
    }
}

// ---------------- k_score: flash-style MFMA. block = (b, head, 16-row i-tile); 4 waves ----------------
// QK^T (MFMA) -> bias gathers -> cross-wave softmax -> P to LDS + bins -> PV (MFMA) -> ctx
__global__ __launch_bounds__(256) void k_score(
    const unsigned short* __restrict__ q_bf, const unsigned short* __restrict__ k_bf,
    const unsigned short* __restrict__ vT_bf, const unsigned short* __restrict__ kht,
    const int* __restrict__ dist, const int* __restrict__ edge,
    const unsigned char* __restrict__ mask, unsigned short* __restrict__ qhe,
    float* __restrict__ ctx)
{
    int g = blockIdx.x;                 // 4096
    int r = g >> 3;                     // 0..511
    int b = (g & 7) + ((r >> 8) << 3);  // XCD-affine
    int rem = r & 255;
    int hh = rem >> 5;
    int i0 = (rem & 31) << 4;
    int bh = b*NH + hh;
    int tid = threadIdx.x;
    int w = tid >> 6, l = tid & 63;
    int lr = l & 15, quad = l >> 4;

    __shared__ __align__(16) unsigned short mje[16][512];   // 16 KB; aliased as cpart[4][16][32] fp32 after bias
    __shared__ __align__(16) unsigned short Pl[16][520];    // 16.25 KB bf16 P
    __shared__ float bins[16][292];                         // 18.7 KB
    __shared__ float red[2][4][16];
    float* cpart = (float*)&mje[0][0];

    // ---- phase A: decode dist/edge (16 contiguous rows), zero bins ----
    {
        const int4* dp = (const int4*)(dist + ((size_t)b*NN + i0)*NN);
        const int4* ep = (const int4*)(edge + ((size_t)b*NN + i0)*NN);
        unsigned short* mf = &mje[0][0];
        for (int idx = tid; idx < 2048; idx += 256) {
            int4 dv = dp[idx];
            int4 ev = ep[idx];
            int m0 = dv.x > 256 ? 256 : dv.x; if (dv.x < 0) m0 = 257;
            int m1 = dv.y > 256 ? 256 : dv.y; if (dv.y < 0) m1 = 257;
            int m2 = dv.z > 256 ? 256 : dv.z; if (dv.z < 0) m2 = 257;
            int m3 = dv.w > 256 ? 256 : dv.w; if (dv.w < 0) m3 = 257;
            int e0 = ev.x > 25 ? 25 : ev.x; if (ev.x < 0) e0 = 26;
            int e1 = ev.y > 25 ? 25 : ev.y; if (ev.y < 0) e1 = 26;
            int e2 = ev.z > 25 ? 25 : ev.z; if (ev.z < 0) e2 = 26;
            int e3 = ev.w > 25 ? 25 : ev.w; if (ev.w < 0) e3 = 26;
            uint2 pk;
            pk.x = (unsigned)(m0 | (e0<<9)) | ((unsigned)(m1 | (e1<<9)) << 16);
            pk.y = (unsigned)(m2 | (e2<<9)) | ((unsigned)(m3 | (e3<<9)) << 16);
            *(uint2*)&mf[idx*4] = pk;
        }
        float* bf_ = &bins[0][0];
        for (int idx = tid; idx < 16*292; idx += 256) bf_[idx] = 0.f;
    }
    __syncthreads();

    // ---- phase B: QK^T via MFMA (wave w covers j in [w*128, w*128+128)) ----
    int jbase = w*128;
    short8 af = *(const short8*)(q_bf + ((size_t)bh*NN + i0 + lr)*DH + quad*8);
    f32x4 sc[8];
    #pragma unroll
    for (int ct = 0; ct < 8; ++ct) {
        short8 bfr = *(const short8*)(k_bf + ((size_t)bh*NN + jbase + ct*16 + lr)*DH + quad*8);
        f32x4 z = (f32x4){0.f,0.f,0.f,0.f};
        sc[ct] = __builtin_amdgcn_mfma_f32_16x16x32_bf16(af, bfr, z, 0, 0, 0);
    }

    // ---- phase C: bias gathers + mask ----
    const unsigned short* khtb = kht + (size_t)bh*NHOP*NN;
    const unsigned char* mrow = mask + (size_t)b*NN;
    const float scale = 0.17677669529663687f;
    unsigned char msk[8];
    #pragma unroll
    for (int ct = 0; ct < 8; ++ct) msk[ct] = mrow[jbase + ct*16 + lr];

    #pragma unroll
    for (int ct = 0; ct < 8; ++ct) {
        int j = jbase + ct*16 + lr;
        #pragma unroll
        for (int reg = 0; reg < 4; ++reg) {
            int il = quad*4 + reg;
            int pk = mje[il][j];
            int m = pk & 511, e = pk >> 9;
            const unsigned short* qhr = qhe + ((size_t)bh*NN + i0 + il)*QHE_S;
            float a = sc[ct][reg] + bf2f(khtb[(size_t)m*NN + j]) + bf2f(qhr[m]) + bf2f(qhr[264 + e]);
            a *= scale;
            if (msk[ct]) a = -INFINITY;
            sc[ct][reg] = a;
        }
    }

    // ---- softmax across all 512 j (cross-wave via LDS) ----
    {
        float mymax[4];
        #pragma unroll
        for (int reg = 0; reg < 4; ++reg) {
            float mx = sc[0][reg];
            #pragma unroll
            for (int ct = 1; ct < 8; ++ct) mx = fmaxf(mx, sc[ct][reg]);
            #pragma unroll
            for (int o = 1; o < 16; o <<= 1) mx = fmaxf(mx, __shfl_xor(mx, o, 16));
            mymax[reg] = mx;
        }
        if (lr == 0) {
            #pragma unroll
            for (int reg = 0; reg < 4; ++reg) red[0][w][quad*4 + reg] = mymax[reg];
        }
        __syncthreads();
        float mysum[4];
        #pragma unroll
        for (int reg = 0; reg < 4; ++reg) {
            int il = quad*4 + reg;
            float mx = fmaxf(fmaxf(red[0][0][il], red[0][1][il]), fmaxf(red[0][2][il], red[0][3][il]));
            float s = 0.f;
            #pragma unroll
            for (int ct = 0; ct < 8; ++ct) { float ex = __expf(sc[ct][reg] - mx); sc[ct][reg] = ex; s += ex; }
            #pragma unroll
            for (int o = 1; o < 16; o <<= 1) s += __shfl_xor(s, o, 16);
            mysum[reg] = s;
        }
        if (lr == 0) {
            #pragma unroll
            for (int reg = 0; reg < 4; ++reg) red[1][w][quad*4 + reg] = mysum[reg];
        }
        __syncthreads();
        float inv_[4];
        #pragma unroll
        for (int reg = 0; reg < 4; ++reg) {
            int il = quad*4 + reg;
            inv_[reg] = 1.0f / (red[1][0][il] + red[1][1][il] + red[1][2][il] + red[1][3][il]);
        }
        // P write + bins scatter
        #pragma unroll
        for (int ct = 0; ct < 8; ++ct) {
            int j = jbase + ct*16 + lr;
            #pragma unroll
            for (int reg = 0; reg < 4; ++reg) {
                int il = quad*4 + reg;
                float ps = sc[ct][reg] * inv_[reg];
                Pl[il][j] = (unsigned short)f2bs(ps);
                int pk = mje[il][j];
                atomicAdd(&bins[il][pk & 511], ps);
                atomicAdd(&bins[il][264 + (pk >> 9)], ps);
            }
        }
    }
    __syncthreads();   // Pl/bins done; mje dead -> cpart alias safe

    // ---- dump bins -> qhe rows (vha, bf16) ----
    {
        int rowd = tid >> 4, c0 = tid & 15;
        unsigned short* dst = qhe + ((size_t)bh*NN + i0 + rowd)*QHE_S;
        for (int c = c0; c < 292; c += 16) dst[c] = (unsigned short)f2bs(bins[rowd][c]);
    }

    // ---- PV via MFMA: wave w handles K-chunk [jbase, jbase+128) ----
    f32x4 acc0 = (f32x4){0.f,0.f,0.f,0.f};
    f32x4 acc1 = (f32x4){0.f,0.f,0.f,0.f};
    #pragma unroll
    for (int t = 0; t < 4; ++t) {
        int kk = jbase + t*32 + quad*8;
        short8 pa = *(const short8*)&Pl[lr][kk];
        short8 b0 = *(const short8*)(vT_bf + ((size_t)bh*DH + lr)*NN + kk);
        short8 b1 = *(const short8*)(vT_bf + ((size_t)bh*DH + 16 + lr)*NN + kk);
        acc0 = __builtin_amdgcn_mfma_f32_16x16x32_bf16(pa, b0, acc0, 0, 0, 0);
        acc1 = __builtin_amdgcn_mfma_f32_16x16x32_bf16(pa, b1, acc1, 0, 0, 0);
    }
    #pragma unroll
    for (int reg = 0; reg < 4; ++reg) {
        int il = quad*4 + reg;
        cpart[((size_t)w*16 + il)*32 + lr]      = acc0[reg];
        cpart[((size_t)w*16 + il)*32 + 16 + lr] = acc1[reg];
    }
    __syncthreads();
    {
        int rowd = tid >> 4, dd = (tid & 15)*2;
        float v0 = 0.f, v1 = 0.f;
        #pragma unroll
        for (int ww = 0; ww < 4; ++ww) {
            v0 += cpart[((size_t)ww*16 + rowd)*32 + dd];
            v1 += cpart[((size_t)ww*16 + rowd)*32 + dd + 1];
        }
        float* cp = ctx + ((size_t)b*NN + i0 + rowd)*DM + hh*DH + dd;
        cp[0] = v0; cp[1] = v1;
    }
}

// ---------------- k_av2: ctx[b,i,h*32+d] += vha[bh,i,:] @ vhve_d[h][d][:]  via MFMA (K=320) ----------------
__global__ __launch_bounds__(256) void k_av2(const unsigned short* __restrict__ vha,
                                             const unsigned short* __restrict__ vhve_d,
                                             float* __restrict__ ctx) {
    int bh = blockIdx.x;
    int hh = bh & (NH-1);
    int b  = bh >> 3;
    int r0 = blockIdx.y * 64;
    int tid = threadIdx.x;
    int w = tid >> 6, l = tid & 63;
    int quad = l >> 4, lr = l & 15;

    const unsigned short* arow = vha + ((size_t)bh*NN + r0 + w*16 + lr)*QHE_S + quad*8;
    const unsigned short* br0  = vhve_d + ((size_t)hh*32 + lr)*320 + quad*8;
    const unsigned short* br1  = vhve_d + ((size_t)hh*32 + 16 + lr)*320 + quad*8;

    f32x4 acc0 = (f32x4){0.f,0.f,0.f,0.f};
    f32x4 acc1 = (f32x4){0.f,0.f,0.f,0.f};
    #pragma unroll
    for (int k0 = 0; k0 < 320; k0 += 32) {
        short8 af = *(const short8*)(arow + k0);
        short8 b0 = *(const short8*)(br0 + k0);
        short8 b1 = *(const short8*)(br1 + k0);
        acc0 = __builtin_amdgcn_mfma_f32_16x16x32_bf16(af, b0, acc0, 0, 0, 0);
        acc1 = __builtin_amdgcn_mfma_f32_16x16x32_bf16(af, b1, acc1, 0, 0, 0);
    }
    #pragma unroll
    for (int reg = 0; reg < 4; ++reg) {
        int row = r0 + w*16 + quad*4 + reg;
        float* cp = ctx + ((size_t)b*NN + row)*DM + hh*DH;
        cp[lr]      += acc0[reg];
        cp[16 + lr] += acc1[reg];
    }
}

extern "C" void kernel_launch(void* const* d_in, const int* in_sizes, int n_in,
                              void* d_out, int out_size, void* d_ws, size_t ws_size,
                              hipStream_t stream) {
    const float* x     = (const float*)d_in[0];
    const unsigned char* mask = (const unsigned char*)d_in[1];
    const int*   dist  = (const int*)d_in[2];
    const int*   edge  = (const int*)d_in[3];
    const float* node_W = (const float*)d_in[4];
    const float* node_b = (const float*)d_in[5];
    const float* ln1_g = (const float*)d_in[6];
    const float* ln1_b = (const float*)d_in[7];
    const float* Wq = (const float*)d_in[8];
    const float* bq = (const float*)d_in[9];
    const float* Wk = (const float*)d_in[10];
    const float* bk = (const float*)d_in[11];
    const float* Wv = (const float*)d_in[12];
    const float* bv = (const float*)d_in[13];
    const float* Wo = (const float*)d_in[14];
    const float* bo = (const float*)d_in[15];
    const float* ln2_g = (const float*)d_in[16];
    const float* ln2_b = (const float*)d_in[17];
    const float* W1 = (const float*)d_in[18];
    const float* b1 = (const float*)d_in[19];
    const float* W2 = (const float*)d_in[20];
    const float* b2 = (const float*)d_in[21];
    const float* q_hop  = (const float*)d_in[22];
    const float* q_edge = (const float*)d_in[23];
    const float* k_hop  = (const float*)d_in[24];
    const float* k_edge = (const float*)d_in[25];
    const float* v_hop  = (const float*)d_in[26];
    const float* v_edge = (const float*)d_in[27];
    const float* fln_g = (const float*)d_in[28];
    const float* fln_b = (const float*)d_in[29];
    const float* out_W = (const float*)d_in[30];
    const float* out_b = (const float*)d_in[31];
    float* out = (float*)d_out;

    float* ws = (float*)d_ws;
    float* h   = ws + 0;                          // 2,097,152
    float* y   = ws + 2097152;                    // 2,097,152
    unsigned short* q_bf  = (unsigned short*)(ws + 4194304);   // 2,097,152 ushorts
    unsigned short* k_bf  = (unsigned short*)(ws + 5242880);
    unsigned short* vT_bf = (unsigned short*)(ws + 6291456);   // [bh][d][n]
    float* ctx = ws + 7340032;                    // 2,097,152
    unsigned short* kht = (unsigned short*)(ws + 9437184);     // 128*258*512 ushorts (8,454,144 floats)
    float* ffn = ws + 9437184;                    // 8,388,608 floats (aliases kht, dead by then)
    unsigned short* qhe = (unsigned short*)(ws + 17891328);    // 128*512*296 ushorts; becomes vha
    // small tables alias y (y dead between qkv-GEMMs and ln2)
    unsigned short* w2     = (unsigned short*)(y);             // 8*304*64 ushorts
    unsigned short* vhve_d = (unsigned short*)(y + 81920);     // 8*32*320 ushorts

    k_mgemm<DIN, DM, 0, 0, 0><<<dim3(ROWS/64, DM/64), 256, 0, stream>>>(x, node_W, node_b, h);
    k_ln<<<ROWS/4, 256, 0, stream>>>(h, ln1_g, ln1_b, y);
    k_mgemm<DM, DM, 0, 0, 1><<<dim3(ROWS/64, DM/64), 256, 0, stream>>>(y, Wq, bq, q_bf);
    k_mgemm<DM, DM, 0, 0, 1><<<dim3(ROWS/64, DM/64), 256, 0, stream>>>(y, Wk, bk, k_bf);
    k_mgemm<DM, DM, 0, 0, 2><<<dim3(ROWS/64, DM/64), 256, 0, stream>>>(y, Wv, bv, vT_bf);
    // y now dead -> build fused tables
    k_prep<<<NH, 256, 0, stream>>>(q_hop, q_edge, k_edge, v_hop, v_edge, w2, vhve_d);
    k_kht2<<<dim3(BB*NH, 5), 256, 0, stream>>>(k_bf, k_hop, kht);
    k_qhe2<<<dim3(BB*NH, NN/64), 256, 0, stream>>>(q_bf, k_bf, w2, qhe);
    k_score<<<BB*NH*(NN/16), 256, 0, stream>>>(q_bf, k_bf, vT_bf, kht, dist, edge, mask, qhe, ctx);
    k_av2<<<dim3(BB*NH, NN/64), 256, 0, stream>>>(qhe, vhve_d, ctx);
    k_mgemm<DM, DM, 0, 1, 0><<<dim3(ROWS/64, DM/64), 256, 0, stream>>>(ctx, Wo, bo, h);
    k_ln<<<ROWS/4, 256, 0, stream>>>(h, ln2_g, ln2_b, y);
    k_mgemm<DM, FF, 1, 0, 0><<<dim3(ROWS/64, FF/64), 256, 0, stream>>>(y, W1, b1, ffn);
    k_mgemm<FF, DM, 0, 1, 0><<<dim3(ROWS/64, DM/64), 256, 0, stream>>>(ffn, W2, b2, h);
    k_ln<<<ROWS/4, 256, 0, stream>>>(h, fln_g, fln_b, y);
    k_mgemm<DM, DOUT, 0, 0, 0><<<dim3(ROWS/64, DOUT/64), 256, 0, stream>>>(y, out_W, out_b, out);
}